// Round 15
// baseline (2538.460 us; speedup 1.0000x reference)
//
#include <hip/hip_runtime.h>
#include <hip/hip_bf16.h>
#include <cmath>

#define B 4
#define S 1024
#define H 1024
#define NH 16
#define HD 64
#define FF 4096
#define CV 2048
#define CV1 2049
#define BS (B*S)            // 4096
#define BSH ((size_t)BS*H)  // 4194304
#define BSF ((size_t)BS*FF) // 16777216

#define F_BIAS  1
#define F_RESID 2
#define F_SILU  4
#define F_MULIN 8

typedef __attribute__((ext_vector_type(8))) _Float16 f16x8;
typedef __attribute__((ext_vector_type(4))) float f32x4;

// Pre-swizzled plane write: element (row,col) stored at
// rowbase + (col&~31) + ((((col>>3)&3)^phi)<<3) + (col&7), phi=(row>>1)&3.
static __device__ inline size_t swz_idx(size_t rowbase, int col, int phi) {
    return rowbase + (size_t)(col & ~31) + ((size_t)(((col >> 3) & 3) ^ phi) << 3) + (col & 7);
}
static __device__ inline void split_store_swz(float v, _Float16* p, size_t plane,
                                              size_t rowbase, int col, int phi, int np) {
    size_t idx = swz_idx(rowbase, col, phi);
    _Float16 h0 = (_Float16)v; p[idx] = h0;
    if (np == 2) p[plane + idx] = (_Float16)(v - (float)h0);
}
// Vectorized: 8 consecutive 8-aligned cols map to one contiguous 16B slot.
static __device__ inline void split_store8_swz(const float* v, _Float16* p, size_t plane,
                                               size_t rowbase, int col8, int phi, int np) {
    size_t idx = swz_idx(rowbase, col8, phi);
    f16x8 h0;
    #pragma unroll
    for (int e = 0; e < 8; ++e) h0[e] = (_Float16)v[e];
    *(f16x8*)&p[idx] = h0;
    if (np == 2) {
        f16x8 h1;
        #pragma unroll
        for (int e = 0; e < 8; ++e) h1[e] = (_Float16)(v[e] - (float)h0[e]);
        *(f16x8*)&p[plane + idx] = h1;
    }
}

// global->LDS async DMA, 16B per lane, LDS dest = base + lane*16
static __device__ inline void gload16(const void* g, void* l) {
    __builtin_amdgcn_global_load_lds(
        (const __attribute__((address_space(1))) void*)g,
        (__attribute__((address_space(3))) void*)l, 16, 0, 0);
}

// XCD-chunk block swizzle. swz=0 none; 1=M-contig chunks; 2=N-contig chunks.
static __device__ inline void tile_coords(int swz, int& bx, int& by) {
    if (swz == 0) { bx = blockIdx.x; by = blockIdx.y; return; }
    int nbx = gridDim.x, nby = gridDim.y;
    int L = blockIdx.y * nbx + blockIdx.x;
    int cpx = (nbx * nby) >> 3;
    int cid = (L & 7) * cpx + (L >> 3);
    if (swz == 1) { by = cid / nbx; bx = cid % nbx; }
    else          { bx = cid / nby; by = cid % nby; }
}

// ============ MFMA GEMM (pass-fused, 2-phase dbuf): one barrier per K-step ============
template<int NP, int NPROD>
__global__ __launch_bounds__(256) void gemm_mf_k(
    const _Float16* __restrict__ A, const _Float16* __restrict__ Wt,
    const float* __restrict__ bias, float* __restrict__ C, const float* __restrict__ resid,
    int M, int N, int K, int ldc, size_t planeA, size_t planeW, int swz)
{
    __shared__ _Float16 As[2][NP][128 * 32];
    __shared__ _Float16 Bs[2][NP][128 * 32];
    const int tid = threadIdx.x;
    const int w = tid >> 6, l = tid & 63;
    const int wm = w >> 1, wn = w & 1;
    int bx, by; tile_coords(swz, bx, by);
    const int row0 = by * 128, col0 = bx * 128;
    const int rA = l >> 2;
    const int cq8 = (l & 3) * 8;
    const int PA[4] = {0, 0, 1, 1};
    const int PW[4] = {0, 1, 0, 1};

    f32x4 acc[4][4];
    #pragma unroll
    for (int i = 0; i < 4; ++i)
        #pragma unroll
        for (int j = 0; j < 4; ++j)
            #pragma unroll
            for (int r = 0; r < 4; ++r) acc[i][j][r] = 0.f;

    const int lr = l & 15, q = l >> 4;

    auto stage = [&](int bf, int k0) {
        #pragma unroll
        for (int p = 0; p < NP; ++p)
            #pragma unroll
            for (int s = 0; s < 2; ++s) {
                int rr = (w * 2 + s) * 16 + rA;
                gload16(A + (size_t)p * planeA + (size_t)(row0 + rr) * K + k0 + cq8,
                        &As[bf][p][(w * 2 + s) * 512]);
                gload16(Wt + (size_t)p * planeW + (size_t)(col0 + rr) * K + k0 + cq8,
                        &Bs[bf][p][(w * 2 + s) * 512]);
            }
    };

    stage(0, 0);
    __syncthreads();
    int cur = 0;
    for (int k0 = 0; k0 < K; k0 += 32) {
        if (k0 + 32 < K) stage(cur ^ 1, k0 + 32);
        f16x8 af[NP][4], bfv[NP][4];
        #pragma unroll
        for (int p = 0; p < NP; ++p)
            #pragma unroll
            for (int i = 0; i < 4; ++i) {
                int ra = wm * 64 + i * 16 + lr;
                af[p][i] = *(const f16x8*)&As[cur][p][ra * 32 + (q ^ ((ra >> 1) & 3)) * 8];
                int rb = wn * 64 + i * 16 + lr;
                bfv[p][i] = *(const f16x8*)&Bs[cur][p][rb * 32 + (q ^ ((rb >> 1) & 3)) * 8];
            }
        #pragma unroll
        for (int pr = 0; pr < NPROD; ++pr) {
            const int pa = PA[pr], pw = PW[pr];
            #pragma unroll
            for (int mi = 0; mi < 4; ++mi)
                #pragma unroll
                for (int ni = 0; ni < 4; ++ni)
                    acc[mi][ni] = __builtin_amdgcn_mfma_f32_16x16x32_f16(
                        af[pa][mi], bfv[pw][ni], acc[mi][ni], 0, 0, 0);
        }
        __syncthreads();
        cur ^= 1;
    }
    const int cw = l & 15, rw = (l >> 4) * 4;
    #pragma unroll
    for (int mi = 0; mi < 4; ++mi)
        #pragma unroll
        for (int ni = 0; ni < 4; ++ni)
            #pragma unroll
            for (int r = 0; r < 4; ++r) {
                int gr = row0 + wm * 64 + mi * 16 + rw + r;
                int gc = col0 + wn * 64 + ni * 16 + cw;
                size_t ci = (size_t)gr * ldc + gc;
                float val = acc[mi][ni][r];
                if (bias)  val += bias[gc];
                if (resid) val += resid[ci];
                C[ci] = val;
            }
}

// ============ Fused gate-up: F = silu(A@Wg)*(A@Wu) -> pre-swz split planes ============
// NP=2 (shallow): single-buffer straight-line (144 VGPR). NP=1 (mid): 2-phase dbuf.
template<int NP, int NPROD>
__global__ __launch_bounds__(256) void gateup_k(
    const _Float16* __restrict__ A, const _Float16* __restrict__ Wg, const _Float16* __restrict__ Wu,
    _Float16* __restrict__ F, int M, int N, int K,
    size_t planeA, size_t planeW, size_t planeF, int npOut, int swz)
{
    const int tid = threadIdx.x;
    const int w = tid >> 6, l = tid & 63;
    const int wm = w >> 1, wn = w & 1;
    int bx, by; tile_coords(swz, bx, by);
    const int row0 = by * 128, col0 = bx * 128;
    const int rA = l >> 2;
    const int cq8 = (l & 3) * 8;
    const int PA[4] = {0, 0, 1, 1};
    const int PW[4] = {0, 1, 0, 1};
    const int lr = l & 15, q = l >> 4;

    f32x4 accg[4][4], accu[4][4];
    #pragma unroll
    for (int i = 0; i < 4; ++i)
        #pragma unroll
        for (int j = 0; j < 4; ++j)
            #pragma unroll
            for (int r = 0; r < 4; ++r) { accg[i][j][r] = 0.f; accu[i][j][r] = 0.f; }

    if constexpr (NP == 2) {
        __shared__ _Float16 As[NP][128 * 32];
        __shared__ _Float16 Bg[NP][128 * 32];
        __shared__ _Float16 Bu[NP][128 * 32];
        for (int k0 = 0; k0 < K; k0 += 32) {
            __syncthreads();
            #pragma unroll
            for (int p = 0; p < NP; ++p)
                #pragma unroll
                for (int s = 0; s < 2; ++s) {
                    int rr = (w * 2 + s) * 16 + rA;
                    gload16(A  + (size_t)p * planeA + (size_t)(row0 + rr) * K + k0 + cq8,
                            &As[p][(w * 2 + s) * 512]);
                    gload16(Wg + (size_t)p * planeW + (size_t)(col0 + rr) * K + k0 + cq8,
                            &Bg[p][(w * 2 + s) * 512]);
                    gload16(Wu + (size_t)p * planeW + (size_t)(col0 + rr) * K + k0 + cq8,
                            &Bu[p][(w * 2 + s) * 512]);
                }
            __syncthreads();
            f16x8 af[NP][4];
            #pragma unroll
            for (int p = 0; p < NP; ++p)
                #pragma unroll
                for (int i = 0; i < 4; ++i) {
                    int ra = wm * 64 + i * 16 + lr;
                    af[p][i] = *(const f16x8*)&As[p][ra * 32 + (q ^ ((ra >> 1) & 3)) * 8];
                }
            #pragma unroll
            for (int pr = 0; pr < NPROD; ++pr) {
                const int pa = PA[pr], pw = PW[pr];
                f16x8 bg[4], bu[4];
                #pragma unroll
                for (int i = 0; i < 4; ++i) {
                    int rb = wn * 64 + i * 16 + lr;
                    int sb = (q ^ ((rb >> 1) & 3)) * 8;
                    bg[i] = *(const f16x8*)&Bg[pw][rb * 32 + sb];
                    bu[i] = *(const f16x8*)&Bu[pw][rb * 32 + sb];
                }
                #pragma unroll
                for (int mi = 0; mi < 4; ++mi)
                    #pragma unroll
                    for (int ni = 0; ni < 4; ++ni) {
                        accg[mi][ni] = __builtin_amdgcn_mfma_f32_16x16x32_f16(
                            af[pa][mi], bg[ni], accg[mi][ni], 0, 0, 0);
                        accu[mi][ni] = __builtin_amdgcn_mfma_f32_16x16x32_f16(
                            af[pa][mi], bu[ni], accu[mi][ni], 0, 0, 0);
                    }
            }
        }
    } else {
        __shared__ _Float16 As[2][128 * 32];
        __shared__ _Float16 Bg[2][128 * 32];
        __shared__ _Float16 Bu[2][128 * 32];
        #pragma unroll
        for (int s = 0; s < 2; ++s) {
            int rr = (w * 2 + s) * 16 + rA;
            gload16(A  + (size_t)(row0 + rr) * K + cq8, &As[0][(w * 2 + s) * 512]);
            gload16(Wg + (size_t)(col0 + rr) * K + cq8, &Bg[0][(w * 2 + s) * 512]);
            gload16(Wu + (size_t)(col0 + rr) * K + cq8, &Bu[0][(w * 2 + s) * 512]);
        }
        __syncthreads();
        int cur = 0;
        for (int k0 = 0; k0 < K; k0 += 32) {
            if (k0 + 32 < K) {
                #pragma unroll
                for (int s = 0; s < 2; ++s) {
                    int rr = (w * 2 + s) * 16 + rA;
                    gload16(A  + (size_t)(row0 + rr) * K + k0 + 32 + cq8, &As[cur ^ 1][(w * 2 + s) * 512]);
                    gload16(Wg + (size_t)(col0 + rr) * K + k0 + 32 + cq8, &Bg[cur ^ 1][(w * 2 + s) * 512]);
                    gload16(Wu + (size_t)(col0 + rr) * K + k0 + 32 + cq8, &Bu[cur ^ 1][(w * 2 + s) * 512]);
                }
            }
            f16x8 af[4], bg[4], bu[4];
            #pragma unroll
            for (int i = 0; i < 4; ++i) {
                int ra = wm * 64 + i * 16 + lr;
                af[i] = *(const f16x8*)&As[cur][ra * 32 + (q ^ ((ra >> 1) & 3)) * 8];
                int rb = wn * 64 + i * 16 + lr;
                int sb = (q ^ ((rb >> 1) & 3)) * 8;
                bg[i] = *(const f16x8*)&Bg[cur][rb * 32 + sb];
                bu[i] = *(const f16x8*)&Bu[cur][rb * 32 + sb];
            }
            #pragma unroll
            for (int mi = 0; mi < 4; ++mi)
                #pragma unroll
                for (int ni = 0; ni < 4; ++ni) {
                    accg[mi][ni] = __builtin_amdgcn_mfma_f32_16x16x32_f16(
                        af[mi], bg[ni], accg[mi][ni], 0, 0, 0);
                    accu[mi][ni] = __builtin_amdgcn_mfma_f32_16x16x32_f16(
                        af[mi], bu[ni], accu[mi][ni], 0, 0, 0);
                }
            __syncthreads();
            cur ^= 1;
        }
    }

    const int cw = l & 15, rw = (l >> 4) * 4;
    #pragma unroll
    for (int mi = 0; mi < 4; ++mi)
        #pragma unroll
        for (int ni = 0; ni < 4; ++ni)
            #pragma unroll
            for (int r = 0; r < 4; ++r) {
                int gr = row0 + wm * 64 + mi * 16 + rw + r;
                int gc = col0 + wn * 64 + ni * 16 + cw;
                float g = accg[mi][ni][r], u = accu[mi][ni][r];
                float val = g / (1.f + expf(-g)) * u;
                split_store_swz(val, F, planeF, (size_t)gr * N, gc, (gr >> 1) & 3, npOut);
            }
}

// ============ MFMA flash attention (fp16, pre-swizzled planes, gload staging) ============
// Causal tile-skip via the PREFIX property of validity (amask = arange<len,
// cvalid = arange<count): a q-tile is all-valid iff its LAST row is valid
// (single uniform scalar load -- no LDS flag, no extra barriers).  For
// all-valid tiles, k-tiles with kt > qt are fully causally masked; scores
// collapse to exactly -1e9 (|s/8| < ulp(1e9)/2), expf underflows to +0, the
// running max is unchanged (co == 1), so skipping them is bit-exact.  Tiles
// containing invalid rows visit all k-tiles (reference uniform softmax).
template<int NP, int NPROD>
__global__ __launch_bounds__(256) void mfattn_k(
    const _Float16* __restrict__ qsp, const _Float16* __restrict__ ksp,
    const _Float16* __restrict__ vtp, _Float16* __restrict__ osp,
    const int* __restrict__ valid)
{
    __shared__ _Float16 KP[NP][2][64 * 32];   // K tile; reused as P planes
    __shared__ _Float16 Vt[NP][2][64 * 32];   // V^T tile
    __shared__ int kvs[64];
    const int tid = threadIdx.x;
    const int w = tid >> 6, l = tid & 63;
    const int lr = l & 15, lq = l >> 4;
    const int qt = blockIdx.x, hh = blockIdx.y, b = blockIdx.z;
    const int rT = l >> 2;
    const int cq8 = (l & 3) * 8;
    const int PA[4] = {0, 0, 1, 1};
    const int PW[4] = {0, 1, 0, 1};

    f16x8 aq[NP][2];
    {
        const int qrowa = qt * 64 + w * 16 + lr;
        const int phiq = (qrowa >> 1) & 3;
        #pragma unroll
        for (int p = 0; p < NP; ++p)
            #pragma unroll
            for (int ks = 0; ks < 2; ++ks)
                aq[p][ks] = *(const f16x8*)(qsp + (size_t)p * BSH
                    + (size_t)(b * S + qrowa) * H + hh * 64 + ks * 32 + ((lq ^ phiq) << 3));
    }
    int qvr[4];
    #pragma unroll
    for (int r = 0; r < 4; ++r)
        qvr[r] = valid[b * S + qt * 64 + w * 16 + lq * 4 + r];

    // prefix-contiguous validity: last row valid => whole tile valid
    const int allv = valid[b * S + qt * 64 + 63];
    const int ktmax = allv ? qt : (S / 64 - 1);

    float m[4], lsum[4];
    f32x4 acco[4];
    #pragma unroll
    for (int r = 0; r < 4; ++r) { m[r] = -3.4e38f; lsum[r] = 0.f; }
    #pragma unroll
    for (int n = 0; n < 4; ++n)
        #pragma unroll
        for (int r = 0; r < 4; ++r) acco[n][r] = 0.f;

    for (int kt = 0; kt <= ktmax; ++kt) {
        __syncthreads();
        {
            const int r = w * 16 + rT;
            #pragma unroll
            for (int p = 0; p < NP; ++p)
                #pragma unroll
                for (int hf = 0; hf < 2; ++hf) {
                    gload16(ksp + (size_t)p * BSH
                            + (size_t)(b * S + kt * 64 + r) * H + hh * 64 + hf * 32 + cq8,
                            &KP[p][hf][w * 512]);
                    gload16(vtp + (size_t)p * BSH
                            + ((size_t)(hh * 64 + r) * B + b) * S + kt * 64 + hf * 32 + cq8,
                            &Vt[p][hf][w * 512]);
                }
        }
        if (tid < 64) kvs[tid] = valid[b * S + kt * 64 + tid];
        __syncthreads();

        // ---- S = Q @ K^T ----
        f32x4 accs[4];
        #pragma unroll
        for (int n = 0; n < 4; ++n)
            #pragma unroll
            for (int r = 0; r < 4; ++r) accs[n][r] = 0.f;
        #pragma unroll
        for (int pr = 0; pr < NPROD; ++pr) {
            const int pa = PA[pr], pw = PW[pr];
            #pragma unroll
            for (int ks = 0; ks < 2; ++ks)
                #pragma unroll
                for (int n = 0; n < 4; ++n) {
                    int rb = n * 16 + lr;
                    f16x8 bk = *(const f16x8*)&KP[pw][ks][rb * 32 + ((lq ^ ((rb >> 1) & 3))) * 8];
                    accs[n] = __builtin_amdgcn_mfma_f32_16x16x32_f16(
                        aq[pa][ks], bk, accs[n], 0, 0, 0);
                }
        }
        // ---- mask + online softmax ----
        float pf[4][4];
        int kva[4];
        #pragma unroll
        for (int n = 0; n < 4; ++n) kva[n] = kvs[n * 16 + lr];
        #pragma unroll
        for (int r = 0; r < 4; ++r) {
            int qr = qt * 64 + w * 16 + lq * 4 + r;
            float rowm = -3.4e38f;
            #pragma unroll
            for (int n = 0; n < 4; ++n) {
                int kc = kt * 64 + n * 16 + lr;
                float sv = accs[n][r] * 0.125f;
                int allowed = (kc <= qr) && qvr[r] && kva[n];
                if (!allowed) sv = sv + -1e9f;
                pf[n][r] = sv;
                rowm = fmaxf(rowm, sv);
            }
            rowm = fmaxf(rowm, __shfl_xor(rowm, 1));
            rowm = fmaxf(rowm, __shfl_xor(rowm, 2));
            rowm = fmaxf(rowm, __shfl_xor(rowm, 4));
            rowm = fmaxf(rowm, __shfl_xor(rowm, 8));
            float mn = fmaxf(m[r], rowm);
            float co = __expf(m[r] - mn);
            float rs = 0.f;
            #pragma unroll
            for (int n = 0; n < 4; ++n) { pf[n][r] = __expf(pf[n][r] - mn); rs += pf[n][r]; }
            rs += __shfl_xor(rs, 1);
            rs += __shfl_xor(rs, 2);
            rs += __shfl_xor(rs, 4);
            rs += __shfl_xor(rs, 8);
            lsum[r] = lsum[r] * co + rs;
            m[r] = mn;
            #pragma unroll
            for (int n = 0; n < 4; ++n) acco[n][r] *= co;
        }
        __syncthreads();
        // ---- write P (fp16 split) into KP, swizzled for a-frag reads ----
        #pragma unroll
        for (int n = 0; n < 4; ++n) {
            int col = n * 16 + lr;
            int hf = col >> 5, colh = col & 31, cq2 = colh >> 3, pos = colh & 7;
            #pragma unroll
            for (int r = 0; r < 4; ++r) {
                int rowg = w * 16 + lq * 4 + r;
                int off = rowg * 32 + (cq2 ^ ((rowg >> 1) & 3)) * 8 + pos;
                float pv = pf[n][r];
                _Float16 h0 = (_Float16)pv;
                KP[0][hf][off] = h0;
                if (NP == 2) KP[1][hf][off] = (_Float16)(pv - (float)h0);
            }
        }
        __syncthreads();
        // ---- O += P @ V ----
        #pragma unroll
        for (int pr = 0; pr < NPROD; ++pr) {
            const int pa = PA[pr], pw = PW[pr];
            #pragma unroll
            for (int ks = 0; ks < 2; ++ks) {
                int ra = w * 16 + lr;
                f16x8 ap = *(const f16x8*)&KP[pa][ks][ra * 32 + ((lq ^ ((ra >> 1) & 3))) * 8];
                #pragma unroll
                for (int n = 0; n < 4; ++n) {
                    int rb = n * 16 + lr;
                    f16x8 bv = *(const f16x8*)&Vt[pw][ks][rb * 32 + ((lq ^ ((rb >> 1) & 3))) * 8];
                    acco[n] = __builtin_amdgcn_mfma_f32_16x16x32_f16(
                        ap, bv, acco[n], 0, 0, 0);
                }
            }
        }
    }
    // ---- write O as pre-swizzled split planes ----
    #pragma unroll
    for (int r = 0; r < 4; ++r) {
        float inv = 1.0f / lsum[r];
        int qr = qt * 64 + w * 16 + lq * 4 + r;
        size_t rowbase = (size_t)(b * S + qr) * H;
        int phi = ((b * S + qr) >> 1) & 3;
        #pragma unroll
        for (int n = 0; n < 4; ++n)
            split_store_swz(acco[n][r] * inv, osp, BSH, rowbase, hh * 64 + n * 16 + lr, phi, NP);
    }
}

// ============ Init: trig table + iota positions (merged) ============
__global__ __launch_bounds__(256) void init_k(float* __restrict__ ct, float* __restrict__ st,
    int* __restrict__ pos)
{
    int idx = blockIdx.x * 256 + threadIdx.x;   // S*32 total
    if (idx < S * 32) {
        int i = idx & 31, p = idx >> 5;
        double inv = exp(-((double)(2 * i) / 64.0) * log(10000.0));
        double ang = (double)p * inv;
        ct[idx] = (float)cos(ang);
        st[idx] = (float)sin(ang);
    }
    if (idx < BS) pos[idx] = idx & (S - 1);
}

// ============ RoPE (q AND k) + fp16 split, vectorized 8-wide stores ============
__global__ __launch_bounds__(256) void rope2_split_k(const float* __restrict__ x,
    int xld, const int* __restrict__ pos,
    const float* __restrict__ ct, const float* __restrict__ st,
    _Float16* __restrict__ yq, _Float16* __restrict__ yk, size_t plane, int np)
{
    int gid = blockIdx.x * 256 + threadIdx.x;   // 2*BS*NH*4 = 524288 items
    int sel = gid >> 18;                        // BS*NH*4 = 262144 = 2^18
    int idx = gid & 262143;
    int i8 = (idx & 3) * 8;
    int head = (idx >> 2) & 15;
    int bs = idx >> 6;
    int p = pos[bs];
    const float* base = x + (size_t)bs * xld + sel * H + head * 64;
    float o1[8], o2[8];
    #pragma unroll
    for (int e = 0; e < 8; ++e) {
        float c = ct[p * 32 + i8 + e], sn = st[p * 32 + i8 + e];
        float x1 = base[i8 + e], x2 = base[32 + i8 + e];
        o1[e] = x1 * c - x2 * sn;
        o2[e] = x2 * c + x1 * sn;
    }
    _Float16* y = sel ? yk : yq;
    size_t rowbase = (size_t)bs * H;
    int phi = (bs >> 1) & 3;
    split_store8_swz(o1, y, plane, rowbase, head * 64 + i8, phi, np);
    split_store8_swz(o2, y, plane, rowbase, head * 64 + 32 + i8, phi, np);
}

// ============ V transpose + split, 64s x 32hd tile, vectorized stores ============
__global__ __launch_bounds__(256) void splitvt_k(const float* __restrict__ V,
    int vld, int voff, _Float16* __restrict__ Vt, size_t plane, int np)
{
    __shared__ float t[64][33];
    const int tid = threadIdx.x;
    const int s0 = blockIdx.x * 64;
    const int hd0 = blockIdx.y * 32;
    const int b = blockIdx.z;
    #pragma unroll
    for (int i = 0; i < 8; ++i) {
        int e = tid + i * 256;          // 0..2047
        int rr = e >> 5, cc = e & 31;   // 64 s-rows x 32 hd
        t[rr][cc] = V[(size_t)(b * S + s0 + rr) * vld + voff + hd0 + cc];
    }
    __syncthreads();
    int rn = tid >> 3, sg = (tid & 7) * 8;   // 32 hd x 8 s-groups
    int hd = hd0 + rn;
    float vals[8];
    #pragma unroll
    for (int e = 0; e < 8; ++e) vals[e] = t[sg + e][rn];
    split_store8_swz(vals, Vt, plane, ((size_t)hd * B + b) * S, s0 + sg, ((hd & 63) >> 1) & 3, np);
}

// ============ Weight transpose + split: W[K,N](srcld) -> Wt [N][K], 32k x 64n tile ============
__global__ __launch_bounds__(256) void splitwt_k(const float* __restrict__ W,
    _Float16* __restrict__ Wt, int K, int N, int srcld, size_t plane, int np)
{
    __shared__ float t[32][65];
    const int tid = threadIdx.x;
    const int n0 = blockIdx.x * 64, k0 = blockIdx.y * 32;
    #pragma unroll
    for (int i = 0; i < 8; ++i) {
        int e = tid + i * 256;
        int rk = e >> 6, cn = e & 63;
        t[rk][cn] = W[(size_t)(k0 + rk) * srcld + n0 + cn];
    }
    __syncthreads();
    int rn = tid >> 2, kg = (tid & 3) * 8;
    int nn = n0 + rn;
    float vals[8];
    #pragma unroll
    for (int e = 0; e < 8; ++e) vals[e] = t[kg + e][rn];
    split_store8_swz(vals, Wt, plane, (size_t)nn * K, k0 + kg, (nn >> 1) & 3, np);
}

// ============ 3-way merged weight split (QKV -> [3H][H] panel) ============
__global__ __launch_bounds__(256) void splitwt3_k(const float* __restrict__ W0,
    const float* __restrict__ W1, const float* __restrict__ W2,
    _Float16* __restrict__ Wt, size_t plane, int np)
{
    __shared__ float t[32][65];
    const int tid = threadIdx.x;
    const int n0 = blockIdx.x * 64, k0 = blockIdx.y * 32;
    const int z = blockIdx.z;
    const float* W = (z == 0) ? W0 : (z == 1) ? W1 : W2;
    #pragma unroll
    for (int i = 0; i < 8; ++i) {
        int e = tid + i * 256;
        int rk = e >> 6, cn = e & 63;
        t[rk][cn] = W[(size_t)(k0 + rk) * H + n0 + cn];
    }
    __syncthreads();
    int rn = tid >> 2, kg = (tid & 3) * 8;
    int nn = n0 + rn;
    int ng = z * H + nn;
    float vals[8];
    #pragma unroll
    for (int e = 0; e < 8; ++e) vals[e] = t[kg + e][rn];
    split_store8_swz(vals, Wt, plane, (size_t)ng * H, k0 + kg, (nn >> 1) & 3, np);
}

// ============ 2-way merged weight split (Wg/Wu) ============
__global__ __launch_bounds__(256) void splitwt2_k(const float* __restrict__ W0,
    const float* __restrict__ W1, _Float16* __restrict__ D0, _Float16* __restrict__ D1,
    size_t plane, int np)
{
    __shared__ float t[32][65];
    const int tid = threadIdx.x;
    const int n0 = blockIdx.x * 64, k0 = blockIdx.y * 32;
    const int z = blockIdx.z;
    const float* W = z ? W1 : W0;
    _Float16* Wt = z ? D1 : D0;
    #pragma unroll
    for (int i = 0; i < 8; ++i) {
        int e = tid + i * 256;
        int rk = e >> 6, cn = e & 63;
        t[rk][cn] = W[(size_t)(k0 + rk) * FF + n0 + cn];
    }
    __syncthreads();
    int rn = tid >> 2, kg = (tid & 3) * 8;
    int nn = n0 + rn;
    float vals[8];
    #pragma unroll
    for (int e = 0; e < 8; ++e) vals[e] = t[kg + e][rn];
    split_store8_swz(vals, Wt, plane, (size_t)nn * H, k0 + kg, (nn >> 1) & 3, np);
}

// ============ Plain fp32 -> fp16 split planes (rows of length H), vectorized ============
__global__ __launch_bounds__(256) void splita_swz_k(const float* __restrict__ x,
    _Float16* __restrict__ y, size_t plane, int np)
{
    int row = blockIdx.x;
    size_t rowbase = (size_t)row * H;
    int phi = (row >> 1) & 3;
    int tid = threadIdx.x;
    if (tid < H / 8) {
        int c0 = tid * 8;
        float vals[8];
        #pragma unroll
        for (int e = 0; e < 8; ++e) vals[e] = x[rowbase + c0 + e];
        split_store8_swz(vals, y, plane, rowbase, c0, phi, np);
    }
}

// ============ RMSNorm -> pre-swz fp16 split ============
__global__ __launch_bounds__(256) void rmsnorm_split_k(const float* __restrict__ x,
    const float* __restrict__ w, _Float16* __restrict__ y, size_t plane, int np)
{
    int row = blockIdx.x;
    const float* xr = x + (size_t)row * H;
    __shared__ float red[256];
    float s = 0.f;
    for (int i = threadIdx.x; i < H; i += 256) { float v = xr[i]; s += v * v; }
    red[threadIdx.x] = s; __syncthreads();
    for (int off = 128; off > 0; off >>= 1) {
        if (threadIdx.x < off) red[threadIdx.x] += red[threadIdx.x + off];
        __syncthreads();
    }
    float r = 1.0f / sqrtf(red[0] / (float)H + 1e-6f);
    size_t rowbase = (size_t)row * H;
    int phi = (row >> 1) & 3;
    if (threadIdx.x < H / 8) {
        int c0 = threadIdx.x * 8;
        float vals[8];
        #pragma unroll
        for (int e = 0; e < 8; ++e) vals[e] = xr[c0 + e] * r * w[c0 + e];
        split_store8_swz(vals, y, plane, rowbase, c0, phi, np);
    }
}

// ---------------- fp32 GEMM (fallback path) ----------------
__global__ __launch_bounds__(256) void gemm_k(
    const float* __restrict__ A, const float* __restrict__ Wm,
    const float* __restrict__ bias, float* __restrict__ C,
    int M, int N, int K, int lda, int ldb, int ldc, int flags)
{
    __shared__ float As[16][65];
    __shared__ float Bs[16][65];
    const int tid = threadIdx.x;
    const int tx = tid & 15, ty = tid >> 4;
    const int row0 = blockIdx.y * 64, col0 = blockIdx.x * 64;
    float acc[4][4] = {};
    for (int k0 = 0; k0 < K; k0 += 16) {
        #pragma unroll
        for (int l = 0; l < 4; ++l) {
            int e = tid + l * 256;
            int r = e >> 4, c = e & 15;
            int gr = row0 + r;
            float vv = 0.f;
            if (gr < M) vv = A[(size_t)gr * lda + (k0 + c)];
            As[c][r] = vv;
        }
        #pragma unroll
        for (int l = 0; l < 4; ++l) {
            int e = tid + l * 256;
            int r = e >> 6, c = e & 63;
            int gc = col0 + c;
            float vv = 0.f;
            if (gc < N) vv = Wm[(size_t)(k0 + r) * ldb + gc];
            Bs[r][c] = vv;
        }
        __syncthreads();
        #pragma unroll
        for (int kk = 0; kk < 16; ++kk) {
            float a[4], bb[4];
            #pragma unroll
            for (int i = 0; i < 4; ++i) a[i] = As[kk][ty * 4 + i];
            #pragma unroll
            for (int j = 0; j < 4; ++j) bb[j] = Bs[kk][tx * 4 + j];
            #pragma unroll
            for (int i = 0; i < 4; ++i)
                #pragma unroll
                for (int j = 0; j < 4; ++j)
                    acc[i][j] += a[i] * bb[j];
        }
        __syncthreads();
    }
    #pragma unroll
    for (int i = 0; i < 4; ++i) {
        int gr = row0 + ty * 4 + i;
        if (gr >= M) continue;
        #pragma unroll
        for (int j = 0; j < 4; ++j) {
            int gc = col0 + tx * 4 + j;
            if (gc >= N) continue;
            float vv = acc[i][j];
            if (flags & F_BIAS)  vv += bias[gc];
            if (flags & F_SILU)  vv = vv / (1.f + expf(-vv));
            size_t cidx = (size_t)gr * ldc + gc;
            if (flags & F_MULIN) vv *= C[cidx];
            if (flags & F_RESID) vv += C[cidx];
            C[cidx] = vv;
        }
    }
}

// ---------------- RMSNorm fp32 (fallback) ----------------
__global__ __launch_bounds__(256) void rmsnorm_k(const float* __restrict__ x,
    const float* __restrict__ w, float* __restrict__ y)
{
    int row = blockIdx.x;
    const float* xr = x + (size_t)row * H;
    float* yr = y + (size_t)row * H;
    __shared__ float red[256];
    float s = 0.f;
    for (int i = threadIdx.x; i < H; i += 256) { float v = xr[i]; s += v * v; }
    red[threadIdx.x] = s; __syncthreads();
    for (int off = 128; off > 0; off >>= 1) {
        if (threadIdx.x < off) red[threadIdx.x] += red[threadIdx.x + off];
        __syncthreads();
    }
    float r = 1.0f / sqrtf(red[0] / (float)H + 1e-6f);
    for (int i = threadIdx.x; i < H; i += 256) yr[i] = xr[i] * r * w[i];
}

// ---------------- Embed gather (float4) ----------------
__global__ __launch_bounds__(256) void embed_k(const int* __restrict__ ids,
    const float* __restrict__ emb, float* __restrict__ h)
{
    int bs = blockIdx.x;
    const float4* e = (const float4*)(emb + (size_t)ids[bs] * H);
    float4* hr = (float4*)(h + (size_t)bs * H);
    hr[threadIdx.x] = e[threadIdx.x];
}

// ---------------- RoPE fp32 in-place (fallback) ----------------
__global__ __launch_bounds__(256) void rope_k(float* __restrict__ x, const int* __restrict__ pos)
{
    int idx = blockIdx.x * 256 + threadIdx.x;
    int i = idx & 31;
    int head = (idx >> 5) & 15;
    int bs = idx >> 9;
    int p = pos[bs];
    double inv = exp(-((double)(2 * i) / 64.0) * log(10000.0));
    double ang = (double)p * inv;
    float c = (float)cos(ang), sn = (float)sin(ang);
    float* base = x + (size_t)bs * H + head * 64;
    float x1 = base[i], x2 = base[i + 32];
    base[i]      = x1 * c - x2 * sn;
    base[i + 32] = x2 * c + x1 * sn;
}

// ---------------- Flash attention fp32 (fallback) ----------------
__global__ __launch_bounds__(256) void fattn_k(const float* __restrict__ q,
    const float* __restrict__ k, const float* __restrict__ v,
    float* __restrict__ o, const int* __restrict__ valid)
{
    const int qt = blockIdx.x, hh = blockIdx.y, b = blockIdx.z;
    const int tid = threadIdx.x;
    const int tx = tid & 15, ty = tid >> 4;
    __shared__ float Qs[64][68];
    __shared__ float Ks[64][68];
    __shared__ float Vs[64][68];
    __shared__ int   kvs[64];
    const size_t hoff = (size_t)hh * HD;

    {
        int row = tid >> 2, d0 = (tid & 3) * 16;
        const float* qp = q + ((size_t)(b * S + qt * 64 + row)) * H + hoff + d0;
        float4* dst = (float4*)&Qs[row][d0];
        const float4* src = (const float4*)qp;
        #pragma unroll
        for (int e = 0; e < 4; ++e) dst[e] = src[e];
    }
    int qv[4]; int qrow_g[4];
    #pragma unroll
    for (int i = 0; i < 4; ++i) {
        qrow_g[i] = qt * 64 + ty * 4 + i;
        qv[i] = valid[b * S + qrow_g[i]];
    }
    float m[4], l[4], acc[4][4];
    #pragma unroll
    for (int i = 0; i < 4; ++i) {
        m[i] = -3.4e38f; l[i] = 0.f;
        #pragma unroll
        for (int j = 0; j < 4; ++j) acc[i][j] = 0.f;
    }

    for (int kt = 0; kt < S / 64; ++kt) {
        __syncthreads();
        {
            int row = tid >> 2, d0 = (tid & 3) * 16;
            const float* kp = k + ((size_t)(b * S + kt * 64 + row)) * H + hoff + d0;
            float4* dst = (float4*)&Ks[row][d0];
            const float4* src = (const float4*)kp;
            #pragma unroll
            for (int e = 0; e < 4; ++e) dst[e] = src[e];
        }
        {
            int kk = tid >> 2, d0 = (tid & 3) * 16;
            const float* vp = v + ((size_t)(b * S + kt * 64 + kk)) * H + hoff + d0;
            #pragma unroll
            for (int e = 0; e < 16; e += 4) {
                float4 vv = *(const float4*)(vp + e);
                Vs[d0 + e + 0][kk] = vv.x;
                Vs[d0 + e + 1][kk] = vv.y;
                Vs[d0 + e + 2][kk] = vv.z;
                Vs[d0 + e + 3][kk] = vv.w;
            }
        }
        if (tid < 64) kvs[tid] = valid[b * S + kt * 64 + tid];
        __syncthreads();

        float s4[4][4];
        #pragma unroll
        for (int i = 0; i < 4; ++i)
            #pragma unroll
            for (int j = 0; j < 4; ++j) s4[i][j] = 0.f;
        #pragma unroll
        for (int c = 0; c < 16; ++c) {
            float4 a[4], bb[4];
            #pragma unroll
            for (int i = 0; i < 4; ++i) a[i]  = ((const float4*)&Qs[ty * 4 + i][0])[c];
            #pragma unroll
            for (int j = 0; j < 4; ++j) bb[j] = ((const float4*)&Ks[tx * 4 + j][0])[c];
            #pragma unroll
            for (int i = 0; i < 4; ++i)
                #pragma unroll
                for (int j = 0; j < 4; ++j) {
                    s4[i][j] += a[i].x * bb[j].x + a[i].y * bb[j].y
                              + a[i].z * bb[j].z + a[i].w * bb[j].w;
                }
        }
        float p[4][4];
        float corr[4];
        #pragma unroll
        for (int i = 0; i < 4; ++i) {
            float rm = -3.4e38f;
            #pragma unroll
            for (int j = 0; j < 4; ++j) {
                int kc = kt * 64 + tx * 4 + j;
                float sv = s4[i][j] * 0.125f;
                int allowed = (kc <= qrow_g[i]) && qv[i] && kvs[tx * 4 + j];
                if (!allowed) sv = sv + -1e9f;
                s4[i][j] = sv;
                rm = fmaxf(rm, sv);
            }
            rm = fmaxf(rm, __shfl_xor(rm, 1));
            rm = fmaxf(rm, __shfl_xor(rm, 2));
            rm = fmaxf(rm, __shfl_xor(rm, 4));
            rm = fmaxf(rm, __shfl_xor(rm, 8));
            float mn = fmaxf(m[i], rm);
            corr[i] = expf(m[i] - mn);
            float rs = 0.f;
            #pragma unroll
            for (int j = 0; j < 4; ++j) { p[i][j] = expf(s4[i][j] - mn); rs += p[i][j]; }
            rs += __shfl_xor(rs, 1);
            rs += __shfl_xor(rs, 2);
            rs += __shfl_xor(rs, 4);
            rs += __shfl_xor(rs, 8);
            l[i] = l[i] * corr[i] + rs;
            m[i] = mn;
            #pragma unroll
            for (int j = 0; j < 4; ++j) acc[i][j] *= corr[i];
        }
        __syncthreads();
        #pragma unroll
        for (int i = 0; i < 4; ++i) {
            float4 pv4 = make_float4(p[i][0], p[i][1], p[i][2], p[i][3]);
            *(float4*)&Ks[ty * 4 + i][tx * 4] = pv4;
        }
        __syncthreads();
        #pragma unroll
        for (int c = 0; c < 16; ++c) {
            float4 a[4], bb[4];
            #pragma unroll
            for (int i = 0; i < 4; ++i) a[i]  = ((const float4*)&Ks[ty * 4 + i][0])[c];
            #pragma unroll
            for (int j = 0; j < 4; ++j) bb[j] = ((const float4*)&Vs[tx * 4 + j][0])[c];
            #pragma unroll
            for (int i = 0; i < 4; ++i)
                #pragma unroll
                for (int j = 0; j < 4; ++j) {
                    acc[i][j] += a[i].x * bb[j].x + a[i].y * bb[j].y
                               + a[i].z * bb[j].z + a[i].w * bb[j].w;
                }
        }
    }
    #pragma unroll
    for (int i = 0; i < 4; ++i) {
        float inv = 1.0f / l[i];
        float4 ov = make_float4(acc[i][0] * inv, acc[i][1] * inv,
                                acc[i][2] * inv, acc[i][3] * inv);
        *(float4*)(o + ((size_t)(b * S + qrow_g[i])) * H + hoff + tx * 4) = ov;
    }
}

// ---------------- Discretize + inline null-logit (fused headcol) ----------------
__global__ __launch_bounds__(256) void discretize_h_k(const float* __restrict__ logits,
    const float* __restrict__ h, const float* __restrict__ head_w, const float* __restrict__ head_b,
    const float* __restrict__ gumbel, _Float16* __restrict__ z, int* __restrict__ chosen)
{
    int bs = blockIdx.x;
    const float* lg = logits + (size_t)bs * CV1;
    const float* gm = gumbel + (size_t)bs * CV1;
    __shared__ float redv[256]; __shared__ int redi[256];
    int tid = threadIdx.x;
    // null logit (col CV): dot(h[bs], head_w[:,CV]) + head_b[CV]
    float ps = 0.f;
    for (int j = tid; j < H; j += 256)
        ps += h[(size_t)bs * H + j] * head_w[(size_t)j * CV1 + CV];
    redv[tid] = ps; __syncthreads();
    for (int off = 128; off > 0; off >>= 1) {
        if (tid < off) redv[tid] += redv[tid + off];
        __syncthreads();
    }
    float nullv = redv[0] + head_b[CV];
    __syncthreads();
    // argmax over all CV1 entries (thread 0 handles j==CV last, preserving order)
    float m = -3.4e38f; int mi = CV1;
    for (int j = tid; j < CV; j += 256) {
        float a = lg[j] + gm[j];
        if (a > m) { m = a; mi = j; }
    }
    if (tid == 0) {
        float a = nullv + gm[CV];
        if (a > m) { m = a; mi = CV; }
    }
    redv[tid] = m; redi[tid] = mi; __syncthreads();
    for (int off = 128; off > 0; off >>= 1) {
        if (tid < off) {
            float vo = redv[tid + off]; int io = redi[tid + off];
            if (vo > redv[tid] || (vo == redv[tid] && io < redi[tid])) { redv[tid] = vo; redi[tid] = io; }
        }
        __syncthreads();
    }
    m = redv[0]; int amax = redi[0];
    __syncthreads();
    float ssum = 0.f;
    for (int j = tid; j < CV; j += 256) ssum += expf(lg[j] + gm[j] - m);
    if (tid == 0) ssum += expf(nullv + gm[CV] - m);
    redv[tid] = ssum; __syncthreads();
    for (int off = 128; off > 0; off >>= 1) {
        if (tid < off) redv[tid] += redv[tid + off];
        __syncthreads();
    }
    float inv = 1.0f / redv[0];
    size_t rowbase = (size_t)bs * CV;
    int phi = (bs >> 1) & 3;
    {
        int j8 = tid * 8;   // CV/8 = 256 groups
        float vals[8];
        #pragma unroll
        for (int e = 0; e < 8; ++e) vals[e] = expf(lg[j8 + e] + gm[j8 + e] - m) * inv;
        split_store8_swz(vals, z, 0, rowbase, j8, phi, 1);
    }
    if (tid == 0) chosen[bs] = amax;
}

__global__ __launch_bounds__(256) void discretize_k(const float* __restrict__ logits,
    const float* __restrict__ gumbel, float* __restrict__ z, int* __restrict__ chosen)
{
    int bs = blockIdx.x;
    const float* lg = logits + (size_t)bs * CV1;
    const float* gm = gumbel + (size_t)bs * CV1;
    __shared__ float redv[256]; __shared__ int redi[256];
    int tid = threadIdx.x;
    float m = -3.4e38f; int mi = CV1;
    for (int j = tid; j < CV1; j += 256) {
        float a = lg[j] + gm[j];
        if (a > m) { m = a; mi = j; }
    }
    redv[tid] = m; redi[tid] = mi; __syncthreads();
    for (int off = 128; off > 0; off >>= 1) {
        if (tid < off) {
            float vo = redv[tid + off]; int io = redi[tid + off];
            if (vo > redv[tid] || (vo == redv[tid] && io < redi[tid])) { redv[tid] = vo; redi[tid] = io; }
        }
        __syncthreads();
    }
    m = redv[0]; int amax = redi[0];
    __syncthreads();
    float ssum = 0.f;
    for (int j = tid; j < CV1; j += 256) ssum += expf(lg[j] + gm[j] - m);
    redv[tid] = ssum; __syncthreads();
    for (int off = 128; off > 0; off >>= 1) {
        if (tid < off) redv[tid] += redv[tid + off];
        __syncthreads();
    }
    float inv = 1.0f / redv[0];
    for (int j = tid; j < CV; j += 256)
        z[(size_t)bs * CV + j] = expf(lg[j] + gm[j] - m) * inv;
    if (tid == 0) chosen[bs] = amax;
}

// ---------------- cea + loss (float4) ----------------
__global__ __launch_bounds__(256) void cea_k(const float* __restrict__ esoft,
    const float* __restrict__ cemb, const int* __restrict__ chosen,
    const int* __restrict__ amask, float* __restrict__ cea, float* __restrict__ partial)
{
    int bs = blockIdx.x;
    int ch = chosen[bs]; int vm = amask[bs];
    int comp = (ch != CV) && vm;
    const float4* ehr = (const float4*)(cemb + (size_t)(ch < CV - 1 ? ch : CV - 1) * H);
    const float4* esr = (const float4*)(esoft + (size_t)bs * H);
    float4* cer = (float4*)(cea + (size_t)bs * H);
    __shared__ float red[256];
    float vmf = vm ? 1.f : 0.f;
    float4 es = esr[threadIdx.x];
    float4 ehv = comp ? ehr[threadIdx.x] : make_float4(0.f, 0.f, 0.f, 0.f);
    float4 o;
    o.x = ((ehv.x + es.x) - es.x) * vmf;
    o.y = ((ehv.y + es.y) - es.y) * vmf;
    o.z = ((ehv.z + es.z) - es.z) * vmf;
    o.w = ((ehv.w + es.w) - es.w) * vmf;
    cer[threadIdx.x] = o;
    float dx = es.x - ehv.x, dy = es.y - ehv.y, dz = es.z - ehv.z, dw = es.w - ehv.w;
    float part = dx * dx + dy * dy + dz * dz + dw * dw;
    red[threadIdx.x] = part; __syncthreads();
    for (int off = 128; off > 0; off >>= 1) {
        if (threadIdx.x < off) red[threadIdx.x] += red[threadIdx.x + off];
        __syncthreads();
    }
    if (threadIdx.x == 0) partial[bs] = red[0];
}

__global__ __launch_bounds__(256) void loss_k(const float* __restrict__ partial, float* __restrict__ out)
{
    __shared__ float red[256];
    float s = 0.f;
    for (int i = threadIdx.x; i < BS; i += 256) s += partial[i];
    red[threadIdx.x] = s; __syncthreads();
    for (int off = 128; off > 0; off >>= 1) {
        if (threadIdx.x < off) red[threadIdx.x] += red[threadIdx.x + off];
        __syncthreads();
    }
    if (threadIdx.x == 0) out[0] = 1.25f * red[0] / (float)BSH;
}

// ---------------- Parallel stable pack ----------------
__global__ __launch_bounds__(1024) void pack_k(const int* __restrict__ chosen,
    const int* __restrict__ amask, int* __restrict__ order, int* __restrict__ cpos,
    int* __restrict__ cvalid, int* __restrict__ counts)
{
    int b = blockIdx.x, t = threadIdx.x;
    __shared__ int sc[1024];
    __shared__ int ord[1024];
    int f = (chosen[b * S + t] != CV && amask[b * S + t]) ? 1 : 0;
    sc[t] = f;
    __syncthreads();
    #pragma unroll
    for (int off = 1; off < 1024; off <<= 1) {
        int add = (t >= off) ? sc[t - off] : 0;
        __syncthreads();
        sc[t] += add;
        __syncthreads();
    }
    int cnt = sc[1023];
    int pos = f ? (sc[t] - 1) : (cnt + t - sc[t]);
    ord[pos] = t;
    __syncthreads();
    int o = ord[t];
    order[b * S + t] = o;
    cvalid[b * S + t] = (t < cnt) ? 1 : 0;
    cpos[b * S + t] = (t < cnt) ? o : 0;
    if (t == 0) counts[b] = cnt;
}

__global__ __launch_bounds__(256) void gather_k(const float* __restrict__ cea,
    const int* __restrict__ order, const int* __restrict__ cvalid, float* __restrict__ h)
{
    int bs = blockIdx.x;
    int b = bs >> 10;
    int src = order[bs];
    float f = cvalid[bs] ? 1.f : 0.f;
    const float4* sp = (const float4*)(cea + (size_t)(b * S + src) * H);
    float4* dst = (float4*)(h + (size_t)bs * H);
    float4 v = sp[threadIdx.x];
    dst[threadIdx.x] = make_float4(v.x * f, v.y * f, v.z * f, v.w * f);
}

__global__ __launch_bounds__(256) void outmask_k(const float* __restrict__ h,
    const int* __restrict__ cvalid, float* __restrict__ out)
{
    int bs = blockIdx.x;
    float f = cvalid[bs] ? 1.f : 0.f;
    const float4* sp = (const float4*)(h + (size_t)bs * H);
    float4* dst = (float4*)(out + (size_t)bs * H);
    float4 v = sp[threadIdx.x];
    dst[threadIdx.x] = make_float4(v.x * f, v.y * f, v.z * f, v.w * f);
}

__global__ __launch_bounds__(256) void iota_k(int* __restrict__ pos)
{
    int idx = blockIdx.x * 256 + threadIdx.x;
    if (idx < BS) pos[idx] = idx & (S - 1);
}

// ================= Host-side drivers =================
static void run_block_f32(int layer,
    const float* ln1, const float* wq, const float* wk, const float* wv,
    const float* wo, const float* ln2, const float* wg, const float* wu, const float* wd,
    float* h, float* hn, float* q, float* k, float* v, float* o, float* f1,
    const int* valid, const int* pos, hipStream_t stream)
{
    size_t LHH = (size_t)layer * H * H;
    size_t LHF = (size_t)layer * H * FF;
    rmsnorm_k<<<BS, 256, 0, stream>>>(h, ln1 + (size_t)layer * H, hn);
    gemm_k<<<dim3(16, 64), 256, 0, stream>>>(hn, wq + LHH, nullptr, q, BS, H, H, H, H, H, 0);
    gemm_k<<<dim3(16, 64), 256, 0, stream>>>(hn, wk + LHH, nullptr, k, BS, H, H, H, H, H, 0);
    gemm_k<<<dim3(16, 64), 256, 0, stream>>>(hn, wv + LHH, nullptr, v, BS, H, H, H, H, H, 0);
    rope_k<<<8192, 256, 0, stream>>>(q, pos);
    rope_k<<<8192, 256, 0, stream>>>(k, pos);
    fattn_k<<<dim3(S / 64, NH, B), 256, 0, stream>>>(q, k, v, o, valid);
    gemm_k<<<dim3(16, 64), 256, 0, stream>>>(o, wo + LHH, nullptr, h, BS, H, H, H, H, H, F_RESID);
    rmsnorm_k<<<BS, 256, 0, stream>>>(h, ln2 + (size_t)layer * H, hn);
    gemm_k<<<dim3(64, 64), 256, 0, stream>>>(hn, wg + LHF, nullptr, f1, BS, FF, H, H, FF, FF, F_SILU);
    gemm_k<<<dim3(64, 64), 256, 0, stream>>>(hn, wu + LHF, nullptr, f1, BS, FF, H, H, FF, FF, F_MULIN);
    gemm_k<<<dim3(16, 64), 256, 0, stream>>>(f1, wd + (size_t)layer * FF * H, nullptr, h, BS, H, FF, FF, H, H, F_RESID);
}

// MFMA block, templated on split planes / products (shallow <2,3>, mid <1,1>)
template<int NP, int NPROD>
static void run_block_mf(int layer,
    const float* ln1, const float* wq, const float* wk, const float* wv,
    const float* wo, const float* ln2, const float* wg, const float* wu, const float* wd,
    float* h, float* qkv,
    _Float16* hnsp, _Float16* osp, _Float16* wsp, _Float16* wsp2, _Float16* f1sp,
    _Float16* qsp, _Float16* ksp, _Float16* vtp,
    const float* ct, const float* st,
    const int* valid, const int* pos, hipStream_t stream)
{
    const size_t PH = (size_t)H * H;        // wo plane
    const size_t P3H = 3 * PH;              // fused qkv plane
    const size_t PGU = (size_t)H * FF;      // wg/wu/wd plane
    const size_t PA = BSH;                  // activation plane
    const size_t PF = BSF;                  // f1 plane
    size_t LHH = (size_t)layer * H * H;
    size_t LHF = (size_t)layer * H * FF;

    rmsnorm_split_k<<<BS, 256, 0, stream>>>(h, ln1 + (size_t)layer * H, hnsp, PA, NP);
    splitwt3_k<<<dim3(H / 64, H / 32, 3), 256, 0, stream>>>(
        wq + LHH, wk + LHH, wv + LHH, wsp, P3H, NP);
    gemm_mf_k<NP, NPROD><<<dim3(3 * H / 128, BS / 128), 256, 0, stream>>>(
        hnsp, wsp, nullptr, qkv, nullptr, BS, 3 * H, H, 3 * H, PA, P3H, 1);
    rope2_split_k<<<2048, 256, 0, stream>>>(qkv, 3 * H, pos, ct, st, qsp, ksp, PA, NP);
    splitvt_k<<<dim3(S / 64, H / 32, B), 256, 0, stream>>>(qkv, 3 * H, 2 * H, vtp, PA, NP);
    mfattn_k<NP, NPROD><<<dim3(S / 64, NH, B), 256, 0, stream>>>(qsp, ksp, vtp, osp, valid);
    splitwt_k<<<dim3(H / 64, H / 32), 256, 0, stream>>>(wo + LHH, wsp, H, H, H, PH, NP);
    gemm_mf_k<NP, NPROD><<<dim3(H / 128, BS / 128), 256, 0, stream>>>(
        osp, wsp, nullptr, h, h, BS, H, H, H, PA, PH, 1);
    rmsnorm_split_k<<<BS, 256, 0, stream>>>(h, ln2 + (size_t)layer * H, hnsp, PA, NP);
    splitwt2_k<<<dim3(FF / 64, H / 32, 2), 256, 0, stream>>>(
        wg + LHF, wu + LHF, wsp, wsp2, PGU, NP);
    gateup_k<NP, NPROD><<<dim3(FF / 128, BS / 128), 256, 0, stream>>>(
        hnsp, wsp, wsp2, f1sp, BS, FF, H, PA, PGU, PF, NP, 2);
    splitwt_k<<<dim3(H / 64, FF / 32), 256, 0, stream>>>(wd + (size_t)layer * FF * H, wsp, FF, H, H, PGU, NP);
    gemm_mf_k<NP, NPROD><<<dim3(H / 128, BS / 128), 256, 0, stream>>>(
        f1sp, wsp, nullptr, h, h, BS, H, FF, H, PF, PGU, 1);
}

extern "C" void kernel_launch(void* const* d_in, const int* in_sizes, int n_in,
                              void* d_out, int out_size, void* d_ws, size_t ws_size,
                              hipStream_t stream)
{
    const int*   ids    = (const int*)d_in[0];
    const int*   amask  = (const int*)d_in[1];
    const float* embed  = (const float*)d_in[2];
    const float* ln1    = (const float*)d_in[3];
    const float* wq     = (const float*)d_in[4];
    const float* wk     = (const float*)d_in[5];
    const float* wv     = (const float*)d_in[6];
    const float* wo     = (const float*)d_in[7];
    const float* ln2    = (const float*)d_in[8];
    const float* wg     = (const float*)d_in[9];
    const float* wu     = (const float*)d_in[10];
    const float* wd     = (const float*)d_in[11];
    const float* head_w = (const float*)d_in[12];
    const float* head_b = (const float*)d_in[13];
    const float* cemb   = (const float*)d_in[14];
    const float* gumbel = (const float*)d_in[15];
    float* out = (float*)d_out;

    const size_t MB = 1ull << 20;
    const size_t NEED = 274 * MB;

    if (ws_size >= NEED) {
        // ===== MFMA path =====
        char* base = (char*)d_ws;
        float* h   = (float*)base;                  // 16MB
        float* qkv = (float*)(base + 16 * MB);      // 48MB [BS][3072]
        _Float16* zb   = (_Float16*)(base + 64 * MB);   // 16MB [BS][CV]
        _Float16* hnsp = (_Float16*)(base + 80 * MB);   // 2 planes x 8MB
        _Float16* osp  = (_Float16*)(base + 104 * MB);
        _Float16* wsp  = (_Float16*)(base + 128 * MB);  // <=24MB weight planes
        _Float16* wsp2 = (_Float16*)(base + 152 * MB);
        _Float16* f1sp = (_Float16*)(base + 176 * MB);  // 2 planes x 32MB
        _Float16* qsp  = (_Float16*)(base + 176 * MB);  // alias f1sp (disjoint lifetime)
        _Float16* ksp  = (_Float16*)(base + 200 * MB);
        _Float16* vtp  = (_Float16*)(base + 224 * MB);
        int* meta   = (int*)(base + 272 * MB);
        int* chosen = meta;
        int* order  = meta + BS;
        int* cpos   = meta + 2 * BS;
        int* cvalid = meta + 3 * BS;
        int* counts = meta + 4 * BS;
        int* pos_sh = meta + 5 * BS;
        float* partial = (float*)(meta + 6 * BS);
        float* ct = (float*)(base + 273 * MB);          // S*32 floats (128KB)
        float* st = ct + S * 32;                        // S*32 floats
        float* logits = qkv;          // qkv dead after shallow blocks
        float* esoft  = qkv;
        float* ceab   = qkv + BSH;

        embed_k<<<BS, 256, 0, stream>>>(ids, embed, h);
        init_k<<<S * 32 / 256, 256, 0, stream>>>(ct, st, pos_sh);

        for (int L = 0; L < 2; ++L)
            run_block_mf<2, 3>(L, ln1, wq, wk, wv, wo, ln2, wg, wu, wd,
                               h, qkv, hnsp, osp, wsp, wsp2, f1sp,
                               qsp, ksp, vtp, ct, st, amask, pos_sh, stream);

        // ---- head logits: fp16 2-plane, ALL 4 products (argmax-critical) ----
        splita_swz_k<<<BS, 256, 0, stream>>>(h, hnsp, BSH, 2);
        splitwt_k<<<dim3(CV / 64, H / 32), 256, 0, stream>>>(head_w, wsp, H, CV, CV1, (size_t)CV * H, 2);
        gemm_mf_k<2, 4><<<dim3(CV / 128, BS / 128), 256, 0, stream>>>(
            hnsp, wsp, head_b, logits, nullptr, BS, CV, H, CV1, BSH, (size_t)CV * H, 1);
        discretize_h_k<<<BS, 256, 0, stream>>>(logits, h, head_w, head_b, gumbel, zb, chosen);

        // ---- e_soft = z @ cemb (fp16 1-plane) ----
        splitwt_k<<<dim3(H / 64, CV / 32), 256, 0, stream>>>(cemb, wsp, CV, H, H, (size_t)H * CV, 1);
        gemm_mf_k<1, 1><<<dim3(H / 128, BS / 128), 256, 0, stream>>>(
            zb, wsp, nullptr, esoft, nullptr, BS, H, CV, H, (size_t)BS * CV, (size_t)H * CV, 0);

        cea_k<<<BS, 256, 0, stream>>>(esoft, cemb, chosen, amask, ceab, partial);
        loss_k<<<1, 256, 0, stream>>>(partial, out + BSH);
        pack_k<<<B, 1024, 0, stream>>>(chosen, amask, order, cpos, cvalid, counts);
        gather_k<<<BS, 256, 0, stream>>>(ceab, order, cvalid, h);

        for (int L = 2; L < 4; ++L)
            run_block_mf<1, 1>(L, ln1, wq, wk, wv, wo, ln2, wg, wu, wd,
                               h, qkv, hnsp, osp, wsp, wsp2, f1sp,
                               qsp, ksp, vtp, ct, st, cvalid, cpos, stream);

        outmask_k<<<BS, 256, 0, stream>>>(h, cvalid, out);
    } else {
        // ===== fallback: fp32 path =====
        float* wsf = (float*)d_ws;
        float* h   = wsf;
        float* hn  = wsf + BSH;
        float* q   = wsf + 2 * BSH;
        float* k   = wsf + 3 * BSH;
        float* v   = wsf + 4 * BSH;
        float* o   = wsf + 5 * BSH;
        float* f1  = wsf + 6 * BSH;
        float* zbuf  = q;
        float* esoft = v;
        float* ceab  = o;
        int* meta   = (int*)(wsf + 6 * BSH + BSF);
        int* chosen = meta;
        int* order  = meta + BS;
        int* cpos   = meta + 2 * BS;
        int* cvalid = meta + 3 * BS;
        int* counts = meta + 4 * BS;
        int* pos_sh = meta + 5 * BS;
        float* partial = (float*)(meta + 6 * BS);

        embed_k<<<BS, 256, 0, stream>>>(ids, embed, h);
        iota_k<<<16, 256, 0, stream>>>(pos_sh);
        for (int L = 0; L < 2; ++L)
            run_block_f32(L, ln1, wq, wk, wv, wo, ln2, wg, wu, wd,
                          h, hn, q, k, v, o, f1, amask, pos_sh, stream);
        gemm_k<<<dim3(33, 64), 256, 0, stream>>>(h, head_w, head_b, f1, BS, CV1, H, H, CV1, CV1, F_BIAS);
        discretize_k<<<BS, 256, 0, stream>>>(f1, gumbel, zbuf, chosen);
        gemm_k<<<dim3(16, 64), 256, 0, stream>>>(zbuf, cemb, nullptr, esoft, BS, H, CV, CV, H, H, 0);
        cea_k<<<BS, 256, 0, stream>>>(esoft, cemb, chosen, amask, ceab, partial);
        loss_k<<<1, 256, 0, stream>>>(partial, out + BSH);
        pack_k<<<B, 1024, 0, stream>>>(chosen, amask, order, cpos, cvalid, counts);
        gather_k<<<BS, 256, 0, stream>>>(ceab, order, cvalid, h);
        for (int L = 2; L < 4; ++L)
            run_block_f32(L, ln1, wq, wk, wv, wo, ln2, wg, wu, wd,
                          h, hn, q, k, v, o, f1, cvalid, cpos, stream);
        outmask_k<<<BS, 256, 0, stream>>>(h, cvalid, out);
    }
}

// Round 16
// 2518.549 us; speedup vs baseline: 1.0079x; 1.0079x over previous
//
#include <hip/hip_runtime.h>
#include <hip/hip_bf16.h>
#include <cmath>

#define B 4
#define S 1024
#define H 1024
#define NH 16
#define HD 64
#define FF 4096
#define CV 2048
#define CV1 2049
#define BS (B*S)            // 4096
#define BSH ((size_t)BS*H)  // 4194304
#define BSF ((size_t)BS*FF) // 16777216

#define F_BIAS  1
#define F_RESID 2
#define F_SILU  4
#define F_MULIN 8

typedef __attribute__((ext_vector_type(8))) _Float16 f16x8;
typedef __attribute__((ext_vector_type(4))) float f32x4;

// Pre-swizzled plane write: element (row,col) stored at
// rowbase + (col&~31) + ((((col>>3)&3)^phi)<<3) + (col&7), phi=(row>>1)&3.
static __device__ inline size_t swz_idx(size_t rowbase, int col, int phi) {
    return rowbase + (size_t)(col & ~31) + ((size_t)(((col >> 3) & 3) ^ phi) << 3) + (col & 7);
}
static __device__ inline void split_store_swz(float v, _Float16* p, size_t plane,
                                              size_t rowbase, int col, int phi, int np) {
    size_t idx = swz_idx(rowbase, col, phi);
    _Float16 h0 = (_Float16)v; p[idx] = h0;
    if (np == 2) p[plane + idx] = (_Float16)(v - (float)h0);
}
// Vectorized: 8 consecutive 8-aligned cols map to one contiguous 16B slot.
static __device__ inline void split_store8_swz(const float* v, _Float16* p, size_t plane,
                                               size_t rowbase, int col8, int phi, int np) {
    size_t idx = swz_idx(rowbase, col8, phi);
    f16x8 h0;
    #pragma unroll
    for (int e = 0; e < 8; ++e) h0[e] = (_Float16)v[e];
    *(f16x8*)&p[idx] = h0;
    if (np == 2) {
        f16x8 h1;
        #pragma unroll
        for (int e = 0; e < 8; ++e) h1[e] = (_Float16)(v[e] - (float)h0[e]);
        *(f16x8*)&p[plane + idx] = h1;
    }
}

// global->LDS async DMA, 16B per lane, LDS dest = base + lane*16
static __device__ inline void gload16(const void* g, void* l) {
    __builtin_amdgcn_global_load_lds(
        (const __attribute__((address_space(1))) void*)g,
        (__attribute__((address_space(3))) void*)l, 16, 0, 0);
}

// XCD-chunk block swizzle. swz=0 none; 1=M-contig chunks; 2=N-contig chunks.
static __device__ inline void tile_coords(int swz, int& bx, int& by) {
    if (swz == 0) { bx = blockIdx.x; by = blockIdx.y; return; }
    int nbx = gridDim.x, nby = gridDim.y;
    int L = blockIdx.y * nbx + blockIdx.x;
    int cpx = (nbx * nby) >> 3;
    int cid = (L & 7) * cpx + (L >> 3);
    if (swz == 1) { by = cid / nbx; bx = cid % nbx; }
    else          { bx = cid / nby; by = cid % nby; }
}

// ============ MFMA GEMM (pass-fused, 2-phase dbuf): one barrier per K-step ============
// rvalid (prefix-contiguous row validity, nullable): if rvalid[row0]==0 the whole
// 128-row block has zero A-rows -> GEMM result is exactly +0; write bias+resid only.
template<int NP, int NPROD>
__global__ __launch_bounds__(256) void gemm_mf_k(
    const _Float16* __restrict__ A, const _Float16* __restrict__ Wt,
    const float* __restrict__ bias, float* __restrict__ C, const float* __restrict__ resid,
    int M, int N, int K, int ldc, size_t planeA, size_t planeW, int swz,
    const int* __restrict__ rvalid)
{
    __shared__ _Float16 As[2][NP][128 * 32];
    __shared__ _Float16 Bs[2][NP][128 * 32];
    const int tid = threadIdx.x;
    const int w = tid >> 6, l = tid & 63;
    const int wm = w >> 1, wn = w & 1;
    int bx, by; tile_coords(swz, bx, by);
    const int row0 = by * 128, col0 = bx * 128;
    const int rA = l >> 2;
    const int cq8 = (l & 3) * 8;
    const int PA[4] = {0, 0, 1, 1};
    const int PW[4] = {0, 1, 0, 1};
    const int lr = l & 15, q = l >> 4;

    if (rvalid && rvalid[row0] == 0) {
        // block-uniform skip: all A-rows are zeros -> result = bias + resid
        const int cw2 = l & 15, rw2 = (l >> 4) * 4;
        #pragma unroll
        for (int mi = 0; mi < 4; ++mi)
            #pragma unroll
            for (int ni = 0; ni < 4; ++ni)
                #pragma unroll
                for (int r = 0; r < 4; ++r) {
                    int gr = row0 + wm * 64 + mi * 16 + rw2 + r;
                    int gc = col0 + wn * 64 + ni * 16 + cw2;
                    size_t ci = (size_t)gr * ldc + gc;
                    float val = bias ? bias[gc] : 0.f;
                    if (resid) val += resid[ci];
                    C[ci] = val;
                }
        return;
    }

    f32x4 acc[4][4];
    #pragma unroll
    for (int i = 0; i < 4; ++i)
        #pragma unroll
        for (int j = 0; j < 4; ++j)
            #pragma unroll
            for (int r = 0; r < 4; ++r) acc[i][j][r] = 0.f;

    auto stage = [&](int bf, int k0) {
        #pragma unroll
        for (int p = 0; p < NP; ++p)
            #pragma unroll
            for (int s = 0; s < 2; ++s) {
                int rr = (w * 2 + s) * 16 + rA;
                gload16(A + (size_t)p * planeA + (size_t)(row0 + rr) * K + k0 + cq8,
                        &As[bf][p][(w * 2 + s) * 512]);
                gload16(Wt + (size_t)p * planeW + (size_t)(col0 + rr) * K + k0 + cq8,
                        &Bs[bf][p][(w * 2 + s) * 512]);
            }
    };

    stage(0, 0);
    __syncthreads();
    int cur = 0;
    for (int k0 = 0; k0 < K; k0 += 32) {
        if (k0 + 32 < K) stage(cur ^ 1, k0 + 32);
        f16x8 af[NP][4], bfv[NP][4];
        #pragma unroll
        for (int p = 0; p < NP; ++p)
            #pragma unroll
            for (int i = 0; i < 4; ++i) {
                int ra = wm * 64 + i * 16 + lr;
                af[p][i] = *(const f16x8*)&As[cur][p][ra * 32 + (q ^ ((ra >> 1) & 3)) * 8];
                int rb = wn * 64 + i * 16 + lr;
                bfv[p][i] = *(const f16x8*)&Bs[cur][p][rb * 32 + (q ^ ((rb >> 1) & 3)) * 8];
            }
        #pragma unroll
        for (int pr = 0; pr < NPROD; ++pr) {
            const int pa = PA[pr], pw = PW[pr];
            #pragma unroll
            for (int mi = 0; mi < 4; ++mi)
                #pragma unroll
                for (int ni = 0; ni < 4; ++ni)
                    acc[mi][ni] = __builtin_amdgcn_mfma_f32_16x16x32_f16(
                        af[pa][mi], bfv[pw][ni], acc[mi][ni], 0, 0, 0);
        }
        __syncthreads();
        cur ^= 1;
    }
    const int cw = l & 15, rw = (l >> 4) * 4;
    #pragma unroll
    for (int mi = 0; mi < 4; ++mi)
        #pragma unroll
        for (int ni = 0; ni < 4; ++ni)
            #pragma unroll
            for (int r = 0; r < 4; ++r) {
                int gr = row0 + wm * 64 + mi * 16 + rw + r;
                int gc = col0 + wn * 64 + ni * 16 + cw;
                size_t ci = (size_t)gr * ldc + gc;
                float val = acc[mi][ni][r];
                if (bias)  val += bias[gc];
                if (resid) val += resid[ci];
                C[ci] = val;
            }
}

// ============ Fused gate-up: F = silu(A@Wg)*(A@Wu) -> pre-swz split planes ============
// NP=2 (shallow): single-buffer straight-line (144 VGPR). NP=1 (mid): 2-phase dbuf.
// rvalid skip: zero A-rows -> silu(0)*0 = +0 -> write zero planes.
template<int NP, int NPROD>
__global__ __launch_bounds__(256) void gateup_k(
    const _Float16* __restrict__ A, const _Float16* __restrict__ Wg, const _Float16* __restrict__ Wu,
    _Float16* __restrict__ F, int M, int N, int K,
    size_t planeA, size_t planeW, size_t planeF, int npOut, int swz,
    const int* __restrict__ rvalid)
{
    const int tid = threadIdx.x;
    const int w = tid >> 6, l = tid & 63;
    const int wm = w >> 1, wn = w & 1;
    int bx, by; tile_coords(swz, bx, by);
    const int row0 = by * 128, col0 = bx * 128;
    const int rA = l >> 2;
    const int cq8 = (l & 3) * 8;
    const int PA[4] = {0, 0, 1, 1};
    const int PW[4] = {0, 1, 0, 1};
    const int lr = l & 15, q = l >> 4;

    if (rvalid && rvalid[row0] == 0) {
        const int cw2 = l & 15, rw2 = (l >> 4) * 4;
        #pragma unroll
        for (int mi = 0; mi < 4; ++mi)
            #pragma unroll
            for (int ni = 0; ni < 4; ++ni)
                #pragma unroll
                for (int r = 0; r < 4; ++r) {
                    int gr = row0 + wm * 64 + mi * 16 + rw2 + r;
                    int gc = col0 + wn * 64 + ni * 16 + cw2;
                    split_store_swz(0.f, F, planeF, (size_t)gr * N, gc, (gr >> 1) & 3, npOut);
                }
        return;
    }

    f32x4 accg[4][4], accu[4][4];
    #pragma unroll
    for (int i = 0; i < 4; ++i)
        #pragma unroll
        for (int j = 0; j < 4; ++j)
            #pragma unroll
            for (int r = 0; r < 4; ++r) { accg[i][j][r] = 0.f; accu[i][j][r] = 0.f; }

    if constexpr (NP == 2) {
        __shared__ _Float16 As[NP][128 * 32];
        __shared__ _Float16 Bg[NP][128 * 32];
        __shared__ _Float16 Bu[NP][128 * 32];
        for (int k0 = 0; k0 < K; k0 += 32) {
            __syncthreads();
            #pragma unroll
            for (int p = 0; p < NP; ++p)
                #pragma unroll
                for (int s = 0; s < 2; ++s) {
                    int rr = (w * 2 + s) * 16 + rA;
                    gload16(A  + (size_t)p * planeA + (size_t)(row0 + rr) * K + k0 + cq8,
                            &As[p][(w * 2 + s) * 512]);
                    gload16(Wg + (size_t)p * planeW + (size_t)(col0 + rr) * K + k0 + cq8,
                            &Bg[p][(w * 2 + s) * 512]);
                    gload16(Wu + (size_t)p * planeW + (size_t)(col0 + rr) * K + k0 + cq8,
                            &Bu[p][(w * 2 + s) * 512]);
                }
            __syncthreads();
            f16x8 af[NP][4];
            #pragma unroll
            for (int p = 0; p < NP; ++p)
                #pragma unroll
                for (int i = 0; i < 4; ++i) {
                    int ra = wm * 64 + i * 16 + lr;
                    af[p][i] = *(const f16x8*)&As[p][ra * 32 + (q ^ ((ra >> 1) & 3)) * 8];
                }
            #pragma unroll
            for (int pr = 0; pr < NPROD; ++pr) {
                const int pa = PA[pr], pw = PW[pr];
                f16x8 bg[4], bu[4];
                #pragma unroll
                for (int i = 0; i < 4; ++i) {
                    int rb = wn * 64 + i * 16 + lr;
                    int sb = (q ^ ((rb >> 1) & 3)) * 8;
                    bg[i] = *(const f16x8*)&Bg[pw][rb * 32 + sb];
                    bu[i] = *(const f16x8*)&Bu[pw][rb * 32 + sb];
                }
                #pragma unroll
                for (int mi = 0; mi < 4; ++mi)
                    #pragma unroll
                    for (int ni = 0; ni < 4; ++ni) {
                        accg[mi][ni] = __builtin_amdgcn_mfma_f32_16x16x32_f16(
                            af[pa][mi], bg[ni], accg[mi][ni], 0, 0, 0);
                        accu[mi][ni] = __builtin_amdgcn_mfma_f32_16x16x32_f16(
                            af[pa][mi], bu[ni], accu[mi][ni], 0, 0, 0);
                    }
            }
        }
    } else {
        __shared__ _Float16 As[2][128 * 32];
        __shared__ _Float16 Bg[2][128 * 32];
        __shared__ _Float16 Bu[2][128 * 32];
        #pragma unroll
        for (int s = 0; s < 2; ++s) {
            int rr = (w * 2 + s) * 16 + rA;
            gload16(A  + (size_t)(row0 + rr) * K + cq8, &As[0][(w * 2 + s) * 512]);
            gload16(Wg + (size_t)(col0 + rr) * K + cq8, &Bg[0][(w * 2 + s) * 512]);
            gload16(Wu + (size_t)(col0 + rr) * K + cq8, &Bu[0][(w * 2 + s) * 512]);
        }
        __syncthreads();
        int cur = 0;
        for (int k0 = 0; k0 < K; k0 += 32) {
            if (k0 + 32 < K) {
                #pragma unroll
                for (int s = 0; s < 2; ++s) {
                    int rr = (w * 2 + s) * 16 + rA;
                    gload16(A  + (size_t)(row0 + rr) * K + k0 + 32 + cq8, &As[cur ^ 1][(w * 2 + s) * 512]);
                    gload16(Wg + (size_t)(col0 + rr) * K + k0 + 32 + cq8, &Bg[cur ^ 1][(w * 2 + s) * 512]);
                    gload16(Wu + (size_t)(col0 + rr) * K + k0 + 32 + cq8, &Bu[cur ^ 1][(w * 2 + s) * 512]);
                }
            }
            f16x8 af[4], bg[4], bu[4];
            #pragma unroll
            for (int i = 0; i < 4; ++i) {
                int ra = wm * 64 + i * 16 + lr;
                af[i] = *(const f16x8*)&As[cur][ra * 32 + (q ^ ((ra >> 1) & 3)) * 8];
                int rb = wn * 64 + i * 16 + lr;
                int sb = (q ^ ((rb >> 1) & 3)) * 8;
                bg[i] = *(const f16x8*)&Bg[cur][rb * 32 + sb];
                bu[i] = *(const f16x8*)&Bu[cur][rb * 32 + sb];
            }
            #pragma unroll
            for (int mi = 0; mi < 4; ++mi)
                #pragma unroll
                for (int ni = 0; ni < 4; ++ni) {
                    accg[mi][ni] = __builtin_amdgcn_mfma_f32_16x16x32_f16(
                        af[mi], bg[ni], accg[mi][ni], 0, 0, 0);
                    accu[mi][ni] = __builtin_amdgcn_mfma_f32_16x16x32_f16(
                        af[mi], bu[ni], accu[mi][ni], 0, 0, 0);
                }
            __syncthreads();
            cur ^= 1;
        }
    }

    const int cw = l & 15, rw = (l >> 4) * 4;
    #pragma unroll
    for (int mi = 0; mi < 4; ++mi)
        #pragma unroll
        for (int ni = 0; ni < 4; ++ni)
            #pragma unroll
            for (int r = 0; r < 4; ++r) {
                int gr = row0 + wm * 64 + mi * 16 + rw + r;
                int gc = col0 + wn * 64 + ni * 16 + cw;
                float g = accg[mi][ni][r], u = accu[mi][ni][r];
                float val = g / (1.f + expf(-g)) * u;
                split_store_swz(val, F, planeF, (size_t)gr * N, gc, (gr >> 1) & 3, npOut);
            }
}

// ============ MFMA flash attention (fp16, pre-swizzled planes, gload staging) ============
// Causal tile-skip via the PREFIX property of validity: a q-tile is all-valid iff
// its LAST row is valid (uniform scalar load, no LDS flag). For all-valid tiles,
// k-tiles with kt > qt are fully masked (scores exactly -1e9, expf -> +0); skipping
// them is bit-exact. SKIPINV (mid layers only): a q-tile whose FIRST row is invalid
// is entirely invalid; its outputs feed only skipped wo rows and are outmask-zeroed,
// so writing zero planes is output-identical.
template<int NP, int NPROD, bool SKIPINV>
__global__ __launch_bounds__(256) void mfattn_k(
    const _Float16* __restrict__ qsp, const _Float16* __restrict__ ksp,
    const _Float16* __restrict__ vtp, _Float16* __restrict__ osp,
    const int* __restrict__ valid)
{
    __shared__ _Float16 KP[NP][2][64 * 32];   // K tile; reused as P planes
    __shared__ _Float16 Vt[NP][2][64 * 32];   // V^T tile
    __shared__ int kvs[64];
    const int tid = threadIdx.x;
    const int w = tid >> 6, l = tid & 63;
    const int lr = l & 15, lq = l >> 4;
    const int qt = blockIdx.x, hh = blockIdx.y, b = blockIdx.z;
    const int rT = l >> 2;
    const int cq8 = (l & 3) * 8;
    const int PA[4] = {0, 0, 1, 1};
    const int PW[4] = {0, 1, 0, 1};

    if (SKIPINV && valid[b * S + qt * 64] == 0) {
        // whole tile invalid (prefix): outputs are irrelevant downstream; write zeros
        #pragma unroll
        for (int r = 0; r < 4; ++r) {
            int qr = qt * 64 + w * 16 + lq * 4 + r;
            size_t rowbase = (size_t)(b * S + qr) * H;
            int phi = ((b * S + qr) >> 1) & 3;
            #pragma unroll
            for (int n = 0; n < 4; ++n)
                split_store_swz(0.f, osp, BSH, rowbase, hh * 64 + n * 16 + lr, phi, NP);
        }
        return;
    }

    f16x8 aq[NP][2];
    {
        const int qrowa = qt * 64 + w * 16 + lr;
        const int phiq = (qrowa >> 1) & 3;
        #pragma unroll
        for (int p = 0; p < NP; ++p)
            #pragma unroll
            for (int ks = 0; ks < 2; ++ks)
                aq[p][ks] = *(const f16x8*)(qsp + (size_t)p * BSH
                    + (size_t)(b * S + qrowa) * H + hh * 64 + ks * 32 + ((lq ^ phiq) << 3));
    }
    int qvr[4];
    #pragma unroll
    for (int r = 0; r < 4; ++r)
        qvr[r] = valid[b * S + qt * 64 + w * 16 + lq * 4 + r];

    // prefix-contiguous validity: last row valid => whole tile valid
    const int allv = valid[b * S + qt * 64 + 63];
    const int ktmax = allv ? qt : (S / 64 - 1);

    float m[4], lsum[4];
    f32x4 acco[4];
    #pragma unroll
    for (int r = 0; r < 4; ++r) { m[r] = -3.4e38f; lsum[r] = 0.f; }
    #pragma unroll
    for (int n = 0; n < 4; ++n)
        #pragma unroll
        for (int r = 0; r < 4; ++r) acco[n][r] = 0.f;

    for (int kt = 0; kt <= ktmax; ++kt) {
        __syncthreads();
        {
            const int r = w * 16 + rT;
            #pragma unroll
            for (int p = 0; p < NP; ++p)
                #pragma unroll
                for (int hf = 0; hf < 2; ++hf) {
                    gload16(ksp + (size_t)p * BSH
                            + (size_t)(b * S + kt * 64 + r) * H + hh * 64 + hf * 32 + cq8,
                            &KP[p][hf][w * 512]);
                    gload16(vtp + (size_t)p * BSH
                            + ((size_t)(hh * 64 + r) * B + b) * S + kt * 64 + hf * 32 + cq8,
                            &Vt[p][hf][w * 512]);
                }
        }
        if (tid < 64) kvs[tid] = valid[b * S + kt * 64 + tid];
        __syncthreads();

        // ---- S = Q @ K^T ----
        f32x4 accs[4];
        #pragma unroll
        for (int n = 0; n < 4; ++n)
            #pragma unroll
            for (int r = 0; r < 4; ++r) accs[n][r] = 0.f;
        #pragma unroll
        for (int pr = 0; pr < NPROD; ++pr) {
            const int pa = PA[pr], pw = PW[pr];
            #pragma unroll
            for (int ks = 0; ks < 2; ++ks)
                #pragma unroll
                for (int n = 0; n < 4; ++n) {
                    int rb = n * 16 + lr;
                    f16x8 bk = *(const f16x8*)&KP[pw][ks][rb * 32 + ((lq ^ ((rb >> 1) & 3))) * 8];
                    accs[n] = __builtin_amdgcn_mfma_f32_16x16x32_f16(
                        aq[pa][ks], bk, accs[n], 0, 0, 0);
                }
        }
        // ---- mask + online softmax ----
        float pf[4][4];
        int kva[4];
        #pragma unroll
        for (int n = 0; n < 4; ++n) kva[n] = kvs[n * 16 + lr];
        #pragma unroll
        for (int r = 0; r < 4; ++r) {
            int qr = qt * 64 + w * 16 + lq * 4 + r;
            float rowm = -3.4e38f;
            #pragma unroll
            for (int n = 0; n < 4; ++n) {
                int kc = kt * 64 + n * 16 + lr;
                float sv = accs[n][r] * 0.125f;
                int allowed = (kc <= qr) && qvr[r] && kva[n];
                if (!allowed) sv = sv + -1e9f;
                pf[n][r] = sv;
                rowm = fmaxf(rowm, sv);
            }
            rowm = fmaxf(rowm, __shfl_xor(rowm, 1));
            rowm = fmaxf(rowm, __shfl_xor(rowm, 2));
            rowm = fmaxf(rowm, __shfl_xor(rowm, 4));
            rowm = fmaxf(rowm, __shfl_xor(rowm, 8));
            float mn = fmaxf(m[r], rowm);
            float co = __expf(m[r] - mn);
            float rs = 0.f;
            #pragma unroll
            for (int n = 0; n < 4; ++n) { pf[n][r] = __expf(pf[n][r] - mn); rs += pf[n][r]; }
            rs += __shfl_xor(rs, 1);
            rs += __shfl_xor(rs, 2);
            rs += __shfl_xor(rs, 4);
            rs += __shfl_xor(rs, 8);
            lsum[r] = lsum[r] * co + rs;
            m[r] = mn;
            #pragma unroll
            for (int n = 0; n < 4; ++n) acco[n][r] *= co;
        }
        __syncthreads();
        // ---- write P (fp16 split) into KP, swizzled for a-frag reads ----
        #pragma unroll
        for (int n = 0; n < 4; ++n) {
            int col = n * 16 + lr;
            int hf = col >> 5, colh = col & 31, cq2 = colh >> 3, pos = colh & 7;
            #pragma unroll
            for (int r = 0; r < 4; ++r) {
                int rowg = w * 16 + lq * 4 + r;
                int off = rowg * 32 + (cq2 ^ ((rowg >> 1) & 3)) * 8 + pos;
                float pv = pf[n][r];
                _Float16 h0 = (_Float16)pv;
                KP[0][hf][off] = h0;
                if (NP == 2) KP[1][hf][off] = (_Float16)(pv - (float)h0);
            }
        }
        __syncthreads();
        // ---- O += P @ V ----
        #pragma unroll
        for (int pr = 0; pr < NPROD; ++pr) {
            const int pa = PA[pr], pw = PW[pr];
            #pragma unroll
            for (int ks = 0; ks < 2; ++ks) {
                int ra = w * 16 + lr;
                f16x8 ap = *(const f16x8*)&KP[pa][ks][ra * 32 + ((lq ^ ((ra >> 1) & 3))) * 8];
                #pragma unroll
                for (int n = 0; n < 4; ++n) {
                    int rb = n * 16 + lr;
                    f16x8 bv = *(const f16x8*)&Vt[pw][ks][rb * 32 + ((lq ^ ((rb >> 1) & 3))) * 8];
                    acco[n] = __builtin_amdgcn_mfma_f32_16x16x32_f16(
                        ap, bv, acco[n], 0, 0, 0);
                }
            }
        }
    }
    // ---- write O as pre-swizzled split planes ----
    #pragma unroll
    for (int r = 0; r < 4; ++r) {
        float inv = 1.0f / lsum[r];
        int qr = qt * 64 + w * 16 + lq * 4 + r;
        size_t rowbase = (size_t)(b * S + qr) * H;
        int phi = ((b * S + qr) >> 1) & 3;
        #pragma unroll
        for (int n = 0; n < 4; ++n)
            split_store_swz(acco[n][r] * inv, osp, BSH, rowbase, hh * 64 + n * 16 + lr, phi, NP);
    }
}

// ============ Init: trig table + iota positions (merged) ============
__global__ __launch_bounds__(256) void init_k(float* __restrict__ ct, float* __restrict__ st,
    int* __restrict__ pos)
{
    int idx = blockIdx.x * 256 + threadIdx.x;   // S*32 total
    if (idx < S * 32) {
        int i = idx & 31, p = idx >> 5;
        double inv = exp(-((double)(2 * i) / 64.0) * log(10000.0));
        double ang = (double)p * inv;
        ct[idx] = (float)cos(ang);
        st[idx] = (float)sin(ang);
    }
    if (idx < BS) pos[idx] = idx & (S - 1);
}

// ============ RoPE (q AND k) + fp16 split, vectorized 8-wide stores ============
__global__ __launch_bounds__(256) void rope2_split_k(const float* __restrict__ x,
    int xld, const int* __restrict__ pos,
    const float* __restrict__ ct, const float* __restrict__ st,
    _Float16* __restrict__ yq, _Float16* __restrict__ yk, size_t plane, int np)
{
    int gid = blockIdx.x * 256 + threadIdx.x;   // 2*BS*NH*4 = 524288 items
    int sel = gid >> 18;                        // BS*NH*4 = 262144 = 2^18
    int idx = gid & 262143;
    int i8 = (idx & 3) * 8;
    int head = (idx >> 2) & 15;
    int bs = idx >> 6;
    int p = pos[bs];
    const float* base = x + (size_t)bs * xld + sel * H + head * 64;
    float o1[8], o2[8];
    #pragma unroll
    for (int e = 0; e < 8; ++e) {
        float c = ct[p * 32 + i8 + e], sn = st[p * 32 + i8 + e];
        float x1 = base[i8 + e], x2 = base[32 + i8 + e];
        o1[e] = x1 * c - x2 * sn;
        o2[e] = x2 * c + x1 * sn;
    }
    _Float16* y = sel ? yk : yq;
    size_t rowbase = (size_t)bs * H;
    int phi = (bs >> 1) & 3;
    split_store8_swz(o1, y, plane, rowbase, head * 64 + i8, phi, np);
    split_store8_swz(o2, y, plane, rowbase, head * 64 + 32 + i8, phi, np);
}

// ============ V transpose + split, 64s x 32hd tile, vectorized stores ============
__global__ __launch_bounds__(256) void splitvt_k(const float* __restrict__ V,
    int vld, int voff, _Float16* __restrict__ Vt, size_t plane, int np)
{
    __shared__ float t[64][33];
    const int tid = threadIdx.x;
    const int s0 = blockIdx.x * 64;
    const int hd0 = blockIdx.y * 32;
    const int b = blockIdx.z;
    #pragma unroll
    for (int i = 0; i < 8; ++i) {
        int e = tid + i * 256;          // 0..2047
        int rr = e >> 5, cc = e & 31;   // 64 s-rows x 32 hd
        t[rr][cc] = V[(size_t)(b * S + s0 + rr) * vld + voff + hd0 + cc];
    }
    __syncthreads();
    int rn = tid >> 3, sg = (tid & 7) * 8;   // 32 hd x 8 s-groups
    int hd = hd0 + rn;
    float vals[8];
    #pragma unroll
    for (int e = 0; e < 8; ++e) vals[e] = t[sg + e][rn];
    split_store8_swz(vals, Vt, plane, ((size_t)hd * B + b) * S, s0 + sg, ((hd & 63) >> 1) & 3, np);
}

// ============ Weight transpose + split: W[K,N](srcld) -> Wt [N][K], 32k x 64n tile ============
__global__ __launch_bounds__(256) void splitwt_k(const float* __restrict__ W,
    _Float16* __restrict__ Wt, int K, int N, int srcld, size_t plane, int np)
{
    __shared__ float t[32][65];
    const int tid = threadIdx.x;
    const int n0 = blockIdx.x * 64, k0 = blockIdx.y * 32;
    #pragma unroll
    for (int i = 0; i < 8; ++i) {
        int e = tid + i * 256;
        int rk = e >> 6, cn = e & 63;
        t[rk][cn] = W[(size_t)(k0 + rk) * srcld + n0 + cn];
    }
    __syncthreads();
    int rn = tid >> 2, kg = (tid & 3) * 8;
    int nn = n0 + rn;
    float vals[8];
    #pragma unroll
    for (int e = 0; e < 8; ++e) vals[e] = t[kg + e][rn];
    split_store8_swz(vals, Wt, plane, (size_t)nn * K, k0 + kg, (nn >> 1) & 3, np);
}

// ============ 3-way merged weight split (QKV -> [3H][H] panel) ============
__global__ __launch_bounds__(256) void splitwt3_k(const float* __restrict__ W0,
    const float* __restrict__ W1, const float* __restrict__ W2,
    _Float16* __restrict__ Wt, size_t plane, int np)
{
    __shared__ float t[32][65];
    const int tid = threadIdx.x;
    const int n0 = blockIdx.x * 64, k0 = blockIdx.y * 32;
    const int z = blockIdx.z;
    const float* W = (z == 0) ? W0 : (z == 1) ? W1 : W2;
    #pragma unroll
    for (int i = 0; i < 8; ++i) {
        int e = tid + i * 256;
        int rk = e >> 6, cn = e & 63;
        t[rk][cn] = W[(size_t)(k0 + rk) * H + n0 + cn];
    }
    __syncthreads();
    int rn = tid >> 2, kg = (tid & 3) * 8;
    int nn = n0 + rn;
    int ng = z * H + nn;
    float vals[8];
    #pragma unroll
    for (int e = 0; e < 8; ++e) vals[e] = t[kg + e][rn];
    split_store8_swz(vals, Wt, plane, (size_t)ng * H, k0 + kg, (nn >> 1) & 3, np);
}

// ============ 2-way merged weight split (Wg/Wu) ============
__global__ __launch_bounds__(256) void splitwt2_k(const float* __restrict__ W0,
    const float* __restrict__ W1, _Float16* __restrict__ D0, _Float16* __restrict__ D1,
    size_t plane, int np)
{
    __shared__ float t[32][65];
    const int tid = threadIdx.x;
    const int n0 = blockIdx.x * 64, k0 = blockIdx.y * 32;
    const int z = blockIdx.z;
    const float* W = z ? W1 : W0;
    _Float16* Wt = z ? D1 : D0;
    #pragma unroll
    for (int i = 0; i < 8; ++i) {
        int e = tid + i * 256;
        int rk = e >> 6, cn = e & 63;
        t[rk][cn] = W[(size_t)(k0 + rk) * FF + n0 + cn];
    }
    __syncthreads();
    int rn = tid >> 2, kg = (tid & 3) * 8;
    int nn = n0 + rn;
    float vals[8];
    #pragma unroll
    for (int e = 0; e < 8; ++e) vals[e] = t[kg + e][rn];
    split_store8_swz(vals, Wt, plane, (size_t)nn * H, k0 + kg, (nn >> 1) & 3, np);
}

// ============ Plain fp32 -> fp16 split planes (rows of length H), vectorized ============
__global__ __launch_bounds__(256) void splita_swz_k(const float* __restrict__ x,
    _Float16* __restrict__ y, size_t plane, int np)
{
    int row = blockIdx.x;
    size_t rowbase = (size_t)row * H;
    int phi = (row >> 1) & 3;
    int tid = threadIdx.x;
    if (tid < H / 8) {
        int c0 = tid * 8;
        float vals[8];
        #pragma unroll
        for (int e = 0; e < 8; ++e) vals[e] = x[rowbase + c0 + e];
        split_store8_swz(vals, y, plane, rowbase, c0, phi, np);
    }
}

// ============ RMSNorm -> pre-swz fp16 split ============
__global__ __launch_bounds__(256) void rmsnorm_split_k(const float* __restrict__ x,
    const float* __restrict__ w, _Float16* __restrict__ y, size_t plane, int np)
{
    int row = blockIdx.x;
    const float* xr = x + (size_t)row * H;
    __shared__ float red[256];
    float s = 0.f;
    for (int i = threadIdx.x; i < H; i += 256) { float v = xr[i]; s += v * v; }
    red[threadIdx.x] = s; __syncthreads();
    for (int off = 128; off > 0; off >>= 1) {
        if (threadIdx.x < off) red[threadIdx.x] += red[threadIdx.x + off];
        __syncthreads();
    }
    float r = 1.0f / sqrtf(red[0] / (float)H + 1e-6f);
    size_t rowbase = (size_t)row * H;
    int phi = (row >> 1) & 3;
    if (threadIdx.x < H / 8) {
        int c0 = threadIdx.x * 8;
        float vals[8];
        #pragma unroll
        for (int e = 0; e < 8; ++e) vals[e] = xr[c0 + e] * r * w[c0 + e];
        split_store8_swz(vals, y, plane, rowbase, c0, phi, np);
    }
}

// ---------------- fp32 GEMM (fallback path) ----------------
__global__ __launch_bounds__(256) void gemm_k(
    const float* __restrict__ A, const float* __restrict__ Wm,
    const float* __restrict__ bias, float* __restrict__ C,
    int M, int N, int K, int lda, int ldb, int ldc, int flags)
{
    __shared__ float As[16][65];
    __shared__ float Bs[16][65];
    const int tid = threadIdx.x;
    const int tx = tid & 15, ty = tid >> 4;
    const int row0 = blockIdx.y * 64, col0 = blockIdx.x * 64;
    float acc[4][4] = {};
    for (int k0 = 0; k0 < K; k0 += 16) {
        #pragma unroll
        for (int l = 0; l < 4; ++l) {
            int e = tid + l * 256;
            int r = e >> 4, c = e & 15;
            int gr = row0 + r;
            float vv = 0.f;
            if (gr < M) vv = A[(size_t)gr * lda + (k0 + c)];
            As[c][r] = vv;
        }
        #pragma unroll
        for (int l = 0; l < 4; ++l) {
            int e = tid + l * 256;
            int r = e >> 6, c = e & 63;
            int gc = col0 + c;
            float vv = 0.f;
            if (gc < N) vv = Wm[(size_t)(k0 + r) * ldb + gc];
            Bs[r][c] = vv;
        }
        __syncthreads();
        #pragma unroll
        for (int kk = 0; kk < 16; ++kk) {
            float a[4], bb[4];
            #pragma unroll
            for (int i = 0; i < 4; ++i) a[i] = As[kk][ty * 4 + i];
            #pragma unroll
            for (int j = 0; j < 4; ++j) bb[j] = Bs[kk][tx * 4 + j];
            #pragma unroll
            for (int i = 0; i < 4; ++i)
                #pragma unroll
                for (int j = 0; j < 4; ++j)
                    acc[i][j] += a[i] * bb[j];
        }
        __syncthreads();
    }
    #pragma unroll
    for (int i = 0; i < 4; ++i) {
        int gr = row0 + ty * 4 + i;
        if (gr >= M) continue;
        #pragma unroll
        for (int j = 0; j < 4; ++j) {
            int gc = col0 + tx * 4 + j;
            if (gc >= N) continue;
            float vv = acc[i][j];
            if (flags & F_BIAS)  vv += bias[gc];
            if (flags & F_SILU)  vv = vv / (1.f + expf(-vv));
            size_t cidx = (size_t)gr * ldc + gc;
            if (flags & F_MULIN) vv *= C[cidx];
            if (flags & F_RESID) vv += C[cidx];
            C[cidx] = vv;
        }
    }
}

// ---------------- RMSNorm fp32 (fallback) ----------------
__global__ __launch_bounds__(256) void rmsnorm_k(const float* __restrict__ x,
    const float* __restrict__ w, float* __restrict__ y)
{
    int row = blockIdx.x;
    const float* xr = x + (size_t)row * H;
    float* yr = y + (size_t)row * H;
    __shared__ float red[256];
    float s = 0.f;
    for (int i = threadIdx.x; i < H; i += 256) { float v = xr[i]; s += v * v; }
    red[threadIdx.x] = s; __syncthreads();
    for (int off = 128; off > 0; off >>= 1) {
        if (threadIdx.x < off) red[threadIdx.x] += red[threadIdx.x + off];
        __syncthreads();
    }
    float r = 1.0f / sqrtf(red[0] / (float)H + 1e-6f);
    for (int i = threadIdx.x; i < H; i += 256) yr[i] = xr[i] * r * w[i];
}

// ---------------- Embed gather (float4) ----------------
__global__ __launch_bounds__(256) void embed_k(const int* __restrict__ ids,
    const float* __restrict__ emb, float* __restrict__ h)
{
    int bs = blockIdx.x;
    const float4* e = (const float4*)(emb + (size_t)ids[bs] * H);
    float4* hr = (float4*)(h + (size_t)bs * H);
    hr[threadIdx.x] = e[threadIdx.x];
}

// ---------------- RoPE fp32 in-place (fallback) ----------------
__global__ __launch_bounds__(256) void rope_k(float* __restrict__ x, const int* __restrict__ pos)
{
    int idx = blockIdx.x * 256 + threadIdx.x;
    int i = idx & 31;
    int head = (idx >> 5) & 15;
    int bs = idx >> 9;
    int p = pos[bs];
    double inv = exp(-((double)(2 * i) / 64.0) * log(10000.0));
    double ang = (double)p * inv;
    float c = (float)cos(ang), sn = (float)sin(ang);
    float* base = x + (size_t)bs * H + head * 64;
    float x1 = base[i], x2 = base[i + 32];
    base[i]      = x1 * c - x2 * sn;
    base[i + 32] = x2 * c + x1 * sn;
}

// ---------------- Flash attention fp32 (fallback) ----------------
__global__ __launch_bounds__(256) void fattn_k(const float* __restrict__ q,
    const float* __restrict__ k, const float* __restrict__ v,
    float* __restrict__ o, const int* __restrict__ valid)
{
    const int qt = blockIdx.x, hh = blockIdx.y, b = blockIdx.z;
    const int tid = threadIdx.x;
    const int tx = tid & 15, ty = tid >> 4;
    __shared__ float Qs[64][68];
    __shared__ float Ks[64][68];
    __shared__ float Vs[64][68];
    __shared__ int   kvs[64];
    const size_t hoff = (size_t)hh * HD;

    {
        int row = tid >> 2, d0 = (tid & 3) * 16;
        const float* qp = q + ((size_t)(b * S + qt * 64 + row)) * H + hoff + d0;
        float4* dst = (float4*)&Qs[row][d0];
        const float4* src = (const float4*)qp;
        #pragma unroll
        for (int e = 0; e < 4; ++e) dst[e] = src[e];
    }
    int qv[4]; int qrow_g[4];
    #pragma unroll
    for (int i = 0; i < 4; ++i) {
        qrow_g[i] = qt * 64 + ty * 4 + i;
        qv[i] = valid[b * S + qrow_g[i]];
    }
    float m[4], l[4], acc[4][4];
    #pragma unroll
    for (int i = 0; i < 4; ++i) {
        m[i] = -3.4e38f; l[i] = 0.f;
        #pragma unroll
        for (int j = 0; j < 4; ++j) acc[i][j] = 0.f;
    }

    for (int kt = 0; kt < S / 64; ++kt) {
        __syncthreads();
        {
            int row = tid >> 2, d0 = (tid & 3) * 16;
            const float* kp = k + ((size_t)(b * S + kt * 64 + row)) * H + hoff + d0;
            float4* dst = (float4*)&Ks[row][d0];
            const float4* src = (const float4*)kp;
            #pragma unroll
            for (int e = 0; e < 4; ++e) dst[e] = src[e];
        }
        {
            int kk = tid >> 2, d0 = (tid & 3) * 16;
            const float* vp = v + ((size_t)(b * S + kt * 64 + kk)) * H + hoff + d0;
            #pragma unroll
            for (int e = 0; e < 16; e += 4) {
                float4 vv = *(const float4*)(vp + e);
                Vs[d0 + e + 0][kk] = vv.x;
                Vs[d0 + e + 1][kk] = vv.y;
                Vs[d0 + e + 2][kk] = vv.z;
                Vs[d0 + e + 3][kk] = vv.w;
            }
        }
        if (tid < 64) kvs[tid] = valid[b * S + kt * 64 + tid];
        __syncthreads();

        float s4[4][4];
        #pragma unroll
        for (int i = 0; i < 4; ++i)
            #pragma unroll
            for (int j = 0; j < 4; ++j) s4[i][j] = 0.f;
        #pragma unroll
        for (int c = 0; c < 16; ++c) {
            float4 a[4], bb[4];
            #pragma unroll
            for (int i = 0; i < 4; ++i) a[i]  = ((const float4*)&Qs[ty * 4 + i][0])[c];
            #pragma unroll
            for (int j = 0; j < 4; ++j) bb[j] = ((const float4*)&Ks[tx * 4 + j][0])[c];
            #pragma unroll
            for (int i = 0; i < 4; ++i)
                #pragma unroll
                for (int j = 0; j < 4; ++j) {
                    s4[i][j] += a[i].x * bb[j].x + a[i].y * bb[j].y
                              + a[i].z * bb[j].z + a[i].w * bb[j].w;
                }
        }
        float p[4][4];
        float corr[4];
        #pragma unroll
        for (int i = 0; i < 4; ++i) {
            float rm = -3.4e38f;
            #pragma unroll
            for (int j = 0; j < 4; ++j) {
                int kc = kt * 64 + tx * 4 + j;
                float sv = s4[i][j] * 0.125f;
                int allowed = (kc <= qrow_g[i]) && qv[i] && kvs[tx * 4 + j];
                if (!allowed) sv = sv + -1e9f;
                s4[i][j] = sv;
                rm = fmaxf(rm, sv);
            }
            rm = fmaxf(rm, __shfl_xor(rm, 1));
            rm = fmaxf(rm, __shfl_xor(rm, 2));
            rm = fmaxf(rm, __shfl_xor(rm, 4));
            rm = fmaxf(rm, __shfl_xor(rm, 8));
            float mn = fmaxf(m[i], rm);
            corr[i] = expf(m[i] - mn);
            float rs = 0.f;
            #pragma unroll
            for (int j = 0; j < 4; ++j) { p[i][j] = expf(s4[i][j] - mn); rs += p[i][j]; }
            rs += __shfl_xor(rs, 1);
            rs += __shfl_xor(rs, 2);
            rs += __shfl_xor(rs, 4);
            rs += __shfl_xor(rs, 8);
            l[i] = l[i] * corr[i] + rs;
            m[i] = mn;
            #pragma unroll
            for (int j = 0; j < 4; ++j) acc[i][j] *= corr[i];
        }
        __syncthreads();
        #pragma unroll
        for (int i = 0; i < 4; ++i) {
            float4 pv4 = make_float4(p[i][0], p[i][1], p[i][2], p[i][3]);
            *(float4*)&Ks[ty * 4 + i][tx * 4] = pv4;
        }
        __syncthreads();
        #pragma unroll
        for (int c = 0; c < 16; ++c) {
            float4 a[4], bb[4];
            #pragma unroll
            for (int i = 0; i < 4; ++i) a[i]  = ((const float4*)&Ks[ty * 4 + i][0])[c];
            #pragma unroll
            for (int j = 0; j < 4; ++j) bb[j] = ((const float4*)&Vs[tx * 4 + j][0])[c];
            #pragma unroll
            for (int i = 0; i < 4; ++i)
                #pragma unroll
                for (int j = 0; j < 4; ++j) {
                    acc[i][j] += a[i].x * bb[j].x + a[i].y * bb[j].y
                               + a[i].z * bb[j].z + a[i].w * bb[j].w;
                }
        }
    }
    #pragma unroll
    for (int i = 0; i < 4; ++i) {
        float inv = 1.0f / l[i];
        float4 ov = make_float4(acc[i][0] * inv, acc[i][1] * inv,
                                acc[i][2] * inv, acc[i][3] * inv);
        *(float4*)(o + ((size_t)(b * S + qrow_g[i])) * H + hoff + tx * 4) = ov;
    }
}

// ---------------- Discretize + inline null-logit (fused headcol) ----------------
__global__ __launch_bounds__(256) void discretize_h_k(const float* __restrict__ logits,
    const float* __restrict__ h, const float* __restrict__ head_w, const float* __restrict__ head_b,
    const float* __restrict__ gumbel, _Float16* __restrict__ z, int* __restrict__ chosen)
{
    int bs = blockIdx.x;
    const float* lg = logits + (size_t)bs * CV1;
    const float* gm = gumbel + (size_t)bs * CV1;
    __shared__ float redv[256]; __shared__ int redi[256];
    int tid = threadIdx.x;
    // null logit (col CV): dot(h[bs], head_w[:,CV]) + head_b[CV]
    float ps = 0.f;
    for (int j = tid; j < H; j += 256)
        ps += h[(size_t)bs * H + j] * head_w[(size_t)j * CV1 + CV];
    redv[tid] = ps; __syncthreads();
    for (int off = 128; off > 0; off >>= 1) {
        if (tid < off) redv[tid] += redv[tid + off];
        __syncthreads();
    }
    float nullv = redv[0] + head_b[CV];
    __syncthreads();
    // argmax over all CV1 entries (thread 0 handles j==CV last, preserving order)
    float m = -3.4e38f; int mi = CV1;
    for (int j = tid; j < CV; j += 256) {
        float a = lg[j] + gm[j];
        if (a > m) { m = a; mi = j; }
    }
    if (tid == 0) {
        float a = nullv + gm[CV];
        if (a > m) { m = a; mi = CV; }
    }
    redv[tid] = m; redi[tid] = mi; __syncthreads();
    for (int off = 128; off > 0; off >>= 1) {
        if (tid < off) {
            float vo = redv[tid + off]; int io = redi[tid + off];
            if (vo > redv[tid] || (vo == redv[tid] && io < redi[tid])) { redv[tid] = vo; redi[tid] = io; }
        }
        __syncthreads();
    }
    m = redv[0]; int amax = redi[0];
    __syncthreads();
    float ssum = 0.f;
    for (int j = tid; j < CV; j += 256) ssum += expf(lg[j] + gm[j] - m);
    if (tid == 0) ssum += expf(nullv + gm[CV] - m);
    redv[tid] = ssum; __syncthreads();
    for (int off = 128; off > 0; off >>= 1) {
        if (tid < off) redv[tid] += redv[tid + off];
        __syncthreads();
    }
    float inv = 1.0f / redv[0];
    size_t rowbase = (size_t)bs * CV;
    int phi = (bs >> 1) & 3;
    {
        int j8 = tid * 8;   // CV/8 = 256 groups
        float vals[8];
        #pragma unroll
        for (int e = 0; e < 8; ++e) vals[e] = expf(lg[j8 + e] + gm[j8 + e] - m) * inv;
        split_store8_swz(vals, z, 0, rowbase, j8, phi, 1);
    }
    if (tid == 0) chosen[bs] = amax;
}

__global__ __launch_bounds__(256) void discretize_k(const float* __restrict__ logits,
    const float* __restrict__ gumbel, float* __restrict__ z, int* __restrict__ chosen)
{
    int bs = blockIdx.x;
    const float* lg = logits + (size_t)bs * CV1;
    const float* gm = gumbel + (size_t)bs * CV1;
    __shared__ float redv[256]; __shared__ int redi[256];
    int tid = threadIdx.x;
    float m = -3.4e38f; int mi = CV1;
    for (int j = tid; j < CV1; j += 256) {
        float a = lg[j] + gm[j];
        if (a > m) { m = a; mi = j; }
    }
    redv[tid] = m; redi[tid] = mi; __syncthreads();
    for (int off = 128; off > 0; off >>= 1) {
        if (tid < off) {
            float vo = redv[tid + off]; int io = redi[tid + off];
            if (vo > redv[tid] || (vo == redv[tid] && io < redi[tid])) { redv[tid] = vo; redi[tid] = io; }
        }
        __syncthreads();
    }
    m = redv[0]; int amax = redi[0];
    __syncthreads();
    float ssum = 0.f;
    for (int j = tid; j < CV1; j += 256) ssum += expf(lg[j] + gm[j] - m);
    redv[tid] = ssum; __syncthreads();
    for (int off = 128; off > 0; off >>= 1) {
        if (tid < off) redv[tid] += redv[tid + off];
        __syncthreads();
    }
    float inv = 1.0f / redv[0];
    for (int j = tid; j < CV; j += 256)
        z[(size_t)bs * CV + j] = expf(lg[j] + gm[j] - m) * inv;
    if (tid == 0) chosen[bs] = amax;
}

// ---------------- cea + loss (float4) ----------------
__global__ __launch_bounds__(256) void cea_k(const float* __restrict__ esoft,
    const float* __restrict__ cemb, const int* __restrict__ chosen,
    const int* __restrict__ amask, float* __restrict__ cea, float* __restrict__ partial)
{
    int bs = blockIdx.x;
    int ch = chosen[bs]; int vm = amask[bs];
    int comp = (ch != CV) && vm;
    const float4* ehr = (const float4*)(cemb + (size_t)(ch < CV - 1 ? ch : CV - 1) * H);
    const float4* esr = (const float4*)(esoft + (size_t)bs * H);
    float4* cer = (float4*)(cea + (size_t)bs * H);
    __shared__ float red[256];
    float vmf = vm ? 1.f : 0.f;
    float4 es = esr[threadIdx.x];
    float4 ehv = comp ? ehr[threadIdx.x] : make_float4(0.f, 0.f, 0.f, 0.f);
    float4 o;
    o.x = ((ehv.x + es.x) - es.x) * vmf;
    o.y = ((ehv.y + es.y) - es.y) * vmf;
    o.z = ((ehv.z + es.z) - es.z) * vmf;
    o.w = ((ehv.w + es.w) - es.w) * vmf;
    cer[threadIdx.x] = o;
    float dx = es.x - ehv.x, dy = es.y - ehv.y, dz = es.z - ehv.z, dw = es.w - ehv.w;
    float part = dx * dx + dy * dy + dz * dz + dw * dw;
    red[threadIdx.x] = part; __syncthreads();
    for (int off = 128; off > 0; off >>= 1) {
        if (threadIdx.x < off) red[threadIdx.x] += red[threadIdx.x + off];
        __syncthreads();
    }
    if (threadIdx.x == 0) partial[bs] = red[0];
}

__global__ __launch_bounds__(256) void loss_k(const float* __restrict__ partial, float* __restrict__ out)
{
    __shared__ float red[256];
    float s = 0.f;
    for (int i = threadIdx.x; i < BS; i += 256) s += partial[i];
    red[threadIdx.x] = s; __syncthreads();
    for (int off = 128; off > 0; off >>= 1) {
        if (threadIdx.x < off) red[threadIdx.x] += red[threadIdx.x + off];
        __syncthreads();
    }
    if (threadIdx.x == 0) out[0] = 1.25f * red[0] / (float)BSH;
}

// ---------------- Parallel stable pack ----------------
__global__ __launch_bounds__(1024) void pack_k(const int* __restrict__ chosen,
    const int* __restrict__ amask, int* __restrict__ order, int* __restrict__ cpos,
    int* __restrict__ cvalid, int* __restrict__ counts)
{
    int b = blockIdx.x, t = threadIdx.x;
    __shared__ int sc[1024];
    __shared__ int ord[1024];
    int f = (chosen[b * S + t] != CV && amask[b * S + t]) ? 1 : 0;
    sc[t] = f;
    __syncthreads();
    #pragma unroll
    for (int off = 1; off < 1024; off <<= 1) {
        int add = (t >= off) ? sc[t - off] : 0;
        __syncthreads();
        sc[t] += add;
        __syncthreads();
    }
    int cnt = sc[1023];
    int pos = f ? (sc[t] - 1) : (cnt + t - sc[t]);
    ord[pos] = t;
    __syncthreads();
    int o = ord[t];
    order[b * S + t] = o;
    cvalid[b * S + t] = (t < cnt) ? 1 : 0;
    cpos[b * S + t] = (t < cnt) ? o : 0;
    if (t == 0) counts[b] = cnt;
}

__global__ __launch_bounds__(256) void gather_k(const float* __restrict__ cea,
    const int* __restrict__ order, const int* __restrict__ cvalid, float* __restrict__ h)
{
    int bs = blockIdx.x;
    int b = bs >> 10;
    int src = order[bs];
    float f = cvalid[bs] ? 1.f : 0.f;
    const float4* sp = (const float4*)(cea + (size_t)(b * S + src) * H);
    float4* dst = (float4*)(h + (size_t)bs * H);
    float4 v = sp[threadIdx.x];
    dst[threadIdx.x] = make_float4(v.x * f, v.y * f, v.z * f, v.w * f);
}

__global__ __launch_bounds__(256) void outmask_k(const float* __restrict__ h,
    const int* __restrict__ cvalid, float* __restrict__ out)
{
    int bs = blockIdx.x;
    float f = cvalid[bs] ? 1.f : 0.f;
    const float4* sp = (const float4*)(h + (size_t)bs * H);
    float4* dst = (float4*)(out + (size_t)bs * H);
    float4 v = sp[threadIdx.x];
    dst[threadIdx.x] = make_float4(v.x * f, v.y * f, v.z * f, v.w * f);
}

__global__ __launch_bounds__(256) void iota_k(int* __restrict__ pos)
{
    int idx = blockIdx.x * 256 + threadIdx.x;
    if (idx < BS) pos[idx] = idx & (S - 1);
}

// ================= Host-side drivers =================
static void run_block_f32(int layer,
    const float* ln1, const float* wq, const float* wk, const float* wv,
    const float* wo, const float* ln2, const float* wg, const float* wu, const float* wd,
    float* h, float* hn, float* q, float* k, float* v, float* o, float* f1,
    const int* valid, const int* pos, hipStream_t stream)
{
    size_t LHH = (size_t)layer * H * H;
    size_t LHF = (size_t)layer * H * FF;
    rmsnorm_k<<<BS, 256, 0, stream>>>(h, ln1 + (size_t)layer * H, hn);
    gemm_k<<<dim3(16, 64), 256, 0, stream>>>(hn, wq + LHH, nullptr, q, BS, H, H, H, H, H, 0);
    gemm_k<<<dim3(16, 64), 256, 0, stream>>>(hn, wk + LHH, nullptr, k, BS, H, H, H, H, H, 0);
    gemm_k<<<dim3(16, 64), 256, 0, stream>>>(hn, wv + LHH, nullptr, v, BS, H, H, H, H, H, 0);
    rope_k<<<8192, 256, 0, stream>>>(q, pos);
    rope_k<<<8192, 256, 0, stream>>>(k, pos);
    fattn_k<<<dim3(S / 64, NH, B), 256, 0, stream>>>(q, k, v, o, valid);
    gemm_k<<<dim3(16, 64), 256, 0, stream>>>(o, wo + LHH, nullptr, h, BS, H, H, H, H, H, F_RESID);
    rmsnorm_k<<<BS, 256, 0, stream>>>(h, ln2 + (size_t)layer * H, hn);
    gemm_k<<<dim3(64, 64), 256, 0, stream>>>(hn, wg + LHF, nullptr, f1, BS, FF, H, H, FF, FF, F_SILU);
    gemm_k<<<dim3(64, 64), 256, 0, stream>>>(hn, wu + LHF, nullptr, f1, BS, FF, H, H, FF, FF, F_MULIN);
    gemm_k<<<dim3(16, 64), 256, 0, stream>>>(f1, wd + (size_t)layer * FF * H, nullptr, h, BS, H, FF, FF, H, H, F_RESID);
}

// MFMA block, templated on split planes / products / invalid-row skip
// (shallow <2,3,false> rvalid=nullptr; mid <1,1,true> rvalid=cvalid)
template<int NP, int NPROD, bool SKIPINV>
static void run_block_mf(int layer,
    const float* ln1, const float* wq, const float* wk, const float* wv,
    const float* wo, const float* ln2, const float* wg, const float* wu, const float* wd,
    float* h, float* qkv,
    _Float16* hnsp, _Float16* osp, _Float16* wsp, _Float16* wsp2, _Float16* f1sp,
    _Float16* qsp, _Float16* ksp, _Float16* vtp,
    const float* ct, const float* st,
    const int* valid, const int* pos, const int* rvalid, hipStream_t stream)
{
    const size_t PH = (size_t)H * H;        // wo plane
    const size_t P3H = 3 * PH;              // fused qkv plane
    const size_t PGU = (size_t)H * FF;      // wg/wu/wd plane
    const size_t PA = BSH;                  // activation plane
    const size_t PF = BSF;                  // f1 plane
    size_t LHH = (size_t)layer * H * H;
    size_t LHF = (size_t)layer * H * FF;

    rmsnorm_split_k<<<BS, 256, 0, stream>>>(h, ln1 + (size_t)layer * H, hnsp, PA, NP);
    splitwt3_k<<<dim3(H / 64, H / 32, 3), 256, 0, stream>>>(
        wq + LHH, wk + LHH, wv + LHH, wsp, P3H, NP);
    gemm_mf_k<NP, NPROD><<<dim3(3 * H / 128, BS / 128), 256, 0, stream>>>(
        hnsp, wsp, nullptr, qkv, nullptr, BS, 3 * H, H, 3 * H, PA, P3H, 1, rvalid);
    rope2_split_k<<<2048, 256, 0, stream>>>(qkv, 3 * H, pos, ct, st, qsp, ksp, PA, NP);
    splitvt_k<<<dim3(S / 64, H / 32, B), 256, 0, stream>>>(qkv, 3 * H, 2 * H, vtp, PA, NP);
    mfattn_k<NP, NPROD, SKIPINV><<<dim3(S / 64, NH, B), 256, 0, stream>>>(qsp, ksp, vtp, osp, valid);
    splitwt_k<<<dim3(H / 64, H / 32), 256, 0, stream>>>(wo + LHH, wsp, H, H, H, PH, NP);
    gemm_mf_k<NP, NPROD><<<dim3(H / 128, BS / 128), 256, 0, stream>>>(
        osp, wsp, nullptr, h, h, BS, H, H, H, PA, PH, 1, rvalid);
    rmsnorm_split_k<<<BS, 256, 0, stream>>>(h, ln2 + (size_t)layer * H, hnsp, PA, NP);
    splitwt2_k<<<dim3(FF / 64, H / 32, 2), 256, 0, stream>>>(
        wg + LHF, wu + LHF, wsp, wsp2, PGU, NP);
    gateup_k<NP, NPROD><<<dim3(FF / 128, BS / 128), 256, 0, stream>>>(
        hnsp, wsp, wsp2, f1sp, BS, FF, H, PA, PGU, PF, NP, 2, rvalid);
    splitwt_k<<<dim3(H / 64, FF / 32), 256, 0, stream>>>(wd + (size_t)layer * FF * H, wsp, FF, H, H, PGU, NP);
    gemm_mf_k<NP, NPROD><<<dim3(H / 128, BS / 128), 256, 0, stream>>>(
        f1sp, wsp, nullptr, h, h, BS, H, FF, H, PF, PGU, 1, rvalid);
}

extern "C" void kernel_launch(void* const* d_in, const int* in_sizes, int n_in,
                              void* d_out, int out_size, void* d_ws, size_t ws_size,
                              hipStream_t stream)
{
    const int*   ids    = (const int*)d_in[0];
    const int*   amask  = (const int*)d_in[1];
    const float* embed  = (const float*)d_in[2];
    const float* ln1    = (const float*)d_in[3];
    const float* wq     = (const float*)d_in[4];
    const float* wk     = (const float*)d_in[5];
    const float* wv     = (const float*)d_in[6];
    const float* wo     = (const float*)d_in[7];
    const float* ln2    = (const float*)d_in[8];
    const float* wg     = (const float*)d_in[9];
    const float* wu     = (const float*)d_in[10];
    const float* wd     = (const float*)d_in[11];
    const float* head_w = (const float*)d_in[12];
    const float* head_b = (const float*)d_in[13];
    const float* cemb   = (const float*)d_in[14];
    const float* gumbel = (const float*)d_in[15];
    float* out = (float*)d_out;

    const size_t MB = 1ull << 20;
    const size_t NEED = 274 * MB;

    if (ws_size >= NEED) {
        // ===== MFMA path =====
        char* base = (char*)d_ws;
        float* h   = (float*)base;                  // 16MB
        float* qkv = (float*)(base + 16 * MB);      // 48MB [BS][3072]
        _Float16* zb   = (_Float16*)(base + 64 * MB);   // 16MB [BS][CV]
        _Float16* hnsp = (_Float16*)(base + 80 * MB);   // 2 planes x 8MB
        _Float16* osp  = (_Float16*)(base + 104 * MB);
        _Float16* wsp  = (_Float16*)(base + 128 * MB);  // <=24MB weight planes
        _Float16* wsp2 = (_Float16*)(base + 152 * MB);
        _Float16* f1sp = (_Float16*)(base + 176 * MB);  // 2 planes x 32MB
        _Float16* qsp  = (_Float16*)(base + 176 * MB);  // alias f1sp (disjoint lifetime)
        _Float16* ksp  = (_Float16*)(base + 200 * MB);
        _Float16* vtp  = (_Float16*)(base + 224 * MB);
        int* meta   = (int*)(base + 272 * MB);
        int* chosen = meta;
        int* order  = meta + BS;
        int* cpos   = meta + 2 * BS;
        int* cvalid = meta + 3 * BS;
        int* counts = meta + 4 * BS;
        int* pos_sh = meta + 5 * BS;
        float* partial = (float*)(meta + 6 * BS);
        float* ct = (float*)(base + 273 * MB);          // S*32 floats (128KB)
        float* st = ct + S * 32;                        // S*32 floats
        float* logits = qkv;          // qkv dead after shallow blocks
        float* esoft  = qkv;
        float* ceab   = qkv + BSH;

        embed_k<<<BS, 256, 0, stream>>>(ids, embed, h);
        init_k<<<S * 32 / 256, 256, 0, stream>>>(ct, st, pos_sh);

        for (int L = 0; L < 2; ++L)
            run_block_mf<2, 3, false>(L, ln1, wq, wk, wv, wo, ln2, wg, wu, wd,
                                      h, qkv, hnsp, osp, wsp, wsp2, f1sp,
                                      qsp, ksp, vtp, ct, st, amask, pos_sh, nullptr, stream);

        // ---- head logits: fp16 2-plane, ALL 4 products (argmax-critical) ----
        splita_swz_k<<<BS, 256, 0, stream>>>(h, hnsp, BSH, 2);
        splitwt_k<<<dim3(CV / 64, H / 32), 256, 0, stream>>>(head_w, wsp, H, CV, CV1, (size_t)CV * H, 2);
        gemm_mf_k<2, 4><<<dim3(CV / 128, BS / 128), 256, 0, stream>>>(
            hnsp, wsp, head_b, logits, nullptr, BS, CV, H, CV1, BSH, (size_t)CV * H, 1, nullptr);
        discretize_h_k<<<BS, 256, 0, stream>>>(logits, h, head_w, head_b, gumbel, zb, chosen);

        // ---- e_soft = z @ cemb (fp16 1-plane) ----
        splitwt_k<<<dim3(H / 64, CV / 32), 256, 0, stream>>>(cemb, wsp, CV, H, H, (size_t)H * CV, 1);
        gemm_mf_k<1, 1><<<dim3(H / 128, BS / 128), 256, 0, stream>>>(
            zb, wsp, nullptr, esoft, nullptr, BS, H, CV, H, (size_t)BS * CV, (size_t)H * CV, 0, nullptr);

        cea_k<<<BS, 256, 0, stream>>>(esoft, cemb, chosen, amask, ceab, partial);
        loss_k<<<1, 256, 0, stream>>>(partial, out + BSH);
        pack_k<<<B, 1024, 0, stream>>>(chosen, amask, order, cpos, cvalid, counts);
        gather_k<<<BS, 256, 0, stream>>>(ceab, order, cvalid, h);

        for (int L = 2; L < 4; ++L)
            run_block_mf<1, 1, true>(L, ln1, wq, wk, wv, wo, ln2, wg, wu, wd,
                                     h, qkv, hnsp, osp, wsp, wsp2, f1sp,
                                     qsp, ksp, vtp, ct, st, cvalid, cpos, cvalid, stream);

        outmask_k<<<BS, 256, 0, stream>>>(h, cvalid, out);
    } else {
        // ===== fallback: fp32 path =====
        float* wsf = (float*)d_ws;
        float* h   = wsf;
        float* hn  = wsf + BSH;
        float* q   = wsf + 2 * BSH;
        float* k   = wsf + 3 * BSH;
        float* v   = wsf + 4 * BSH;
        float* o   = wsf + 5 * BSH;
        float* f1  = wsf + 6 * BSH;
        float* zbuf  = q;
        float* esoft = v;
        float* ceab  = o;
        int* meta   = (int*)(wsf + 6 * BSH + BSF);
        int* chosen = meta;
        int* order  = meta + BS;
        int* cpos   = meta + 2 * BS;
        int* cvalid = meta + 3 * BS;
        int* counts = meta + 4 * BS;
        int* pos_sh = meta + 5 * BS;
        float* partial = (float*)(meta + 6 * BS);

        embed_k<<<BS, 256, 0, stream>>>(ids, embed, h);
        iota_k<<<16, 256, 0, stream>>>(pos_sh);
        for (int L = 0; L < 2; ++L)
            run_block_f32(L, ln1, wq, wk, wv, wo, ln2, wg, wu, wd,
                          h, hn, q, k, v, o, f1, amask, pos_sh, stream);
        gemm_k<<<dim3(33, 64), 256, 0, stream>>>(h, head_w, head_b, f1, BS, CV1, H, H, CV1, CV1, F_BIAS);
        discretize_k<<<BS, 256, 0, stream>>>(f1, gumbel, zbuf, chosen);
        gemm_k<<<dim3(16, 64), 256, 0, stream>>>(zbuf, cemb, nullptr, esoft, BS, H, CV, CV, H, H, 0);
        cea_k<<<BS, 256, 0, stream>>>(esoft, cemb, chosen, amask, ceab, partial);
        loss_k<<<1, 256, 0, stream>>>(partial, out + BSH);
        pack_k<<<B, 1024, 0, stream>>>(chosen, amask, order, cpos, cvalid, counts);
        gather_k<<<BS, 256, 0, stream>>>(ceab, order, cvalid, h);
        for (int L = 2; L < 4; ++L)
            run_block_f32(L, ln1, wq, wk, wv, wo, ln2, wg, wu, wd,
                          h, hn, q, k, v, o, f1, cvalid, cpos, stream);
        outmask_k<<<BS, 256, 0, stream>>>(h, cvalid, out);
    }
}

// Round 17
// 2484.644 us; speedup vs baseline: 1.0217x; 1.0136x over previous
//
#include <hip/hip_runtime.h>
#include <hip/hip_bf16.h>
#include <cmath>

#define B 4
#define S 1024
#define H 1024
#define NH 16
#define HD 64
#define FF 4096
#define CV 2048
#define CV1 2049
#define BS (B*S)            // 4096
#define BSH ((size_t)BS*H)  // 4194304
#define BSF ((size_t)BS*FF) // 16777216

#define F_BIAS  1
#define F_RESID 2
#define F_SILU  4
#define F_MULIN 8

typedef __attribute__((ext_vector_type(8))) _Float16 f16x8;
typedef __attribute__((ext_vector_type(4))) float f32x4;

// Pre-swizzled plane write: element (row,col) stored at
// rowbase + (col&~31) + ((((col>>3)&3)^phi)<<3) + (col&7), phi=(row>>1)&3.
static __device__ inline size_t swz_idx(size_t rowbase, int col, int phi) {
    return rowbase + (size_t)(col & ~31) + ((size_t)(((col >> 3) & 3) ^ phi) << 3) + (col & 7);
}
static __device__ inline void split_store_swz(float v, _Float16* p, size_t plane,
                                              size_t rowbase, int col, int phi, int np) {
    size_t idx = swz_idx(rowbase, col, phi);
    _Float16 h0 = (_Float16)v; p[idx] = h0;
    if (np == 2) p[plane + idx] = (_Float16)(v - (float)h0);
}
// Vectorized: 8 consecutive 8-aligned cols map to one contiguous 16B slot.
static __device__ inline void split_store8_swz(const float* v, _Float16* p, size_t plane,
                                               size_t rowbase, int col8, int phi, int np) {
    size_t idx = swz_idx(rowbase, col8, phi);
    f16x8 h0;
    #pragma unroll
    for (int e = 0; e < 8; ++e) h0[e] = (_Float16)v[e];
    *(f16x8*)&p[idx] = h0;
    if (np == 2) {
        f16x8 h1;
        #pragma unroll
        for (int e = 0; e < 8; ++e) h1[e] = (_Float16)(v[e] - (float)h0[e]);
        *(f16x8*)&p[plane + idx] = h1;
    }
}

// global->LDS async DMA, 16B per lane, LDS dest = base + lane*16
static __device__ inline void gload16(const void* g, void* l) {
    __builtin_amdgcn_global_load_lds(
        (const __attribute__((address_space(1))) void*)g,
        (__attribute__((address_space(3))) void*)l, 16, 0, 0);
}

// XCD-chunk block swizzle. swz=0 none; 1=M-contig chunks; 2=N-contig chunks.
static __device__ inline void tile_coords(int swz, int& bx, int& by) {
    if (swz == 0) { bx = blockIdx.x; by = blockIdx.y; return; }
    int nbx = gridDim.x, nby = gridDim.y;
    int L = blockIdx.y * nbx + blockIdx.x;
    int cpx = (nbx * nby) >> 3;
    int cid = (L & 7) * cpx + (L >> 3);
    if (swz == 1) { by = cid / nbx; bx = cid % nbx; }
    else          { bx = cid / nby; by = cid % nby; }
}

// ============ MFMA GEMM (pass-fused, 2-phase dbuf): one barrier per K-step ============
// rvalid (prefix-contiguous row validity, nullable): if rvalid[row0]==0 the whole
// 128-row block has zero A-rows -> GEMM result is exactly +0; write bias+resid only.
template<int NP, int NPROD>
__global__ __launch_bounds__(256) void gemm_mf_k(
    const _Float16* __restrict__ A, const _Float16* __restrict__ Wt,
    const float* __restrict__ bias, float* __restrict__ C, const float* __restrict__ resid,
    int M, int N, int K, int ldc, size_t planeA, size_t planeW, int swz,
    const int* __restrict__ rvalid)
{
    __shared__ _Float16 As[2][NP][128 * 32];
    __shared__ _Float16 Bs[2][NP][128 * 32];
    const int tid = threadIdx.x;
    const int w = tid >> 6, l = tid & 63;
    const int wm = w >> 1, wn = w & 1;
    int bx, by; tile_coords(swz, bx, by);
    const int row0 = by * 128, col0 = bx * 128;
    const int rA = l >> 2;
    const int cq8 = (l & 3) * 8;
    const int PA[4] = {0, 0, 1, 1};
    const int PW[4] = {0, 1, 0, 1};
    const int lr = l & 15, q = l >> 4;

    if (rvalid && rvalid[row0] == 0) {
        // block-uniform skip: all A-rows are zeros -> result = bias + resid
        const int cw2 = l & 15, rw2 = (l >> 4) * 4;
        #pragma unroll
        for (int mi = 0; mi < 4; ++mi)
            #pragma unroll
            for (int ni = 0; ni < 4; ++ni)
                #pragma unroll
                for (int r = 0; r < 4; ++r) {
                    int gr = row0 + wm * 64 + mi * 16 + rw2 + r;
                    int gc = col0 + wn * 64 + ni * 16 + cw2;
                    size_t ci = (size_t)gr * ldc + gc;
                    float val = bias ? bias[gc] : 0.f;
                    if (resid) val += resid[ci];
                    C[ci] = val;
                }
        return;
    }

    f32x4 acc[4][4];
    #pragma unroll
    for (int i = 0; i < 4; ++i)
        #pragma unroll
        for (int j = 0; j < 4; ++j)
            #pragma unroll
            for (int r = 0; r < 4; ++r) acc[i][j][r] = 0.f;

    auto stage = [&](int bf, int k0) {
        #pragma unroll
        for (int p = 0; p < NP; ++p)
            #pragma unroll
            for (int s = 0; s < 2; ++s) {
                int rr = (w * 2 + s) * 16 + rA;
                gload16(A + (size_t)p * planeA + (size_t)(row0 + rr) * K + k0 + cq8,
                        &As[bf][p][(w * 2 + s) * 512]);
                gload16(Wt + (size_t)p * planeW + (size_t)(col0 + rr) * K + k0 + cq8,
                        &Bs[bf][p][(w * 2 + s) * 512]);
            }
    };

    stage(0, 0);
    __syncthreads();
    int cur = 0;
    for (int k0 = 0; k0 < K; k0 += 32) {
        if (k0 + 32 < K) stage(cur ^ 1, k0 + 32);
        f16x8 af[NP][4], bfv[NP][4];
        #pragma unroll
        for (int p = 0; p < NP; ++p)
            #pragma unroll
            for (int i = 0; i < 4; ++i) {
                int ra = wm * 64 + i * 16 + lr;
                af[p][i] = *(const f16x8*)&As[cur][p][ra * 32 + (q ^ ((ra >> 1) & 3)) * 8];
                int rb = wn * 64 + i * 16 + lr;
                bfv[p][i] = *(const f16x8*)&Bs[cur][p][rb * 32 + (q ^ ((rb >> 1) & 3)) * 8];
            }
        #pragma unroll
        for (int pr = 0; pr < NPROD; ++pr) {
            const int pa = PA[pr], pw = PW[pr];
            #pragma unroll
            for (int mi = 0; mi < 4; ++mi)
                #pragma unroll
                for (int ni = 0; ni < 4; ++ni)
                    acc[mi][ni] = __builtin_amdgcn_mfma_f32_16x16x32_f16(
                        af[pa][mi], bfv[pw][ni], acc[mi][ni], 0, 0, 0);
        }
        __syncthreads();
        cur ^= 1;
    }
    const int cw = l & 15, rw = (l >> 4) * 4;
    #pragma unroll
    for (int mi = 0; mi < 4; ++mi)
        #pragma unroll
        for (int ni = 0; ni < 4; ++ni)
            #pragma unroll
            for (int r = 0; r < 4; ++r) {
                int gr = row0 + wm * 64 + mi * 16 + rw + r;
                int gc = col0 + wn * 64 + ni * 16 + cw;
                size_t ci = (size_t)gr * ldc + gc;
                float val = acc[mi][ni][r];
                if (bias)  val += bias[gc];
                if (resid) val += resid[ci];
                C[ci] = val;
            }
}

// ============ Fused QKV GEMM + RoPE + split planes + V-transpose ============
// Same GEMM body as gemm_mf_k (N = 3H panel of [q|k|v] weights).  The epilogue
// consumes acc directly:  sel = col0>>10 (block-uniform, 128 | 1024).
//   sel<2 (q/k): rope pairs col i (i = ni*16+cw < 32 for ni in {0,1}) with
//     col i+32 (= acc[mi][ni+2]); o1/o2 stored swizzled exactly as rope2_split_k.
//   sel==2 (v): transpose-store to vtp[(c*B+b)*S + s], phi = ((c&63)>>1)&3,
//     exactly as splitvt_k.  Bit-identical: same fp32 acc, same ct/st, same
//     per-element fp16 rounding (fp32 C round-trip was lossless).
template<int NP, int NPROD>
__global__ __launch_bounds__(256) void gemmqkv_k(
    const _Float16* __restrict__ A, const _Float16* __restrict__ Wt,
    const int* __restrict__ pos, const float* __restrict__ ct, const float* __restrict__ st,
    _Float16* __restrict__ qsp, _Float16* __restrict__ ksp, _Float16* __restrict__ vtp,
    int K, size_t planeA, size_t planeW, int swz, const int* __restrict__ rvalid)
{
    __shared__ _Float16 As[2][NP][128 * 32];
    __shared__ _Float16 Bs[2][NP][128 * 32];
    const int tid = threadIdx.x;
    const int w = tid >> 6, l = tid & 63;
    const int wm = w >> 1, wn = w & 1;
    int bx, by; tile_coords(swz, bx, by);
    const int row0 = by * 128, col0 = bx * 128;
    const int rA = l >> 2;
    const int cq8 = (l & 3) * 8;
    const int PA[4] = {0, 0, 1, 1};
    const int PW[4] = {0, 1, 0, 1};
    const int lr = l & 15, q = l >> 4;
    const int sel = col0 >> 10;             // 0=q, 1=k, 2=v (block-uniform)
    const int cbase = col0 & 1023;          // within-plane column base
    const int cw = l & 15, rw = (l >> 4) * 4;

    if (rvalid && rvalid[row0] == 0) {
        // zero A-rows: gemm=0, rope(0)=0 -> write zeros to the target planes
        if (sel < 2) {
            _Float16* y = sel ? ksp : qsp;
            #pragma unroll
            for (int mi = 0; mi < 4; ++mi)
                #pragma unroll
                for (int r = 0; r < 4; ++r) {
                    int gr = row0 + wm * 64 + mi * 16 + rw + r;
                    size_t rowbase = (size_t)gr * H;
                    int phi = (gr >> 1) & 3;
                    #pragma unroll
                    for (int ni = 0; ni < 2; ++ni) {
                        int c = cbase + wn * 64 + ni * 16 + cw;
                        split_store_swz(0.f, y, BSH, rowbase, c, phi, NP);
                        split_store_swz(0.f, y, BSH, rowbase, c + 32, phi, NP);
                    }
                }
        } else {
            #pragma unroll
            for (int ni = 0; ni < 4; ++ni) {
                int c = cbase + wn * 64 + ni * 16 + cw;
                int phiv = ((c & 63) >> 1) & 3;
                #pragma unroll
                for (int mi = 0; mi < 4; ++mi)
                    #pragma unroll
                    for (int r = 0; r < 4; ++r) {
                        int gr = row0 + wm * 64 + mi * 16 + rw + r;
                        int b = gr >> 10, scol = gr & 1023;
                        split_store_swz(0.f, vtp, BSH, ((size_t)c * B + b) * S, scol, phiv, NP);
                    }
            }
        }
        return;
    }

    f32x4 acc[4][4];
    #pragma unroll
    for (int i = 0; i < 4; ++i)
        #pragma unroll
        for (int j = 0; j < 4; ++j)
            #pragma unroll
            for (int r = 0; r < 4; ++r) acc[i][j][r] = 0.f;

    auto stage = [&](int bf, int k0) {
        #pragma unroll
        for (int p = 0; p < NP; ++p)
            #pragma unroll
            for (int s = 0; s < 2; ++s) {
                int rr = (w * 2 + s) * 16 + rA;
                gload16(A + (size_t)p * planeA + (size_t)(row0 + rr) * K + k0 + cq8,
                        &As[bf][p][(w * 2 + s) * 512]);
                gload16(Wt + (size_t)p * planeW + (size_t)(col0 + rr) * K + k0 + cq8,
                        &Bs[bf][p][(w * 2 + s) * 512]);
            }
    };

    stage(0, 0);
    __syncthreads();
    int cur = 0;
    for (int k0 = 0; k0 < K; k0 += 32) {
        if (k0 + 32 < K) stage(cur ^ 1, k0 + 32);
        f16x8 af[NP][4], bfv[NP][4];
        #pragma unroll
        for (int p = 0; p < NP; ++p)
            #pragma unroll
            for (int i = 0; i < 4; ++i) {
                int ra = wm * 64 + i * 16 + lr;
                af[p][i] = *(const f16x8*)&As[cur][p][ra * 32 + (q ^ ((ra >> 1) & 3)) * 8];
                int rb = wn * 64 + i * 16 + lr;
                bfv[p][i] = *(const f16x8*)&Bs[cur][p][rb * 32 + (q ^ ((rb >> 1) & 3)) * 8];
            }
        #pragma unroll
        for (int pr = 0; pr < NPROD; ++pr) {
            const int pa = PA[pr], pw = PW[pr];
            #pragma unroll
            for (int mi = 0; mi < 4; ++mi)
                #pragma unroll
                for (int ni = 0; ni < 4; ++ni)
                    acc[mi][ni] = __builtin_amdgcn_mfma_f32_16x16x32_f16(
                        af[pa][mi], bfv[pw][ni], acc[mi][ni], 0, 0, 0);
        }
        __syncthreads();
        cur ^= 1;
    }

    if (sel < 2) {
        _Float16* y = sel ? ksp : qsp;
        #pragma unroll
        for (int mi = 0; mi < 4; ++mi)
            #pragma unroll
            for (int r = 0; r < 4; ++r) {
                int gr = row0 + wm * 64 + mi * 16 + rw + r;
                int p = pos[gr];
                size_t rowbase = (size_t)gr * H;
                int phi = (gr >> 1) & 3;
                #pragma unroll
                for (int ni = 0; ni < 2; ++ni) {
                    int i2 = ni * 16 + cw;                 // within-half rotation index, <32
                    int c = cbase + wn * 64 + i2;
                    float cc = ct[p * 32 + i2], sn = st[p * 32 + i2];
                    float x1 = acc[mi][ni][r], x2 = acc[mi][ni + 2][r];
                    split_store_swz(x1 * cc - x2 * sn, y, BSH, rowbase, c, phi, NP);
                    split_store_swz(x2 * cc + x1 * sn, y, BSH, rowbase, c + 32, phi, NP);
                }
            }
    } else {
        #pragma unroll
        for (int ni = 0; ni < 4; ++ni) {
            int c = cbase + wn * 64 + ni * 16 + cw;
            int phiv = ((c & 63) >> 1) & 3;
            #pragma unroll
            for (int mi = 0; mi < 4; ++mi)
                #pragma unroll
                for (int r = 0; r < 4; ++r) {
                    int gr = row0 + wm * 64 + mi * 16 + rw + r;
                    int b = gr >> 10, scol = gr & 1023;
                    split_store_swz(acc[mi][ni][r], vtp, BSH, ((size_t)c * B + b) * S, scol, phiv, NP);
                }
        }
    }
}

// ============ Fused gate-up: F = silu(A@Wg)*(A@Wu) -> pre-swz split planes ============
// NP=2 (shallow): single-buffer straight-line (144 VGPR). NP=1 (mid): 2-phase dbuf.
// rvalid skip: zero A-rows -> silu(0)*0 = +0 -> write zero planes.
template<int NP, int NPROD>
__global__ __launch_bounds__(256) void gateup_k(
    const _Float16* __restrict__ A, const _Float16* __restrict__ Wg, const _Float16* __restrict__ Wu,
    _Float16* __restrict__ F, int M, int N, int K,
    size_t planeA, size_t planeW, size_t planeF, int npOut, int swz,
    const int* __restrict__ rvalid)
{
    const int tid = threadIdx.x;
    const int w = tid >> 6, l = tid & 63;
    const int wm = w >> 1, wn = w & 1;
    int bx, by; tile_coords(swz, bx, by);
    const int row0 = by * 128, col0 = bx * 128;
    const int rA = l >> 2;
    const int cq8 = (l & 3) * 8;
    const int PA[4] = {0, 0, 1, 1};
    const int PW[4] = {0, 1, 0, 1};
    const int lr = l & 15, q = l >> 4;

    if (rvalid && rvalid[row0] == 0) {
        const int cw2 = l & 15, rw2 = (l >> 4) * 4;
        #pragma unroll
        for (int mi = 0; mi < 4; ++mi)
            #pragma unroll
            for (int ni = 0; ni < 4; ++ni)
                #pragma unroll
                for (int r = 0; r < 4; ++r) {
                    int gr = row0 + wm * 64 + mi * 16 + rw2 + r;
                    int gc = col0 + wn * 64 + ni * 16 + cw2;
                    split_store_swz(0.f, F, planeF, (size_t)gr * N, gc, (gr >> 1) & 3, npOut);
                }
        return;
    }

    f32x4 accg[4][4], accu[4][4];
    #pragma unroll
    for (int i = 0; i < 4; ++i)
        #pragma unroll
        for (int j = 0; j < 4; ++j)
            #pragma unroll
            for (int r = 0; r < 4; ++r) { accg[i][j][r] = 0.f; accu[i][j][r] = 0.f; }

    if constexpr (NP == 2) {
        __shared__ _Float16 As[NP][128 * 32];
        __shared__ _Float16 Bg[NP][128 * 32];
        __shared__ _Float16 Bu[NP][128 * 32];
        for (int k0 = 0; k0 < K; k0 += 32) {
            __syncthreads();
            #pragma unroll
            for (int p = 0; p < NP; ++p)
                #pragma unroll
                for (int s = 0; s < 2; ++s) {
                    int rr = (w * 2 + s) * 16 + rA;
                    gload16(A  + (size_t)p * planeA + (size_t)(row0 + rr) * K + k0 + cq8,
                            &As[p][(w * 2 + s) * 512]);
                    gload16(Wg + (size_t)p * planeW + (size_t)(col0 + rr) * K + k0 + cq8,
                            &Bg[p][(w * 2 + s) * 512]);
                    gload16(Wu + (size_t)p * planeW + (size_t)(col0 + rr) * K + k0 + cq8,
                            &Bu[p][(w * 2 + s) * 512]);
                }
            __syncthreads();
            f16x8 af[NP][4];
            #pragma unroll
            for (int p = 0; p < NP; ++p)
                #pragma unroll
                for (int i = 0; i < 4; ++i) {
                    int ra = wm * 64 + i * 16 + lr;
                    af[p][i] = *(const f16x8*)&As[p][ra * 32 + (q ^ ((ra >> 1) & 3)) * 8];
                }
            #pragma unroll
            for (int pr = 0; pr < NPROD; ++pr) {
                const int pa = PA[pr], pw = PW[pr];
                f16x8 bg[4], bu[4];
                #pragma unroll
                for (int i = 0; i < 4; ++i) {
                    int rb = wn * 64 + i * 16 + lr;
                    int sb = (q ^ ((rb >> 1) & 3)) * 8;
                    bg[i] = *(const f16x8*)&Bg[pw][rb * 32 + sb];
                    bu[i] = *(const f16x8*)&Bu[pw][rb * 32 + sb];
                }
                #pragma unroll
                for (int mi = 0; mi < 4; ++mi)
                    #pragma unroll
                    for (int ni = 0; ni < 4; ++ni) {
                        accg[mi][ni] = __builtin_amdgcn_mfma_f32_16x16x32_f16(
                            af[pa][mi], bg[ni], accg[mi][ni], 0, 0, 0);
                        accu[mi][ni] = __builtin_amdgcn_mfma_f32_16x16x32_f16(
                            af[pa][mi], bu[ni], accu[mi][ni], 0, 0, 0);
                    }
            }
        }
    } else {
        __shared__ _Float16 As[2][128 * 32];
        __shared__ _Float16 Bg[2][128 * 32];
        __shared__ _Float16 Bu[2][128 * 32];
        #pragma unroll
        for (int s = 0; s < 2; ++s) {
            int rr = (w * 2 + s) * 16 + rA;
            gload16(A  + (size_t)(row0 + rr) * K + cq8, &As[0][(w * 2 + s) * 512]);
            gload16(Wg + (size_t)(col0 + rr) * K + cq8, &Bg[0][(w * 2 + s) * 512]);
            gload16(Wu + (size_t)(col0 + rr) * K + cq8, &Bu[0][(w * 2 + s) * 512]);
        }
        __syncthreads();
        int cur = 0;
        for (int k0 = 0; k0 < K; k0 += 32) {
            if (k0 + 32 < K) {
                #pragma unroll
                for (int s = 0; s < 2; ++s) {
                    int rr = (w * 2 + s) * 16 + rA;
                    gload16(A  + (size_t)(row0 + rr) * K + k0 + 32 + cq8, &As[cur ^ 1][(w * 2 + s) * 512]);
                    gload16(Wg + (size_t)(col0 + rr) * K + k0 + 32 + cq8, &Bg[cur ^ 1][(w * 2 + s) * 512]);
                    gload16(Wu + (size_t)(col0 + rr) * K + k0 + 32 + cq8, &Bu[cur ^ 1][(w * 2 + s) * 512]);
                }
            }
            f16x8 af[4], bg[4], bu[4];
            #pragma unroll
            for (int i = 0; i < 4; ++i) {
                int ra = wm * 64 + i * 16 + lr;
                af[i] = *(const f16x8*)&As[cur][ra * 32 + (q ^ ((ra >> 1) & 3)) * 8];
                int rb = wn * 64 + i * 16 + lr;
                int sb = (q ^ ((rb >> 1) & 3)) * 8;
                bg[i] = *(const f16x8*)&Bg[cur][rb * 32 + sb];
                bu[i] = *(const f16x8*)&Bu[cur][rb * 32 + sb];
            }
            #pragma unroll
            for (int mi = 0; mi < 4; ++mi)
                #pragma unroll
                for (int ni = 0; ni < 4; ++ni) {
                    accg[mi][ni] = __builtin_amdgcn_mfma_f32_16x16x32_f16(
                        af[mi], bg[ni], accg[mi][ni], 0, 0, 0);
                    accu[mi][ni] = __builtin_amdgcn_mfma_f32_16x16x32_f16(
                        af[mi], bu[ni], accu[mi][ni], 0, 0, 0);
                }
            __syncthreads();
            cur ^= 1;
        }
    }

    const int cw = l & 15, rw = (l >> 4) * 4;
    #pragma unroll
    for (int mi = 0; mi < 4; ++mi)
        #pragma unroll
        for (int ni = 0; ni < 4; ++ni)
            #pragma unroll
            for (int r = 0; r < 4; ++r) {
                int gr = row0 + wm * 64 + mi * 16 + rw + r;
                int gc = col0 + wn * 64 + ni * 16 + cw;
                float g = accg[mi][ni][r], u = accu[mi][ni][r];
                float val = g / (1.f + expf(-g)) * u;
                split_store_swz(val, F, planeF, (size_t)gr * N, gc, (gr >> 1) & 3, npOut);
            }
}

// ============ MFMA flash attention (fp16, pre-swizzled planes, gload staging) ============
// Causal tile-skip via the PREFIX property of validity: a q-tile is all-valid iff
// its LAST row is valid (uniform scalar load, no LDS flag). For all-valid tiles,
// k-tiles with kt > qt are fully masked (scores exactly -1e9, expf -> +0); skipping
// them is bit-exact. SKIPINV (mid layers only): a q-tile whose FIRST row is invalid
// is entirely invalid; its outputs feed only skipped wo rows and are outmask-zeroed,
// so writing zero planes is output-identical.
template<int NP, int NPROD, bool SKIPINV>
__global__ __launch_bounds__(256) void mfattn_k(
    const _Float16* __restrict__ qsp, const _Float16* __restrict__ ksp,
    const _Float16* __restrict__ vtp, _Float16* __restrict__ osp,
    const int* __restrict__ valid)
{
    __shared__ _Float16 KP[NP][2][64 * 32];   // K tile; reused as P planes
    __shared__ _Float16 Vt[NP][2][64 * 32];   // V^T tile
    __shared__ int kvs[64];
    const int tid = threadIdx.x;
    const int w = tid >> 6, l = tid & 63;
    const int lr = l & 15, lq = l >> 4;
    const int qt = blockIdx.x, hh = blockIdx.y, b = blockIdx.z;
    const int rT = l >> 2;
    const int cq8 = (l & 3) * 8;
    const int PA[4] = {0, 0, 1, 1};
    const int PW[4] = {0, 1, 0, 1};

    if (SKIPINV && valid[b * S + qt * 64] == 0) {
        // whole tile invalid (prefix): outputs are irrelevant downstream; write zeros
        #pragma unroll
        for (int r = 0; r < 4; ++r) {
            int qr = qt * 64 + w * 16 + lq * 4 + r;
            size_t rowbase = (size_t)(b * S + qr) * H;
            int phi = ((b * S + qr) >> 1) & 3;
            #pragma unroll
            for (int n = 0; n < 4; ++n)
                split_store_swz(0.f, osp, BSH, rowbase, hh * 64 + n * 16 + lr, phi, NP);
        }
        return;
    }

    f16x8 aq[NP][2];
    {
        const int qrowa = qt * 64 + w * 16 + lr;
        const int phiq = (qrowa >> 1) & 3;
        #pragma unroll
        for (int p = 0; p < NP; ++p)
            #pragma unroll
            for (int ks = 0; ks < 2; ++ks)
                aq[p][ks] = *(const f16x8*)(qsp + (size_t)p * BSH
                    + (size_t)(b * S + qrowa) * H + hh * 64 + ks * 32 + ((lq ^ phiq) << 3));
    }
    int qvr[4];
    #pragma unroll
    for (int r = 0; r < 4; ++r)
        qvr[r] = valid[b * S + qt * 64 + w * 16 + lq * 4 + r];

    // prefix-contiguous validity: last row valid => whole tile valid
    const int allv = valid[b * S + qt * 64 + 63];
    const int ktmax = allv ? qt : (S / 64 - 1);

    float m[4], lsum[4];
    f32x4 acco[4];
    #pragma unroll
    for (int r = 0; r < 4; ++r) { m[r] = -3.4e38f; lsum[r] = 0.f; }
    #pragma unroll
    for (int n = 0; n < 4; ++n)
        #pragma unroll
        for (int r = 0; r < 4; ++r) acco[n][r] = 0.f;

    for (int kt = 0; kt <= ktmax; ++kt) {
        __syncthreads();
        {
            const int r = w * 16 + rT;
            #pragma unroll
            for (int p = 0; p < NP; ++p)
                #pragma unroll
                for (int hf = 0; hf < 2; ++hf) {
                    gload16(ksp + (size_t)p * BSH
                            + (size_t)(b * S + kt * 64 + r) * H + hh * 64 + hf * 32 + cq8,
                            &KP[p][hf][w * 512]);
                    gload16(vtp + (size_t)p * BSH
                            + ((size_t)(hh * 64 + r) * B + b) * S + kt * 64 + hf * 32 + cq8,
                            &Vt[p][hf][w * 512]);
                }
        }
        if (tid < 64) kvs[tid] = valid[b * S + kt * 64 + tid];
        __syncthreads();

        // ---- S = Q @ K^T ----
        f32x4 accs[4];
        #pragma unroll
        for (int n = 0; n < 4; ++n)
            #pragma unroll
            for (int r = 0; r < 4; ++r) accs[n][r] = 0.f;
        #pragma unroll
        for (int pr = 0; pr < NPROD; ++pr) {
            const int pa = PA[pr], pw = PW[pr];
            #pragma unroll
            for (int ks = 0; ks < 2; ++ks)
                #pragma unroll
                for (int n = 0; n < 4; ++n) {
                    int rb = n * 16 + lr;
                    f16x8 bk = *(const f16x8*)&KP[pw][ks][rb * 32 + ((lq ^ ((rb >> 1) & 3))) * 8];
                    accs[n] = __builtin_amdgcn_mfma_f32_16x16x32_f16(
                        aq[pa][ks], bk, accs[n], 0, 0, 0);
                }
        }
        // ---- mask + online softmax ----
        float pf[4][4];
        int kva[4];
        #pragma unroll
        for (int n = 0; n < 4; ++n) kva[n] = kvs[n * 16 + lr];
        #pragma unroll
        for (int r = 0; r < 4; ++r) {
            int qr = qt * 64 + w * 16 + lq * 4 + r;
            float rowm = -3.4e38f;
            #pragma unroll
            for (int n = 0; n < 4; ++n) {
                int kc = kt * 64 + n * 16 + lr;
                float sv = accs[n][r] * 0.125f;
                int allowed = (kc <= qr) && qvr[r] && kva[n];
                if (!allowed) sv = sv + -1e9f;
                pf[n][r] = sv;
                rowm = fmaxf(rowm, sv);
            }
            rowm = fmaxf(rowm, __shfl_xor(rowm, 1));
            rowm = fmaxf(rowm, __shfl_xor(rowm, 2));
            rowm = fmaxf(rowm, __shfl_xor(rowm, 4));
            rowm = fmaxf(rowm, __shfl_xor(rowm, 8));
            float mn = fmaxf(m[r], rowm);
            float co = __expf(m[r] - mn);
            float rs = 0.f;
            #pragma unroll
            for (int n = 0; n < 4; ++n) { pf[n][r] = __expf(pf[n][r] - mn); rs += pf[n][r]; }
            rs += __shfl_xor(rs, 1);
            rs += __shfl_xor(rs, 2);
            rs += __shfl_xor(rs, 4);
            rs += __shfl_xor(rs, 8);
            lsum[r] = lsum[r] * co + rs;
            m[r] = mn;
            #pragma unroll
            for (int n = 0; n < 4; ++n) acco[n][r] *= co;
        }
        __syncthreads();
        // ---- write P (fp16 split) into KP, swizzled for a-frag reads ----
        #pragma unroll
        for (int n = 0; n < 4; ++n) {
            int col = n * 16 + lr;
            int hf = col >> 5, colh = col & 31, cq2 = colh >> 3, pos = colh & 7;
            #pragma unroll
            for (int r = 0; r < 4; ++r) {
                int rowg = w * 16 + lq * 4 + r;
                int off = rowg * 32 + (cq2 ^ ((rowg >> 1) & 3)) * 8 + pos;
                float pv = pf[n][r];
                _Float16 h0 = (_Float16)pv;
                KP[0][hf][off] = h0;
                if (NP == 2) KP[1][hf][off] = (_Float16)(pv - (float)h0);
            }
        }
        __syncthreads();
        // ---- O += P @ V ----
        #pragma unroll
        for (int pr = 0; pr < NPROD; ++pr) {
            const int pa = PA[pr], pw = PW[pr];
            #pragma unroll
            for (int ks = 0; ks < 2; ++ks) {
                int ra = w * 16 + lr;
                f16x8 ap = *(const f16x8*)&KP[pa][ks][ra * 32 + ((lq ^ ((ra >> 1) & 3))) * 8];
                #pragma unroll
                for (int n = 0; n < 4; ++n) {
                    int rb = n * 16 + lr;
                    f16x8 bv = *(const f16x8*)&Vt[pw][ks][rb * 32 + ((lq ^ ((rb >> 1) & 3))) * 8];
                    acco[n] = __builtin_amdgcn_mfma_f32_16x16x32_f16(
                        ap, bv, acco[n], 0, 0, 0);
                }
            }
        }
    }
    // ---- write O as pre-swizzled split planes ----
    #pragma unroll
    for (int r = 0; r < 4; ++r) {
        float inv = 1.0f / lsum[r];
        int qr = qt * 64 + w * 16 + lq * 4 + r;
        size_t rowbase = (size_t)(b * S + qr) * H;
        int phi = ((b * S + qr) >> 1) & 3;
        #pragma unroll
        for (int n = 0; n < 4; ++n)
            split_store_swz(acco[n][r] * inv, osp, BSH, rowbase, hh * 64 + n * 16 + lr, phi, NP);
    }
}

// ============ Init: trig table + iota positions (merged) ============
__global__ __launch_bounds__(256) void init_k(float* __restrict__ ct, float* __restrict__ st,
    int* __restrict__ pos)
{
    int idx = blockIdx.x * 256 + threadIdx.x;   // S*32 total
    if (idx < S * 32) {
        int i = idx & 31, p = idx >> 5;
        double inv = exp(-((double)(2 * i) / 64.0) * log(10000.0));
        double ang = (double)p * inv;
        ct[idx] = (float)cos(ang);
        st[idx] = (float)sin(ang);
    }
    if (idx < BS) pos[idx] = idx & (S - 1);
}

// ============ RoPE (q AND k) + fp16 split, vectorized 8-wide stores ============
// (unused in MF path since the qkv fusion; kept for reference/fallback safety)
__global__ __launch_bounds__(256) void rope2_split_k(const float* __restrict__ x,
    int xld, const int* __restrict__ pos,
    const float* __restrict__ ct, const float* __restrict__ st,
    _Float16* __restrict__ yq, _Float16* __restrict__ yk, size_t plane, int np)
{
    int gid = blockIdx.x * 256 + threadIdx.x;   // 2*BS*NH*4 = 524288 items
    int sel = gid >> 18;                        // BS*NH*4 = 262144 = 2^18
    int idx = gid & 262143;
    int i8 = (idx & 3) * 8;
    int head = (idx >> 2) & 15;
    int bs = idx >> 6;
    int p = pos[bs];
    const float* base = x + (size_t)bs * xld + sel * H + head * 64;
    float o1[8], o2[8];
    #pragma unroll
    for (int e = 0; e < 8; ++e) {
        float c = ct[p * 32 + i8 + e], sn = st[p * 32 + i8 + e];
        float x1 = base[i8 + e], x2 = base[32 + i8 + e];
        o1[e] = x1 * c - x2 * sn;
        o2[e] = x2 * c + x1 * sn;
    }
    _Float16* y = sel ? yk : yq;
    size_t rowbase = (size_t)bs * H;
    int phi = (bs >> 1) & 3;
    split_store8_swz(o1, y, plane, rowbase, head * 64 + i8, phi, np);
    split_store8_swz(o2, y, plane, rowbase, head * 64 + 32 + i8, phi, np);
}

// ============ V transpose + split, 64s x 32hd tile, vectorized stores ============
// (unused in MF path since the qkv fusion)
__global__ __launch_bounds__(256) void splitvt_k(const float* __restrict__ V,
    int vld, int voff, _Float16* __restrict__ Vt, size_t plane, int np)
{
    __shared__ float t[64][33];
    const int tid = threadIdx.x;
    const int s0 = blockIdx.x * 64;
    const int hd0 = blockIdx.y * 32;
    const int b = blockIdx.z;
    #pragma unroll
    for (int i = 0; i < 8; ++i) {
        int e = tid + i * 256;          // 0..2047
        int rr = e >> 5, cc = e & 31;   // 64 s-rows x 32 hd
        t[rr][cc] = V[(size_t)(b * S + s0 + rr) * vld + voff + hd0 + cc];
    }
    __syncthreads();
    int rn = tid >> 3, sg = (tid & 7) * 8;   // 32 hd x 8 s-groups
    int hd = hd0 + rn;
    float vals[8];
    #pragma unroll
    for (int e = 0; e < 8; ++e) vals[e] = t[sg + e][rn];
    split_store8_swz(vals, Vt, plane, ((size_t)hd * B + b) * S, s0 + sg, ((hd & 63) >> 1) & 3, np);
}

// ============ Weight transpose + split: W[K,N](srcld) -> Wt [N][K], 32k x 64n tile ============
__global__ __launch_bounds__(256) void splitwt_k(const float* __restrict__ W,
    _Float16* __restrict__ Wt, int K, int N, int srcld, size_t plane, int np)
{
    __shared__ float t[32][65];
    const int tid = threadIdx.x;
    const int n0 = blockIdx.x * 64, k0 = blockIdx.y * 32;
    #pragma unroll
    for (int i = 0; i < 8; ++i) {
        int e = tid + i * 256;
        int rk = e >> 6, cn = e & 63;
        t[rk][cn] = W[(size_t)(k0 + rk) * srcld + n0 + cn];
    }
    __syncthreads();
    int rn = tid >> 2, kg = (tid & 3) * 8;
    int nn = n0 + rn;
    float vals[8];
    #pragma unroll
    for (int e = 0; e < 8; ++e) vals[e] = t[kg + e][rn];
    split_store8_swz(vals, Wt, plane, (size_t)nn * K, k0 + kg, (nn >> 1) & 3, np);
}

// ============ 3-way merged weight split (QKV -> [3H][H] panel) ============
__global__ __launch_bounds__(256) void splitwt3_k(const float* __restrict__ W0,
    const float* __restrict__ W1, const float* __restrict__ W2,
    _Float16* __restrict__ Wt, size_t plane, int np)
{
    __shared__ float t[32][65];
    const int tid = threadIdx.x;
    const int n0 = blockIdx.x * 64, k0 = blockIdx.y * 32;
    const int z = blockIdx.z;
    const float* W = (z == 0) ? W0 : (z == 1) ? W1 : W2;
    #pragma unroll
    for (int i = 0; i < 8; ++i) {
        int e = tid + i * 256;
        int rk = e >> 6, cn = e & 63;
        t[rk][cn] = W[(size_t)(k0 + rk) * H + n0 + cn];
    }
    __syncthreads();
    int rn = tid >> 2, kg = (tid & 3) * 8;
    int nn = n0 + rn;
    int ng = z * H + nn;
    float vals[8];
    #pragma unroll
    for (int e = 0; e < 8; ++e) vals[e] = t[kg + e][rn];
    split_store8_swz(vals, Wt, plane, (size_t)ng * H, k0 + kg, (nn >> 1) & 3, np);
}

// ============ 2-way merged weight split (Wg/Wu) ============
__global__ __launch_bounds__(256) void splitwt2_k(const float* __restrict__ W0,
    const float* __restrict__ W1, _Float16* __restrict__ D0, _Float16* __restrict__ D1,
    size_t plane, int np)
{
    __shared__ float t[32][65];
    const int tid = threadIdx.x;
    const int n0 = blockIdx.x * 64, k0 = blockIdx.y * 32;
    const int z = blockIdx.z;
    const float* W = z ? W1 : W0;
    _Float16* Wt = z ? D1 : D0;
    #pragma unroll
    for (int i = 0; i < 8; ++i) {
        int e = tid + i * 256;
        int rk = e >> 6, cn = e & 63;
        t[rk][cn] = W[(size_t)(k0 + rk) * FF + n0 + cn];
    }
    __syncthreads();
    int rn = tid >> 2, kg = (tid & 3) * 8;
    int nn = n0 + rn;
    float vals[8];
    #pragma unroll
    for (int e = 0; e < 8; ++e) vals[e] = t[kg + e][rn];
    split_store8_swz(vals, Wt, plane, (size_t)nn * H, k0 + kg, (nn >> 1) & 3, np);
}

// ============ Plain fp32 -> fp16 split planes (rows of length H), vectorized ============
__global__ __launch_bounds__(256) void splita_swz_k(const float* __restrict__ x,
    _Float16* __restrict__ y, size_t plane, int np)
{
    int row = blockIdx.x;
    size_t rowbase = (size_t)row * H;
    int phi = (row >> 1) & 3;
    int tid = threadIdx.x;
    if (tid < H / 8) {
        int c0 = tid * 8;
        float vals[8];
        #pragma unroll
        for (int e = 0; e < 8; ++e) vals[e] = x[rowbase + c0 + e];
        split_store8_swz(vals, y, plane, rowbase, c0, phi, np);
    }
}

// ============ RMSNorm -> pre-swz fp16 split ============
__global__ __launch_bounds__(256) void rmsnorm_split_k(const float* __restrict__ x,
    const float* __restrict__ w, _Float16* __restrict__ y, size_t plane, int np)
{
    int row = blockIdx.x;
    const float* xr = x + (size_t)row * H;
    __shared__ float red[256];
    float s = 0.f;
    for (int i = threadIdx.x; i < H; i += 256) { float v = xr[i]; s += v * v; }
    red[threadIdx.x] = s; __syncthreads();
    for (int off = 128; off > 0; off >>= 1) {
        if (threadIdx.x < off) red[threadIdx.x] += red[threadIdx.x + off];
        __syncthreads();
    }
    float r = 1.0f / sqrtf(red[0] / (float)H + 1e-6f);
    size_t rowbase = (size_t)row * H;
    int phi = (row >> 1) & 3;
    if (threadIdx.x < H / 8) {
        int c0 = threadIdx.x * 8;
        float vals[8];
        #pragma unroll
        for (int e = 0; e < 8; ++e) vals[e] = xr[c0 + e] * r * w[c0 + e];
        split_store8_swz(vals, y, plane, rowbase, c0, phi, np);
    }
}

// ---------------- fp32 GEMM (fallback path) ----------------
__global__ __launch_bounds__(256) void gemm_k(
    const float* __restrict__ A, const float* __restrict__ Wm,
    const float* __restrict__ bias, float* __restrict__ C,
    int M, int N, int K, int lda, int ldb, int ldc, int flags)
{
    __shared__ float As[16][65];
    __shared__ float Bs[16][65];
    const int tid = threadIdx.x;
    const int tx = tid & 15, ty = tid >> 4;
    const int row0 = blockIdx.y * 64, col0 = blockIdx.x * 64;
    float acc[4][4] = {};
    for (int k0 = 0; k0 < K; k0 += 16) {
        #pragma unroll
        for (int l = 0; l < 4; ++l) {
            int e = tid + l * 256;
            int r = e >> 4, c = e & 15;
            int gr = row0 + r;
            float vv = 0.f;
            if (gr < M) vv = A[(size_t)gr * lda + (k0 + c)];
            As[c][r] = vv;
        }
        #pragma unroll
        for (int l = 0; l < 4; ++l) {
            int e = tid + l * 256;
            int r = e >> 6, c = e & 63;
            int gc = col0 + c;
            float vv = 0.f;
            if (gc < N) vv = Wm[(size_t)(k0 + r) * ldb + gc];
            Bs[r][c] = vv;
        }
        __syncthreads();
        #pragma unroll
        for (int kk = 0; kk < 16; ++kk) {
            float a[4], bb[4];
            #pragma unroll
            for (int i = 0; i < 4; ++i) a[i] = As[kk][ty * 4 + i];
            #pragma unroll
            for (int j = 0; j < 4; ++j) bb[j] = Bs[kk][tx * 4 + j];
            #pragma unroll
            for (int i = 0; i < 4; ++i)
                #pragma unroll
                for (int j = 0; j < 4; ++j)
                    acc[i][j] += a[i] * bb[j];
        }
        __syncthreads();
    }
    #pragma unroll
    for (int i = 0; i < 4; ++i) {
        int gr = row0 + ty * 4 + i;
        if (gr >= M) continue;
        #pragma unroll
        for (int j = 0; j < 4; ++j) {
            int gc = col0 + tx * 4 + j;
            if (gc >= N) continue;
            float vv = acc[i][j];
            if (flags & F_BIAS)  vv += bias[gc];
            if (flags & F_SILU)  vv = vv / (1.f + expf(-vv));
            size_t cidx = (size_t)gr * ldc + gc;
            if (flags & F_MULIN) vv *= C[cidx];
            if (flags & F_RESID) vv += C[cidx];
            C[cidx] = vv;
        }
    }
}

// ---------------- RMSNorm fp32 (fallback) ----------------
__global__ __launch_bounds__(256) void rmsnorm_k(const float* __restrict__ x,
    const float* __restrict__ w, float* __restrict__ y)
{
    int row = blockIdx.x;
    const float* xr = x + (size_t)row * H;
    float* yr = y + (size_t)row * H;
    __shared__ float red[256];
    float s = 0.f;
    for (int i = threadIdx.x; i < H; i += 256) { float v = xr[i]; s += v * v; }
    red[threadIdx.x] = s; __syncthreads();
    for (int off = 128; off > 0; off >>= 1) {
        if (threadIdx.x < off) red[threadIdx.x] += red[threadIdx.x + off];
        __syncthreads();
    }
    float r = 1.0f / sqrtf(red[0] / (float)H + 1e-6f);
    for (int i = threadIdx.x; i < H; i += 256) yr[i] = xr[i] * r * w[i];
}

// ---------------- Embed gather (float4) ----------------
__global__ __launch_bounds__(256) void embed_k(const int* __restrict__ ids,
    const float* __restrict__ emb, float* __restrict__ h)
{
    int bs = blockIdx.x;
    const float4* e = (const float4*)(emb + (size_t)ids[bs] * H);
    float4* hr = (float4*)(h + (size_t)bs * H);
    hr[threadIdx.x] = e[threadIdx.x];
}

// ---------------- RoPE fp32 in-place (fallback) ----------------
__global__ __launch_bounds__(256) void rope_k(float* __restrict__ x, const int* __restrict__ pos)
{
    int idx = blockIdx.x * 256 + threadIdx.x;
    int i = idx & 31;
    int head = (idx >> 5) & 15;
    int bs = idx >> 9;
    int p = pos[bs];
    double inv = exp(-((double)(2 * i) / 64.0) * log(10000.0));
    double ang = (double)p * inv;
    float c = (float)cos(ang), sn = (float)sin(ang);
    float* base = x + (size_t)bs * H + head * 64;
    float x1 = base[i], x2 = base[i + 32];
    base[i]      = x1 * c - x2 * sn;
    base[i + 32] = x2 * c + x1 * sn;
}

// ---------------- Flash attention fp32 (fallback) ----------------
__global__ __launch_bounds__(256) void fattn_k(const float* __restrict__ q,
    const float* __restrict__ k, const float* __restrict__ v,
    float* __restrict__ o, const int* __restrict__ valid)
{
    const int qt = blockIdx.x, hh = blockIdx.y, b = blockIdx.z;
    const int tid = threadIdx.x;
    const int tx = tid & 15, ty = tid >> 4;
    __shared__ float Qs[64][68];
    __shared__ float Ks[64][68];
    __shared__ float Vs[64][68];
    __shared__ int   kvs[64];
    const size_t hoff = (size_t)hh * HD;

    {
        int row = tid >> 2, d0 = (tid & 3) * 16;
        const float* qp = q + ((size_t)(b * S + qt * 64 + row)) * H + hoff + d0;
        float4* dst = (float4*)&Qs[row][d0];
        const float4* src = (const float4*)qp;
        #pragma unroll
        for (int e = 0; e < 4; ++e) dst[e] = src[e];
    }
    int qv[4]; int qrow_g[4];
    #pragma unroll
    for (int i = 0; i < 4; ++i) {
        qrow_g[i] = qt * 64 + ty * 4 + i;
        qv[i] = valid[b * S + qrow_g[i]];
    }
    float m[4], l[4], acc[4][4];
    #pragma unroll
    for (int i = 0; i < 4; ++i) {
        m[i] = -3.4e38f; l[i] = 0.f;
        #pragma unroll
        for (int j = 0; j < 4; ++j) acc[i][j] = 0.f;
    }

    for (int kt = 0; kt < S / 64; ++kt) {
        __syncthreads();
        {
            int row = tid >> 2, d0 = (tid & 3) * 16;
            const float* kp = k + ((size_t)(b * S + kt * 64 + row)) * H + hoff + d0;
            float4* dst = (float4*)&Ks[row][d0];
            const float4* src = (const float4*)kp;
            #pragma unroll
            for (int e = 0; e < 4; ++e) dst[e] = src[e];
        }
        {
            int kk = tid >> 2, d0 = (tid & 3) * 16;
            const float* vp = v + ((size_t)(b * S + kt * 64 + kk)) * H + hoff + d0;
            #pragma unroll
            for (int e = 0; e < 16; e += 4) {
                float4 vv = *(const float4*)(vp + e);
                Vs[d0 + e + 0][kk] = vv.x;
                Vs[d0 + e + 1][kk] = vv.y;
                Vs[d0 + e + 2][kk] = vv.z;
                Vs[d0 + e + 3][kk] = vv.w;
            }
        }
        if (tid < 64) kvs[tid] = valid[b * S + kt * 64 + tid];
        __syncthreads();

        float s4[4][4];
        #pragma unroll
        for (int i = 0; i < 4; ++i)
            #pragma unroll
            for (int j = 0; j < 4; ++j) s4[i][j] = 0.f;
        #pragma unroll
        for (int c = 0; c < 16; ++c) {
            float4 a[4], bb[4];
            #pragma unroll
            for (int i = 0; i < 4; ++i) a[i]  = ((const float4*)&Qs[ty * 4 + i][0])[c];
            #pragma unroll
            for (int j = 0; j < 4; ++j) bb[j] = ((const float4*)&Ks[tx * 4 + j][0])[c];
            #pragma unroll
            for (int i = 0; i < 4; ++i)
                #pragma unroll
                for (int j = 0; j < 4; ++j) {
                    s4[i][j] += a[i].x * bb[j].x + a[i].y * bb[j].y
                              + a[i].z * bb[j].z + a[i].w * bb[j].w;
                }
        }
        float p[4][4];
        float corr[4];
        #pragma unroll
        for (int i = 0; i < 4; ++i) {
            float rm = -3.4e38f;
            #pragma unroll
            for (int j = 0; j < 4; ++j) {
                int kc = kt * 64 + tx * 4 + j;
                float sv = s4[i][j] * 0.125f;
                int allowed = (kc <= qrow_g[i]) && qv[i] && kvs[tx * 4 + j];
                if (!allowed) sv = sv + -1e9f;
                s4[i][j] = sv;
                rm = fmaxf(rm, sv);
            }
            rm = fmaxf(rm, __shfl_xor(rm, 1));
            rm = fmaxf(rm, __shfl_xor(rm, 2));
            rm = fmaxf(rm, __shfl_xor(rm, 4));
            rm = fmaxf(rm, __shfl_xor(rm, 8));
            float mn = fmaxf(m[i], rm);
            corr[i] = expf(m[i] - mn);
            float rs = 0.f;
            #pragma unroll
            for (int j = 0; j < 4; ++j) { p[i][j] = expf(s4[i][j] - mn); rs += p[i][j]; }
            rs += __shfl_xor(rs, 1);
            rs += __shfl_xor(rs, 2);
            rs += __shfl_xor(rs, 4);
            rs += __shfl_xor(rs, 8);
            l[i] = l[i] * corr[i] + rs;
            m[i] = mn;
            #pragma unroll
            for (int j = 0; j < 4; ++j) acc[i][j] *= corr[i];
        }
        __syncthreads();
        #pragma unroll
        for (int i = 0; i < 4; ++i) {
            float4 pv4 = make_float4(p[i][0], p[i][1], p[i][2], p[i][3]);
            *(float4*)&Ks[ty * 4 + i][tx * 4] = pv4;
        }
        __syncthreads();
        #pragma unroll
        for (int c = 0; c < 16; ++c) {
            float4 a[4], bb[4];
            #pragma unroll
            for (int i = 0; i < 4; ++i) a[i]  = ((const float4*)&Ks[ty * 4 + i][0])[c];
            #pragma unroll
            for (int j = 0; j < 4; ++j) bb[j] = ((const float4*)&Vs[tx * 4 + j][0])[c];
            #pragma unroll
            for (int i = 0; i < 4; ++i)
                #pragma unroll
                for (int j = 0; j < 4; ++j) {
                    acc[i][j] += a[i].x * bb[j].x + a[i].y * bb[j].y
                               + a[i].z * bb[j].z + a[i].w * bb[j].w;
                }
        }
    }
    #pragma unroll
    for (int i = 0; i < 4; ++i) {
        float inv = 1.0f / l[i];
        float4 ov = make_float4(acc[i][0] * inv, acc[i][1] * inv,
                                acc[i][2] * inv, acc[i][3] * inv);
        *(float4*)(o + ((size_t)(b * S + qrow_g[i])) * H + hoff + tx * 4) = ov;
    }
}

// ---------------- Discretize + inline null-logit (fused headcol) ----------------
__global__ __launch_bounds__(256) void discretize_h_k(const float* __restrict__ logits,
    const float* __restrict__ h, const float* __restrict__ head_w, const float* __restrict__ head_b,
    const float* __restrict__ gumbel, _Float16* __restrict__ z, int* __restrict__ chosen)
{
    int bs = blockIdx.x;
    const float* lg = logits + (size_t)bs * CV1;
    const float* gm = gumbel + (size_t)bs * CV1;
    __shared__ float redv[256]; __shared__ int redi[256];
    int tid = threadIdx.x;
    // null logit (col CV): dot(h[bs], head_w[:,CV]) + head_b[CV]
    float ps = 0.f;
    for (int j = tid; j < H; j += 256)
        ps += h[(size_t)bs * H + j] * head_w[(size_t)j * CV1 + CV];
    redv[tid] = ps; __syncthreads();
    for (int off = 128; off > 0; off >>= 1) {
        if (tid < off) redv[tid] += redv[tid + off];
        __syncthreads();
    }
    float nullv = redv[0] + head_b[CV];
    __syncthreads();
    // argmax over all CV1 entries (thread 0 handles j==CV last, preserving order)
    float m = -3.4e38f; int mi = CV1;
    for (int j = tid; j < CV; j += 256) {
        float a = lg[j] + gm[j];
        if (a > m) { m = a; mi = j; }
    }
    if (tid == 0) {
        float a = nullv + gm[CV];
        if (a > m) { m = a; mi = CV; }
    }
    redv[tid] = m; redi[tid] = mi; __syncthreads();
    for (int off = 128; off > 0; off >>= 1) {
        if (tid < off) {
            float vo = redv[tid + off]; int io = redi[tid + off];
            if (vo > redv[tid] || (vo == redv[tid] && io < redi[tid])) { redv[tid] = vo; redi[tid] = io; }
        }
        __syncthreads();
    }
    m = redv[0]; int amax = redi[0];
    __syncthreads();
    float ssum = 0.f;
    for (int j = tid; j < CV; j += 256) ssum += expf(lg[j] + gm[j] - m);
    if (tid == 0) ssum += expf(nullv + gm[CV] - m);
    redv[tid] = ssum; __syncthreads();
    for (int off = 128; off > 0; off >>= 1) {
        if (tid < off) redv[tid] += redv[tid + off];
        __syncthreads();
    }
    float inv = 1.0f / redv[0];
    size_t rowbase = (size_t)bs * CV;
    int phi = (bs >> 1) & 3;
    {
        int j8 = tid * 8;   // CV/8 = 256 groups
        float vals[8];
        #pragma unroll
        for (int e = 0; e < 8; ++e) vals[e] = expf(lg[j8 + e] + gm[j8 + e] - m) * inv;
        split_store8_swz(vals, z, 0, rowbase, j8, phi, 1);
    }
    if (tid == 0) chosen[bs] = amax;
}

__global__ __launch_bounds__(256) void discretize_k(const float* __restrict__ logits,
    const float* __restrict__ gumbel, float* __restrict__ z, int* __restrict__ chosen)
{
    int bs = blockIdx.x;
    const float* lg = logits + (size_t)bs * CV1;
    const float* gm = gumbel + (size_t)bs * CV1;
    __shared__ float redv[256]; __shared__ int redi[256];
    int tid = threadIdx.x;
    float m = -3.4e38f; int mi = CV1;
    for (int j = tid; j < CV1; j += 256) {
        float a = lg[j] + gm[j];
        if (a > m) { m = a; mi = j; }
    }
    redv[tid] = m; redi[tid] = mi; __syncthreads();
    for (int off = 128; off > 0; off >>= 1) {
        if (tid < off) {
            float vo = redv[tid + off]; int io = redi[tid + off];
            if (vo > redv[tid] || (vo == redv[tid] && io < redi[tid])) { redv[tid] = vo; redi[tid] = io; }
        }
        __syncthreads();
    }
    m = redv[0]; int amax = redi[0];
    __syncthreads();
    float ssum = 0.f;
    for (int j = tid; j < CV1; j += 256) ssum += expf(lg[j] + gm[j] - m);
    redv[tid] = ssum; __syncthreads();
    for (int off = 128; off > 0; off >>= 1) {
        if (tid < off) redv[tid] += redv[tid + off];
        __syncthreads();
    }
    float inv = 1.0f / redv[0];
    for (int j = tid; j < CV; j += 256)
        z[(size_t)bs * CV + j] = expf(lg[j] + gm[j] - m) * inv;
    if (tid == 0) chosen[bs] = amax;
}

// ---------------- cea + loss (float4) ----------------
__global__ __launch_bounds__(256) void cea_k(const float* __restrict__ esoft,
    const float* __restrict__ cemb, const int* __restrict__ chosen,
    const int* __restrict__ amask, float* __restrict__ cea, float* __restrict__ partial)
{
    int bs = blockIdx.x;
    int ch = chosen[bs]; int vm = amask[bs];
    int comp = (ch != CV) && vm;
    const float4* ehr = (const float4*)(cemb + (size_t)(ch < CV - 1 ? ch : CV - 1) * H);
    const float4* esr = (const float4*)(esoft + (size_t)bs * H);
    float4* cer = (float4*)(cea + (size_t)bs * H);
    __shared__ float red[256];
    float vmf = vm ? 1.f : 0.f;
    float4 es = esr[threadIdx.x];
    float4 ehv = comp ? ehr[threadIdx.x] : make_float4(0.f, 0.f, 0.f, 0.f);
    float4 o;
    o.x = ((ehv.x + es.x) - es.x) * vmf;
    o.y = ((ehv.y + es.y) - es.y) * vmf;
    o.z = ((ehv.z + es.z) - es.z) * vmf;
    o.w = ((ehv.w + es.w) - es.w) * vmf;
    cer[threadIdx.x] = o;
    float dx = es.x - ehv.x, dy = es.y - ehv.y, dz = es.z - ehv.z, dw = es.w - ehv.w;
    float part = dx * dx + dy * dy + dz * dz + dw * dw;
    red[threadIdx.x] = part; __syncthreads();
    for (int off = 128; off > 0; off >>= 1) {
        if (threadIdx.x < off) red[threadIdx.x] += red[threadIdx.x + off];
        __syncthreads();
    }
    if (threadIdx.x == 0) partial[bs] = red[0];
}

__global__ __launch_bounds__(256) void loss_k(const float* __restrict__ partial, float* __restrict__ out)
{
    __shared__ float red[256];
    float s = 0.f;
    for (int i = threadIdx.x; i < BS; i += 256) s += partial[i];
    red[threadIdx.x] = s; __syncthreads();
    for (int off = 128; off > 0; off >>= 1) {
        if (threadIdx.x < off) red[threadIdx.x] += red[threadIdx.x + off];
        __syncthreads();
    }
    if (threadIdx.x == 0) out[0] = 1.25f * red[0] / (float)BSH;
}

// ---------------- Parallel stable pack ----------------
__global__ __launch_bounds__(1024) void pack_k(const int* __restrict__ chosen,
    const int* __restrict__ amask, int* __restrict__ order, int* __restrict__ cpos,
    int* __restrict__ cvalid, int* __restrict__ counts)
{
    int b = blockIdx.x, t = threadIdx.x;
    __shared__ int sc[1024];
    __shared__ int ord[1024];
    int f = (chosen[b * S + t] != CV && amask[b * S + t]) ? 1 : 0;
    sc[t] = f;
    __syncthreads();
    #pragma unroll
    for (int off = 1; off < 1024; off <<= 1) {
        int add = (t >= off) ? sc[t - off] : 0;
        __syncthreads();
        sc[t] += add;
        __syncthreads();
    }
    int cnt = sc[1023];
    int pos = f ? (sc[t] - 1) : (cnt + t - sc[t]);
    ord[pos] = t;
    __syncthreads();
    int o = ord[t];
    order[b * S + t] = o;
    cvalid[b * S + t] = (t < cnt) ? 1 : 0;
    cpos[b * S + t] = (t < cnt) ? o : 0;
    if (t == 0) counts[b] = cnt;
}

__global__ __launch_bounds__(256) void gather_k(const float* __restrict__ cea,
    const int* __restrict__ order, const int* __restrict__ cvalid, float* __restrict__ h)
{
    int bs = blockIdx.x;
    int b = bs >> 10;
    int src = order[bs];
    float f = cvalid[bs] ? 1.f : 0.f;
    const float4* sp = (const float4*)(cea + (size_t)(b * S + src) * H);
    float4* dst = (float4*)(h + (size_t)bs * H);
    float4 v = sp[threadIdx.x];
    dst[threadIdx.x] = make_float4(v.x * f, v.y * f, v.z * f, v.w * f);
}

__global__ __launch_bounds__(256) void outmask_k(const float* __restrict__ h,
    const int* __restrict__ cvalid, float* __restrict__ out)
{
    int bs = blockIdx.x;
    float f = cvalid[bs] ? 1.f : 0.f;
    const float4* sp = (const float4*)(h + (size_t)bs * H);
    float4* dst = (float4*)(out + (size_t)bs * H);
    float4 v = sp[threadIdx.x];
    dst[threadIdx.x] = make_float4(v.x * f, v.y * f, v.z * f, v.w * f);
}

__global__ __launch_bounds__(256) void iota_k(int* __restrict__ pos)
{
    int idx = blockIdx.x * 256 + threadIdx.x;
    if (idx < BS) pos[idx] = idx & (S - 1);
}

// ================= Host-side drivers =================
static void run_block_f32(int layer,
    const float* ln1, const float* wq, const float* wk, const float* wv,
    const float* wo, const float* ln2, const float* wg, const float* wu, const float* wd,
    float* h, float* hn, float* q, float* k, float* v, float* o, float* f1,
    const int* valid, const int* pos, hipStream_t stream)
{
    size_t LHH = (size_t)layer * H * H;
    size_t LHF = (size_t)layer * H * FF;
    rmsnorm_k<<<BS, 256, 0, stream>>>(h, ln1 + (size_t)layer * H, hn);
    gemm_k<<<dim3(16, 64), 256, 0, stream>>>(hn, wq + LHH, nullptr, q, BS, H, H, H, H, H, 0);
    gemm_k<<<dim3(16, 64), 256, 0, stream>>>(hn, wk + LHH, nullptr, k, BS, H, H, H, H, H, 0);
    gemm_k<<<dim3(16, 64), 256, 0, stream>>>(hn, wv + LHH, nullptr, v, BS, H, H, H, H, H, 0);
    rope_k<<<8192, 256, 0, stream>>>(q, pos);
    rope_k<<<8192, 256, 0, stream>>>(k, pos);
    fattn_k<<<dim3(S / 64, NH, B), 256, 0, stream>>>(q, k, v, o, valid);
    gemm_k<<<dim3(16, 64), 256, 0, stream>>>(o, wo + LHH, nullptr, h, BS, H, H, H, H, H, F_RESID);
    rmsnorm_k<<<BS, 256, 0, stream>>>(h, ln2 + (size_t)layer * H, hn);
    gemm_k<<<dim3(64, 64), 256, 0, stream>>>(hn, wg + LHF, nullptr, f1, BS, FF, H, H, FF, FF, F_SILU);
    gemm_k<<<dim3(64, 64), 256, 0, stream>>>(hn, wu + LHF, nullptr, f1, BS, FF, H, H, FF, FF, F_MULIN);
    gemm_k<<<dim3(16, 64), 256, 0, stream>>>(f1, wd + (size_t)layer * FF * H, nullptr, h, BS, H, FF, FF, H, H, F_RESID);
}

// MFMA block, templated on split planes / products / invalid-row skip
// (shallow <2,3,false> rvalid=nullptr; mid <1,1,true> rvalid=cvalid)
template<int NP, int NPROD, bool SKIPINV>
static void run_block_mf(int layer,
    const float* ln1, const float* wq, const float* wk, const float* wv,
    const float* wo, const float* ln2, const float* wg, const float* wu, const float* wd,
    float* h, float* qkv,
    _Float16* hnsp, _Float16* osp, _Float16* wsp, _Float16* wsp2, _Float16* f1sp,
    _Float16* qsp, _Float16* ksp, _Float16* vtp,
    const float* ct, const float* st,
    const int* valid, const int* pos, const int* rvalid, hipStream_t stream)
{
    const size_t PH = (size_t)H * H;        // wo plane
    const size_t P3H = 3 * PH;              // fused qkv plane
    const size_t PGU = (size_t)H * FF;      // wg/wu/wd plane
    const size_t PA = BSH;                  // activation plane
    const size_t PF = BSF;                  // f1 plane
    size_t LHH = (size_t)layer * H * H;
    size_t LHF = (size_t)layer * H * FF;

    rmsnorm_split_k<<<BS, 256, 0, stream>>>(h, ln1 + (size_t)layer * H, hnsp, PA, NP);
    splitwt3_k<<<dim3(H / 64, H / 32, 3), 256, 0, stream>>>(
        wq + LHH, wk + LHH, wv + LHH, wsp, P3H, NP);
    // Fused QKV GEMM + RoPE + split + V-transpose (replaces gemm_mf + rope2_split + splitvt)
    gemmqkv_k<NP, NPROD><<<dim3(3 * H / 128, BS / 128), 256, 0, stream>>>(
        hnsp, wsp, pos, ct, st, qsp, ksp, vtp, H, PA, P3H, 1, rvalid);
    mfattn_k<NP, NPROD, SKIPINV><<<dim3(S / 64, NH, B), 256, 0, stream>>>(qsp, ksp, vtp, osp, valid);
    splitwt_k<<<dim3(H / 64, H / 32), 256, 0, stream>>>(wo + LHH, wsp, H, H, H, PH, NP);
    gemm_mf_k<NP, NPROD><<<dim3(H / 128, BS / 128), 256, 0, stream>>>(
        osp, wsp, nullptr, h, h, BS, H, H, H, PA, PH, 1, rvalid);
    rmsnorm_split_k<<<BS, 256, 0, stream>>>(h, ln2 + (size_t)layer * H, hnsp, PA, NP);
    splitwt2_k<<<dim3(FF / 64, H / 32, 2), 256, 0, stream>>>(
        wg + LHF, wu + LHF, wsp, wsp2, PGU, NP);
    gateup_k<NP, NPROD><<<dim3(FF / 128, BS / 128), 256, 0, stream>>>(
        hnsp, wsp, wsp2, f1sp, BS, FF, H, PA, PGU, PF, NP, 2, rvalid);
    splitwt_k<<<dim3(H / 64, FF / 32), 256, 0, stream>>>(wd + (size_t)layer * FF * H, wsp, FF, H, H, PGU, NP);
    gemm_mf_k<NP, NPROD><<<dim3(H / 128, BS / 128), 256, 0, stream>>>(
        f1sp, wsp, nullptr, h, h, BS, H, FF, H, PF, PGU, 1, rvalid);
}

extern "C" void kernel_launch(void* const* d_in, const int* in_sizes, int n_in,
                              void* d_out, int out_size, void* d_ws, size_t ws_size,
                              hipStream_t stream)
{
    const int*   ids    = (const int*)d_in[0];
    const int*   amask  = (const int*)d_in[1];
    const float* embed  = (const float*)d_in[2];
    const float* ln1    = (const float*)d_in[3];
    const float* wq     = (const float*)d_in[4];
    const float* wk     = (const float*)d_in[5];
    const float* wv     = (const float*)d_in[6];
    const float* wo     = (const float*)d_in[7];
    const float* ln2    = (const float*)d_in[8];
    const float* wg     = (const float*)d_in[9];
    const float* wu     = (const float*)d_in[10];
    const float* wd     = (const float*)d_in[11];
    const float* head_w = (const float*)d_in[12];
    const float* head_b = (const float*)d_in[13];
    const float* cemb   = (const float*)d_in[14];
    const float* gumbel = (const float*)d_in[15];
    float* out = (float*)d_out;

    const size_t MB = 1ull << 20;
    const size_t NEED = 274 * MB;

    if (ws_size >= NEED) {
        // ===== MFMA path =====
        char* base = (char*)d_ws;
        float* h   = (float*)base;                  // 16MB
        float* qkv = (float*)(base + 16 * MB);      // 48MB [BS][3072] (logits/esoft workspace)
        _Float16* zb   = (_Float16*)(base + 64 * MB);   // 16MB [BS][CV]
        _Float16* hnsp = (_Float16*)(base + 80 * MB);   // 2 planes x 8MB
        _Float16* osp  = (_Float16*)(base + 104 * MB);
        _Float16* wsp  = (_Float16*)(base + 128 * MB);  // <=24MB weight planes
        _Float16* wsp2 = (_Float16*)(base + 152 * MB);
        _Float16* f1sp = (_Float16*)(base + 176 * MB);  // 2 planes x 32MB
        _Float16* qsp  = (_Float16*)(base + 176 * MB);  // alias f1sp (disjoint lifetime)
        _Float16* ksp  = (_Float16*)(base + 200 * MB);
        _Float16* vtp  = (_Float16*)(base + 224 * MB);
        int* meta   = (int*)(base + 272 * MB);
        int* chosen = meta;
        int* order  = meta + BS;
        int* cpos   = meta + 2 * BS;
        int* cvalid = meta + 3 * BS;
        int* counts = meta + 4 * BS;
        int* pos_sh = meta + 5 * BS;
        float* partial = (float*)(meta + 6 * BS);
        float* ct = (float*)(base + 273 * MB);          // S*32 floats (128KB)
        float* st = ct + S * 32;                        // S*32 floats
        float* logits = qkv;          // qkv workspace reuse
        float* esoft  = qkv;
        float* ceab   = qkv + BSH;

        embed_k<<<BS, 256, 0, stream>>>(ids, embed, h);
        init_k<<<S * 32 / 256, 256, 0, stream>>>(ct, st, pos_sh);

        for (int L = 0; L < 2; ++L)
            run_block_mf<2, 3, false>(L, ln1, wq, wk, wv, wo, ln2, wg, wu, wd,
                                      h, qkv, hnsp, osp, wsp, wsp2, f1sp,
                                      qsp, ksp, vtp, ct, st, amask, pos_sh, nullptr, stream);

        // ---- head logits: fp16 2-plane, ALL 4 products (argmax-critical) ----
        splita_swz_k<<<BS, 256, 0, stream>>>(h, hnsp, BSH, 2);
        splitwt_k<<<dim3(CV / 64, H / 32), 256, 0, stream>>>(head_w, wsp, H, CV, CV1, (size_t)CV * H, 2);
        gemm_mf_k<2, 4><<<dim3(CV / 128, BS / 128), 256, 0, stream>>>(
            hnsp, wsp, head_b, logits, nullptr, BS, CV, H, CV1, BSH, (size_t)CV * H, 1, nullptr);
        discretize_h_k<<<BS, 256, 0, stream>>>(logits, h, head_w, head_b, gumbel, zb, chosen);

        // ---- e_soft = z @ cemb (fp16 1-plane) ----
        splitwt_k<<<dim3(H / 64, CV / 32), 256, 0, stream>>>(cemb, wsp, CV, H, H, (size_t)H * CV, 1);
        gemm_mf_k<1, 1><<<dim3(H / 128, BS / 128), 256, 0, stream>>>(
            zb, wsp, nullptr, esoft, nullptr, BS, H, CV, H, (size_t)BS * CV, (size_t)H * CV, 0, nullptr);

        cea_k<<<BS, 256, 0, stream>>>(esoft, cemb, chosen, amask, ceab, partial);
        loss_k<<<1, 256, 0, stream>>>(partial, out + BSH);
        pack_k<<<B, 1024, 0, stream>>>(chosen, amask, order, cpos, cvalid, counts);
        gather_k<<<BS, 256, 0, stream>>>(ceab, order, cvalid, h);

        for (int L = 2; L < 4; ++L)
            run_block_mf<1, 1, true>(L, ln1, wq, wk, wv, wo, ln2, wg, wu, wd,
                                     h, qkv, hnsp, osp, wsp, wsp2, f1sp,
                                     qsp, ksp, vtp, ct, st, cvalid, cpos, cvalid, stream);

        outmask_k<<<BS, 256, 0, stream>>>(h, cvalid, out);
    } else {
        // ===== fallback: fp32 path =====
        float* wsf = (float*)d_ws;
        float* h   = wsf;
        float* hn  = wsf + BSH;
        float* q   = wsf + 2 * BSH;
        float* k   = wsf + 3 * BSH;
        float* v   = wsf + 4 * BSH;
        float* o   = wsf + 5 * BSH;
        float* f1  = wsf + 6 * BSH;
        float* zbuf  = q;
        float* esoft = v;
        float* ceab  = o;
        int* meta   = (int*)(wsf + 6 * BSH + BSF);
        int* chosen = meta;
        int* order  = meta + BS;
        int* cpos   = meta + 2 * BS;
        int* cvalid = meta + 3 * BS;
        int* counts = meta + 4 * BS;
        int* pos_sh = meta + 5 * BS;
        float* partial = (float*)(meta + 6 * BS);

        embed_k<<<BS, 256, 0, stream>>>(ids, embed, h);
        iota_k<<<16, 256, 0, stream>>>(pos_sh);
        for (int L = 0; L < 2; ++L)
            run_block_f32(L, ln1, wq, wk, wv, wo, ln2, wg, wu, wd,
                          h, hn, q, k, v, o, f1, amask, pos_sh, stream);
        gemm_k<<<dim3(33, 64), 256, 0, stream>>>(h, head_w, head_b, f1, BS, CV1, H, H, CV1, CV1, F_BIAS);
        discretize_k<<<BS, 256, 0, stream>>>(f1, gumbel, zbuf, chosen);
        gemm_k<<<dim3(16, 64), 256, 0, stream>>>(zbuf, cemb, nullptr, esoft, BS, H, CV, CV, H, H, 0);
        cea_k<<<BS, 256, 0, stream>>>(esoft, cemb, chosen, amask, ceab, partial);
        loss_k<<<1, 256, 0, stream>>>(partial, out + BSH);
        pack_k<<<B, 1024, 0, stream>>>(chosen, amask, order, cpos, cvalid, counts);
        gather_k<<<BS, 256, 0, stream>>>(ceab, order, cvalid, h);
        for (int L = 2; L < 4; ++L)
            run_block_f32(L, ln1, wq, wk, wv, wo, ln2, wg, wu, wd,
                          h, hn, q, k, v, o, f1, cvalid, cpos, stream);
        outmask_k<<<BS, 256, 0, stream>>>(h, cvalid, out);
    }
}

// Round 18
// 2455.457 us; speedup vs baseline: 1.0338x; 1.0119x over previous
//
#include <hip/hip_runtime.h>
#include <hip/hip_bf16.h>
#include <cmath>

#define B 4
#define S 1024
#define H 1024
#define NH 16
#define HD 64
#define FF 4096
#define CV 2048
#define CV1 2049
#define BS (B*S)            // 4096
#define BSH ((size_t)BS*H)  // 4194304
#define BSF ((size_t)BS*FF) // 16777216

#define F_BIAS  1
#define F_RESID 2
#define F_SILU  4
#define F_MULIN 8

typedef __attribute__((ext_vector_type(8))) _Float16 f16x8;
typedef __attribute__((ext_vector_type(4))) float f32x4;

// Pre-swizzled plane write: element (row,col) stored at
// rowbase + (col&~31) + ((((col>>3)&3)^phi)<<3) + (col&7), phi=(row>>1)&3.
static __device__ inline size_t swz_idx(size_t rowbase, int col, int phi) {
    return rowbase + (size_t)(col & ~31) + ((size_t)(((col >> 3) & 3) ^ phi) << 3) + (col & 7);
}
static __device__ inline void split_store_swz(float v, _Float16* p, size_t plane,
                                              size_t rowbase, int col, int phi, int np) {
    size_t idx = swz_idx(rowbase, col, phi);
    _Float16 h0 = (_Float16)v; p[idx] = h0;
    if (np == 2) p[plane + idx] = (_Float16)(v - (float)h0);
}
// Vectorized: 8 consecutive 8-aligned cols map to one contiguous 16B slot.
static __device__ inline void split_store8_swz(const float* v, _Float16* p, size_t plane,
                                               size_t rowbase, int col8, int phi, int np) {
    size_t idx = swz_idx(rowbase, col8, phi);
    f16x8 h0;
    #pragma unroll
    for (int e = 0; e < 8; ++e) h0[e] = (_Float16)v[e];
    *(f16x8*)&p[idx] = h0;
    if (np == 2) {
        f16x8 h1;
        #pragma unroll
        for (int e = 0; e < 8; ++e) h1[e] = (_Float16)(v[e] - (float)h0[e]);
        *(f16x8*)&p[plane + idx] = h1;
    }
}

// global->LDS async DMA, 16B per lane, LDS dest = base + lane*16
static __device__ inline void gload16(const void* g, void* l) {
    __builtin_amdgcn_global_load_lds(
        (const __attribute__((address_space(1))) void*)g,
        (__attribute__((address_space(3))) void*)l, 16, 0, 0);
}

// XCD-chunk block swizzle. swz=0 none; 1=M-contig chunks; 2=N-contig chunks.
static __device__ inline void tile_coords(int swz, int& bx, int& by) {
    if (swz == 0) { bx = blockIdx.x; by = blockIdx.y; return; }
    int nbx = gridDim.x, nby = gridDim.y;
    int L = blockIdx.y * nbx + blockIdx.x;
    int cpx = (nbx * nby) >> 3;
    int cid = (L & 7) * cpx + (L >> 3);
    if (swz == 1) { by = cid / nbx; bx = cid % nbx; }
    else          { bx = cid / nby; by = cid % nby; }
}

// ============ MFMA GEMM (pass-fused, 2-phase dbuf): one barrier per K-step ============
// rvalid (prefix-contiguous row validity, nullable): if rvalid[row0]==0 the whole
// 128-row block has zero A-rows -> GEMM result is exactly +0; write bias+resid only.
template<int NP, int NPROD>
__global__ __launch_bounds__(256) void gemm_mf_k(
    const _Float16* __restrict__ A, const _Float16* __restrict__ Wt,
    const float* __restrict__ bias, float* __restrict__ C, const float* __restrict__ resid,
    int M, int N, int K, int ldc, size_t planeA, size_t planeW, int swz,
    const int* __restrict__ rvalid)
{
    __shared__ _Float16 As[2][NP][128 * 32];
    __shared__ _Float16 Bs[2][NP][128 * 32];
    const int tid = threadIdx.x;
    const int w = tid >> 6, l = tid & 63;
    const int wm = w >> 1, wn = w & 1;
    int bx, by; tile_coords(swz, bx, by);
    const int row0 = by * 128, col0 = bx * 128;
    const int rA = l >> 2;
    const int cq8 = (l & 3) * 8;
    const int PA[4] = {0, 0, 1, 1};
    const int PW[4] = {0, 1, 0, 1};
    const int lr = l & 15, q = l >> 4;

    if (rvalid && rvalid[row0] == 0) {
        // block-uniform skip: all A-rows are zeros -> result = bias + resid
        const int cw2 = l & 15, rw2 = (l >> 4) * 4;
        #pragma unroll
        for (int mi = 0; mi < 4; ++mi)
            #pragma unroll
            for (int ni = 0; ni < 4; ++ni)
                #pragma unroll
                for (int r = 0; r < 4; ++r) {
                    int gr = row0 + wm * 64 + mi * 16 + rw2 + r;
                    int gc = col0 + wn * 64 + ni * 16 + cw2;
                    size_t ci = (size_t)gr * ldc + gc;
                    float val = bias ? bias[gc] : 0.f;
                    if (resid) val += resid[ci];
                    C[ci] = val;
                }
        return;
    }

    f32x4 acc[4][4];
    #pragma unroll
    for (int i = 0; i < 4; ++i)
        #pragma unroll
        for (int j = 0; j < 4; ++j)
            #pragma unroll
            for (int r = 0; r < 4; ++r) acc[i][j][r] = 0.f;

    auto stage = [&](int bf, int k0) {
        #pragma unroll
        for (int p = 0; p < NP; ++p)
            #pragma unroll
            for (int s = 0; s < 2; ++s) {
                int rr = (w * 2 + s) * 16 + rA;
                gload16(A + (size_t)p * planeA + (size_t)(row0 + rr) * K + k0 + cq8,
                        &As[bf][p][(w * 2 + s) * 512]);
                gload16(Wt + (size_t)p * planeW + (size_t)(col0 + rr) * K + k0 + cq8,
                        &Bs[bf][p][(w * 2 + s) * 512]);
            }
    };

    stage(0, 0);
    __syncthreads();
    int cur = 0;
    for (int k0 = 0; k0 < K; k0 += 32) {
        if (k0 + 32 < K) stage(cur ^ 1, k0 + 32);
        f16x8 af[NP][4], bfv[NP][4];
        #pragma unroll
        for (int p = 0; p < NP; ++p)
            #pragma unroll
            for (int i = 0; i < 4; ++i) {
                int ra = wm * 64 + i * 16 + lr;
                af[p][i] = *(const f16x8*)&As[cur][p][ra * 32 + (q ^ ((ra >> 1) & 3)) * 8];
                int rb = wn * 64 + i * 16 + lr;
                bfv[p][i] = *(const f16x8*)&Bs[cur][p][rb * 32 + (q ^ ((rb >> 1) & 3)) * 8];
            }
        #pragma unroll
        for (int pr = 0; pr < NPROD; ++pr) {
            const int pa = PA[pr], pw = PW[pr];
            #pragma unroll
            for (int mi = 0; mi < 4; ++mi)
                #pragma unroll
                for (int ni = 0; ni < 4; ++ni)
                    acc[mi][ni] = __builtin_amdgcn_mfma_f32_16x16x32_f16(
                        af[pa][mi], bfv[pw][ni], acc[mi][ni], 0, 0, 0);
        }
        __syncthreads();
        cur ^= 1;
    }
    const int cw = l & 15, rw = (l >> 4) * 4;
    #pragma unroll
    for (int mi = 0; mi < 4; ++mi)
        #pragma unroll
        for (int ni = 0; ni < 4; ++ni)
            #pragma unroll
            for (int r = 0; r < 4; ++r) {
                int gr = row0 + wm * 64 + mi * 16 + rw + r;
                int gc = col0 + wn * 64 + ni * 16 + cw;
                size_t ci = (size_t)gr * ldc + gc;
                float val = acc[mi][ni][r];
                if (bias)  val += bias[gc];
                if (resid) val += resid[ci];
                C[ci] = val;
            }
}

// ============ Fused QKV GEMM + RoPE + split planes + V-transpose ============
// Same GEMM body as gemm_mf_k (N = 3H panel of [q|k|v] weights).  The epilogue
// consumes acc directly:  sel = col0>>10 (block-uniform, 128 | 1024).
template<int NP, int NPROD>
__global__ __launch_bounds__(256) void gemmqkv_k(
    const _Float16* __restrict__ A, const _Float16* __restrict__ Wt,
    const int* __restrict__ pos, const float* __restrict__ ct, const float* __restrict__ st,
    _Float16* __restrict__ qsp, _Float16* __restrict__ ksp, _Float16* __restrict__ vtp,
    int K, size_t planeA, size_t planeW, int swz, const int* __restrict__ rvalid)
{
    __shared__ _Float16 As[2][NP][128 * 32];
    __shared__ _Float16 Bs[2][NP][128 * 32];
    const int tid = threadIdx.x;
    const int w = tid >> 6, l = tid & 63;
    const int wm = w >> 1, wn = w & 1;
    int bx, by; tile_coords(swz, bx, by);
    const int row0 = by * 128, col0 = bx * 128;
    const int rA = l >> 2;
    const int cq8 = (l & 3) * 8;
    const int PA[4] = {0, 0, 1, 1};
    const int PW[4] = {0, 1, 0, 1};
    const int lr = l & 15, q = l >> 4;
    const int sel = col0 >> 10;             // 0=q, 1=k, 2=v (block-uniform)
    const int cbase = col0 & 1023;          // within-plane column base
    const int cw = l & 15, rw = (l >> 4) * 4;

    if (rvalid && rvalid[row0] == 0) {
        // zero A-rows: gemm=0, rope(0)=0 -> write zeros to the target planes
        if (sel < 2) {
            _Float16* y = sel ? ksp : qsp;
            #pragma unroll
            for (int mi = 0; mi < 4; ++mi)
                #pragma unroll
                for (int r = 0; r < 4; ++r) {
                    int gr = row0 + wm * 64 + mi * 16 + rw + r;
                    size_t rowbase = (size_t)gr * H;
                    int phi = (gr >> 1) & 3;
                    #pragma unroll
                    for (int ni = 0; ni < 2; ++ni) {
                        int c = cbase + wn * 64 + ni * 16 + cw;
                        split_store_swz(0.f, y, BSH, rowbase, c, phi, NP);
                        split_store_swz(0.f, y, BSH, rowbase, c + 32, phi, NP);
                    }
                }
        } else {
            #pragma unroll
            for (int ni = 0; ni < 4; ++ni) {
                int c = cbase + wn * 64 + ni * 16 + cw;
                int phiv = ((c & 63) >> 1) & 3;
                #pragma unroll
                for (int mi = 0; mi < 4; ++mi)
                    #pragma unroll
                    for (int r = 0; r < 4; ++r) {
                        int gr = row0 + wm * 64 + mi * 16 + rw + r;
                        int b = gr >> 10, scol = gr & 1023;
                        split_store_swz(0.f, vtp, BSH, ((size_t)c * B + b) * S, scol, phiv, NP);
                    }
            }
        }
        return;
    }

    f32x4 acc[4][4];
    #pragma unroll
    for (int i = 0; i < 4; ++i)
        #pragma unroll
        for (int j = 0; j < 4; ++j)
            #pragma unroll
            for (int r = 0; r < 4; ++r) acc[i][j][r] = 0.f;

    auto stage = [&](int bf, int k0) {
        #pragma unroll
        for (int p = 0; p < NP; ++p)
            #pragma unroll
            for (int s = 0; s < 2; ++s) {
                int rr = (w * 2 + s) * 16 + rA;
                gload16(A + (size_t)p * planeA + (size_t)(row0 + rr) * K + k0 + cq8,
                        &As[bf][p][(w * 2 + s) * 512]);
                gload16(Wt + (size_t)p * planeW + (size_t)(col0 + rr) * K + k0 + cq8,
                        &Bs[bf][p][(w * 2 + s) * 512]);
            }
    };

    stage(0, 0);
    __syncthreads();
    int cur = 0;
    for (int k0 = 0; k0 < K; k0 += 32) {
        if (k0 + 32 < K) stage(cur ^ 1, k0 + 32);
        f16x8 af[NP][4], bfv[NP][4];
        #pragma unroll
        for (int p = 0; p < NP; ++p)
            #pragma unroll
            for (int i = 0; i < 4; ++i) {
                int ra = wm * 64 + i * 16 + lr;
                af[p][i] = *(const f16x8*)&As[cur][p][ra * 32 + (q ^ ((ra >> 1) & 3)) * 8];
                int rb = wn * 64 + i * 16 + lr;
                bfv[p][i] = *(const f16x8*)&Bs[cur][p][rb * 32 + (q ^ ((rb >> 1) & 3)) * 8];
            }
        #pragma unroll
        for (int pr = 0; pr < NPROD; ++pr) {
            const int pa = PA[pr], pw = PW[pr];
            #pragma unroll
            for (int mi = 0; mi < 4; ++mi)
                #pragma unroll
                for (int ni = 0; ni < 4; ++ni)
                    acc[mi][ni] = __builtin_amdgcn_mfma_f32_16x16x32_f16(
                        af[pa][mi], bfv[pw][ni], acc[mi][ni], 0, 0, 0);
        }
        __syncthreads();
        cur ^= 1;
    }

    if (sel < 2) {
        _Float16* y = sel ? ksp : qsp;
        #pragma unroll
        for (int mi = 0; mi < 4; ++mi)
            #pragma unroll
            for (int r = 0; r < 4; ++r) {
                int gr = row0 + wm * 64 + mi * 16 + rw + r;
                int p = pos[gr];
                size_t rowbase = (size_t)gr * H;
                int phi = (gr >> 1) & 3;
                #pragma unroll
                for (int ni = 0; ni < 2; ++ni) {
                    int i2 = ni * 16 + cw;                 // within-half rotation index, <32
                    int c = cbase + wn * 64 + i2;
                    float cc = ct[p * 32 + i2], sn = st[p * 32 + i2];
                    float x1 = acc[mi][ni][r], x2 = acc[mi][ni + 2][r];
                    split_store_swz(x1 * cc - x2 * sn, y, BSH, rowbase, c, phi, NP);
                    split_store_swz(x2 * cc + x1 * sn, y, BSH, rowbase, c + 32, phi, NP);
                }
            }
    } else {
        #pragma unroll
        for (int ni = 0; ni < 4; ++ni) {
            int c = cbase + wn * 64 + ni * 16 + cw;
            int phiv = ((c & 63) >> 1) & 3;
            #pragma unroll
            for (int mi = 0; mi < 4; ++mi)
                #pragma unroll
                for (int r = 0; r < 4; ++r) {
                    int gr = row0 + wm * 64 + mi * 16 + rw + r;
                    int b = gr >> 10, scol = gr & 1023;
                    split_store_swz(acc[mi][ni][r], vtp, BSH, ((size_t)c * B + b) * S, scol, phiv, NP);
                }
        }
    }
}

// ============ Fused gate-up: F = silu(A@Wg)*(A@Wu) -> pre-swz split planes ============
// NP=2 (shallow): single-buffer straight-line (144 VGPR). NP=1 (mid): 2-phase dbuf.
// rvalid skip: zero A-rows -> silu(0)*0 = +0 -> write zero planes.
template<int NP, int NPROD>
__global__ __launch_bounds__(256) void gateup_k(
    const _Float16* __restrict__ A, const _Float16* __restrict__ Wg, const _Float16* __restrict__ Wu,
    _Float16* __restrict__ F, int M, int N, int K,
    size_t planeA, size_t planeW, size_t planeF, int npOut, int swz,
    const int* __restrict__ rvalid)
{
    const int tid = threadIdx.x;
    const int w = tid >> 6, l = tid & 63;
    const int wm = w >> 1, wn = w & 1;
    int bx, by; tile_coords(swz, bx, by);
    const int row0 = by * 128, col0 = bx * 128;
    const int rA = l >> 2;
    const int cq8 = (l & 3) * 8;
    const int PA[4] = {0, 0, 1, 1};
    const int PW[4] = {0, 1, 0, 1};
    const int lr = l & 15, q = l >> 4;

    if (rvalid && rvalid[row0] == 0) {
        const int cw2 = l & 15, rw2 = (l >> 4) * 4;
        #pragma unroll
        for (int mi = 0; mi < 4; ++mi)
            #pragma unroll
            for (int ni = 0; ni < 4; ++ni)
                #pragma unroll
                for (int r = 0; r < 4; ++r) {
                    int gr = row0 + wm * 64 + mi * 16 + rw2 + r;
                    int gc = col0 + wn * 64 + ni * 16 + cw2;
                    split_store_swz(0.f, F, planeF, (size_t)gr * N, gc, (gr >> 1) & 3, npOut);
                }
        return;
    }

    f32x4 accg[4][4], accu[4][4];
    #pragma unroll
    for (int i = 0; i < 4; ++i)
        #pragma unroll
        for (int j = 0; j < 4; ++j)
            #pragma unroll
            for (int r = 0; r < 4; ++r) { accg[i][j][r] = 0.f; accu[i][j][r] = 0.f; }

    if constexpr (NP == 2) {
        __shared__ _Float16 As[NP][128 * 32];
        __shared__ _Float16 Bg[NP][128 * 32];
        __shared__ _Float16 Bu[NP][128 * 32];
        for (int k0 = 0; k0 < K; k0 += 32) {
            __syncthreads();
            #pragma unroll
            for (int p = 0; p < NP; ++p)
                #pragma unroll
                for (int s = 0; s < 2; ++s) {
                    int rr = (w * 2 + s) * 16 + rA;
                    gload16(A  + (size_t)p * planeA + (size_t)(row0 + rr) * K + k0 + cq8,
                            &As[p][(w * 2 + s) * 512]);
                    gload16(Wg + (size_t)p * planeW + (size_t)(col0 + rr) * K + k0 + cq8,
                            &Bg[p][(w * 2 + s) * 512]);
                    gload16(Wu + (size_t)p * planeW + (size_t)(col0 + rr) * K + k0 + cq8,
                            &Bu[p][(w * 2 + s) * 512]);
                }
            __syncthreads();
            f16x8 af[NP][4];
            #pragma unroll
            for (int p = 0; p < NP; ++p)
                #pragma unroll
                for (int i = 0; i < 4; ++i) {
                    int ra = wm * 64 + i * 16 + lr;
                    af[p][i] = *(const f16x8*)&As[p][ra * 32 + (q ^ ((ra >> 1) & 3)) * 8];
                }
            #pragma unroll
            for (int pr = 0; pr < NPROD; ++pr) {
                const int pa = PA[pr], pw = PW[pr];
                f16x8 bg[4], bu[4];
                #pragma unroll
                for (int i = 0; i < 4; ++i) {
                    int rb = wn * 64 + i * 16 + lr;
                    int sb = (q ^ ((rb >> 1) & 3)) * 8;
                    bg[i] = *(const f16x8*)&Bg[pw][rb * 32 + sb];
                    bu[i] = *(const f16x8*)&Bu[pw][rb * 32 + sb];
                }
                #pragma unroll
                for (int mi = 0; mi < 4; ++mi)
                    #pragma unroll
                    for (int ni = 0; ni < 4; ++ni) {
                        accg[mi][ni] = __builtin_amdgcn_mfma_f32_16x16x32_f16(
                            af[pa][mi], bg[ni], accg[mi][ni], 0, 0, 0);
                        accu[mi][ni] = __builtin_amdgcn_mfma_f32_16x16x32_f16(
                            af[pa][mi], bu[ni], accu[mi][ni], 0, 0, 0);
                    }
            }
        }
    } else {
        __shared__ _Float16 As[2][128 * 32];
        __shared__ _Float16 Bg[2][128 * 32];
        __shared__ _Float16 Bu[2][128 * 32];
        #pragma unroll
        for (int s = 0; s < 2; ++s) {
            int rr = (w * 2 + s) * 16 + rA;
            gload16(A  + (size_t)(row0 + rr) * K + cq8, &As[0][(w * 2 + s) * 512]);
            gload16(Wg + (size_t)(col0 + rr) * K + cq8, &Bg[0][(w * 2 + s) * 512]);
            gload16(Wu + (size_t)(col0 + rr) * K + cq8, &Bu[0][(w * 2 + s) * 512]);
        }
        __syncthreads();
        int cur = 0;
        for (int k0 = 0; k0 < K; k0 += 32) {
            if (k0 + 32 < K) {
                #pragma unroll
                for (int s = 0; s < 2; ++s) {
                    int rr = (w * 2 + s) * 16 + rA;
                    gload16(A  + (size_t)(row0 + rr) * K + k0 + 32 + cq8, &As[cur ^ 1][(w * 2 + s) * 512]);
                    gload16(Wg + (size_t)(col0 + rr) * K + k0 + 32 + cq8, &Bg[cur ^ 1][(w * 2 + s) * 512]);
                    gload16(Wu + (size_t)(col0 + rr) * K + k0 + 32 + cq8, &Bu[cur ^ 1][(w * 2 + s) * 512]);
                }
            }
            f16x8 af[4], bg[4], bu[4];
            #pragma unroll
            for (int i = 0; i < 4; ++i) {
                int ra = wm * 64 + i * 16 + lr;
                af[i] = *(const f16x8*)&As[cur][ra * 32 + (q ^ ((ra >> 1) & 3)) * 8];
                int rb = wn * 64 + i * 16 + lr;
                int sb = (q ^ ((rb >> 1) & 3)) * 8;
                bg[i] = *(const f16x8*)&Bg[cur][rb * 32 + sb];
                bu[i] = *(const f16x8*)&Bu[cur][rb * 32 + sb];
            }
            #pragma unroll
            for (int mi = 0; mi < 4; ++mi)
                #pragma unroll
                for (int ni = 0; ni < 4; ++ni) {
                    accg[mi][ni] = __builtin_amdgcn_mfma_f32_16x16x32_f16(
                        af[mi], bg[ni], accg[mi][ni], 0, 0, 0);
                    accu[mi][ni] = __builtin_amdgcn_mfma_f32_16x16x32_f16(
                        af[mi], bu[ni], accu[mi][ni], 0, 0, 0);
                }
            __syncthreads();
            cur ^= 1;
        }
    }

    const int cw = l & 15, rw = (l >> 4) * 4;
    #pragma unroll
    for (int mi = 0; mi < 4; ++mi)
        #pragma unroll
        for (int ni = 0; ni < 4; ++ni)
            #pragma unroll
            for (int r = 0; r < 4; ++r) {
                int gr = row0 + wm * 64 + mi * 16 + rw + r;
                int gc = col0 + wn * 64 + ni * 16 + cw;
                float g = accg[mi][ni][r], u = accu[mi][ni][r];
                float val = g / (1.f + expf(-g)) * u;
                split_store_swz(val, F, planeF, (size_t)gr * N, gc, (gr >> 1) & 3, npOut);
            }
}

// ============ MFMA flash attention (fp16, pre-swizzled planes, gload staging) ============
template<int NP, int NPROD, bool SKIPINV>
__global__ __launch_bounds__(256) void mfattn_k(
    const _Float16* __restrict__ qsp, const _Float16* __restrict__ ksp,
    const _Float16* __restrict__ vtp, _Float16* __restrict__ osp,
    const int* __restrict__ valid)
{
    __shared__ _Float16 KP[NP][2][64 * 32];   // K tile; reused as P planes
    __shared__ _Float16 Vt[NP][2][64 * 32];   // V^T tile
    __shared__ int kvs[64];
    const int tid = threadIdx.x;
    const int w = tid >> 6, l = tid & 63;
    const int lr = l & 15, lq = l >> 4;
    const int qt = blockIdx.x, hh = blockIdx.y, b = blockIdx.z;
    const int rT = l >> 2;
    const int cq8 = (l & 3) * 8;
    const int PA[4] = {0, 0, 1, 1};
    const int PW[4] = {0, 1, 0, 1};

    if (SKIPINV && valid[b * S + qt * 64] == 0) {
        // whole tile invalid (prefix): outputs are irrelevant downstream; write zeros
        #pragma unroll
        for (int r = 0; r < 4; ++r) {
            int qr = qt * 64 + w * 16 + lq * 4 + r;
            size_t rowbase = (size_t)(b * S + qr) * H;
            int phi = ((b * S + qr) >> 1) & 3;
            #pragma unroll
            for (int n = 0; n < 4; ++n)
                split_store_swz(0.f, osp, BSH, rowbase, hh * 64 + n * 16 + lr, phi, NP);
        }
        return;
    }

    f16x8 aq[NP][2];
    {
        const int qrowa = qt * 64 + w * 16 + lr;
        const int phiq = (qrowa >> 1) & 3;
        #pragma unroll
        for (int p = 0; p < NP; ++p)
            #pragma unroll
            for (int ks = 0; ks < 2; ++ks)
                aq[p][ks] = *(const f16x8*)(qsp + (size_t)p * BSH
                    + (size_t)(b * S + qrowa) * H + hh * 64 + ks * 32 + ((lq ^ phiq) << 3));
    }
    int qvr[4];
    #pragma unroll
    for (int r = 0; r < 4; ++r)
        qvr[r] = valid[b * S + qt * 64 + w * 16 + lq * 4 + r];

    // prefix-contiguous validity: last row valid => whole tile valid
    const int allv = valid[b * S + qt * 64 + 63];
    const int ktmax = allv ? qt : (S / 64 - 1);

    float m[4], lsum[4];
    f32x4 acco[4];
    #pragma unroll
    for (int r = 0; r < 4; ++r) { m[r] = -3.4e38f; lsum[r] = 0.f; }
    #pragma unroll
    for (int n = 0; n < 4; ++n)
        #pragma unroll
        for (int r = 0; r < 4; ++r) acco[n][r] = 0.f;

    for (int kt = 0; kt <= ktmax; ++kt) {
        __syncthreads();
        {
            const int r = w * 16 + rT;
            #pragma unroll
            for (int p = 0; p < NP; ++p)
                #pragma unroll
                for (int hf = 0; hf < 2; ++hf) {
                    gload16(ksp + (size_t)p * BSH
                            + (size_t)(b * S + kt * 64 + r) * H + hh * 64 + hf * 32 + cq8,
                            &KP[p][hf][w * 512]);
                    gload16(vtp + (size_t)p * BSH
                            + ((size_t)(hh * 64 + r) * B + b) * S + kt * 64 + hf * 32 + cq8,
                            &Vt[p][hf][w * 512]);
                }
        }
        if (tid < 64) kvs[tid] = valid[b * S + kt * 64 + tid];
        __syncthreads();

        // ---- S = Q @ K^T ----
        f32x4 accs[4];
        #pragma unroll
        for (int n = 0; n < 4; ++n)
            #pragma unroll
            for (int r = 0; r < 4; ++r) accs[n][r] = 0.f;
        #pragma unroll
        for (int pr = 0; pr < NPROD; ++pr) {
            const int pa = PA[pr], pw = PW[pr];
            #pragma unroll
            for (int ks = 0; ks < 2; ++ks)
                #pragma unroll
                for (int n = 0; n < 4; ++n) {
                    int rb = n * 16 + lr;
                    f16x8 bk = *(const f16x8*)&KP[pw][ks][rb * 32 + ((lq ^ ((rb >> 1) & 3))) * 8];
                    accs[n] = __builtin_amdgcn_mfma_f32_16x16x32_f16(
                        aq[pa][ks], bk, accs[n], 0, 0, 0);
                }
        }
        // ---- mask + online softmax ----
        float pf[4][4];
        int kva[4];
        #pragma unroll
        for (int n = 0; n < 4; ++n) kva[n] = kvs[n * 16 + lr];
        #pragma unroll
        for (int r = 0; r < 4; ++r) {
            int qr = qt * 64 + w * 16 + lq * 4 + r;
            float rowm = -3.4e38f;
            #pragma unroll
            for (int n = 0; n < 4; ++n) {
                int kc = kt * 64 + n * 16 + lr;
                float sv = accs[n][r] * 0.125f;
                int allowed = (kc <= qr) && qvr[r] && kva[n];
                if (!allowed) sv = sv + -1e9f;
                pf[n][r] = sv;
                rowm = fmaxf(rowm, sv);
            }
            rowm = fmaxf(rowm, __shfl_xor(rowm, 1));
            rowm = fmaxf(rowm, __shfl_xor(rowm, 2));
            rowm = fmaxf(rowm, __shfl_xor(rowm, 4));
            rowm = fmaxf(rowm, __shfl_xor(rowm, 8));
            float mn = fmaxf(m[r], rowm);
            float co = __expf(m[r] - mn);
            float rs = 0.f;
            #pragma unroll
            for (int n = 0; n < 4; ++n) { pf[n][r] = __expf(pf[n][r] - mn); rs += pf[n][r]; }
            rs += __shfl_xor(rs, 1);
            rs += __shfl_xor(rs, 2);
            rs += __shfl_xor(rs, 4);
            rs += __shfl_xor(rs, 8);
            lsum[r] = lsum[r] * co + rs;
            m[r] = mn;
            #pragma unroll
            for (int n = 0; n < 4; ++n) acco[n][r] *= co;
        }
        __syncthreads();
        // ---- write P (fp16 split) into KP, swizzled for a-frag reads ----
        #pragma unroll
        for (int n = 0; n < 4; ++n) {
            int col = n * 16 + lr;
            int hf = col >> 5, colh = col & 31, cq2 = colh >> 3, pos = colh & 7;
            #pragma unroll
            for (int r = 0; r < 4; ++r) {
                int rowg = w * 16 + lq * 4 + r;
                int off = rowg * 32 + (cq2 ^ ((rowg >> 1) & 3)) * 8 + pos;
                float pv = pf[n][r];
                _Float16 h0 = (_Float16)pv;
                KP[0][hf][off] = h0;
                if (NP == 2) KP[1][hf][off] = (_Float16)(pv - (float)h0);
            }
        }
        __syncthreads();
        // ---- O += P @ V ----
        #pragma unroll
        for (int pr = 0; pr < NPROD; ++pr) {
            const int pa = PA[pr], pw = PW[pr];
            #pragma unroll
            for (int ks = 0; ks < 2; ++ks) {
                int ra = w * 16 + lr;
                f16x8 ap = *(const f16x8*)&KP[pa][ks][ra * 32 + ((lq ^ ((ra >> 1) & 3))) * 8];
                #pragma unroll
                for (int n = 0; n < 4; ++n) {
                    int rb = n * 16 + lr;
                    f16x8 bv = *(const f16x8*)&Vt[pw][ks][rb * 32 + ((lq ^ ((rb >> 1) & 3))) * 8];
                    acco[n] = __builtin_amdgcn_mfma_f32_16x16x32_f16(
                        ap, bv, acco[n], 0, 0, 0);
                }
            }
        }
    }
    // ---- write O as pre-swizzled split planes ----
    #pragma unroll
    for (int r = 0; r < 4; ++r) {
        float inv = 1.0f / lsum[r];
        int qr = qt * 64 + w * 16 + lq * 4 + r;
        size_t rowbase = (size_t)(b * S + qr) * H;
        int phi = ((b * S + qr) >> 1) & 3;
        #pragma unroll
        for (int n = 0; n < 4; ++n)
            split_store_swz(acco[n][r] * inv, osp, BSH, rowbase, hh * 64 + n * 16 + lr, phi, NP);
    }
}

// ============ Init: trig table + iota positions (merged) ============
__global__ __launch_bounds__(256) void init_k(float* __restrict__ ct, float* __restrict__ st,
    int* __restrict__ pos)
{
    int idx = blockIdx.x * 256 + threadIdx.x;   // S*32 total
    if (idx < S * 32) {
        int i = idx & 31, p = idx >> 5;
        double inv = exp(-((double)(2 * i) / 64.0) * log(10000.0));
        double ang = (double)p * inv;
        ct[idx] = (float)cos(ang);
        st[idx] = (float)sin(ang);
    }
    if (idx < BS) pos[idx] = idx & (S - 1);
}

// ============ Merged per-layer weight split: qkv(3) + wo + wg/wu + wd, one launch ============
// Block ranges: [0,1536) qkv (subz=bid/512 -> wq/wk/wv), [1536,2048) wo,
// [2048,6144) wg/wu (z=(bid-2048)>>11), [6144,8192) wd.
// Per-element math identical to the former splitwt3_k / splitwt_k / splitwt2_k.
__global__ __launch_bounds__(256) void splitlayer_k(
    const float* __restrict__ wq, const float* __restrict__ wk, const float* __restrict__ wv,
    const float* __restrict__ wo, const float* __restrict__ wg, const float* __restrict__ wu,
    const float* __restrict__ wd,
    _Float16* __restrict__ qkvp, _Float16* __restrict__ wop,
    _Float16* __restrict__ wgp, _Float16* __restrict__ wup, _Float16* __restrict__ wdp,
    int np)
{
    __shared__ float t[32][65];
    const int tid = threadIdx.x;
    const int bid = blockIdx.x;
    const float* W; _Float16* D; int srcld, Krow, n0, k0; size_t plane, doff = 0;
    if (bid < 1536) {                       // qkv: 3 x (H/64=16 x H/32=32) = 1536
        int subz = bid / 512, w2 = bid % 512;
        W = (subz == 0) ? wq : (subz == 1) ? wk : wv;
        D = qkvp; doff = (size_t)subz * H * H;
        srcld = H; Krow = H; plane = 3ull * H * H;
        n0 = (w2 & 15) * 64; k0 = (w2 >> 4) * 32;
    } else if (bid < 2048) {                // wo: 16 x 32 = 512
        int w2 = bid - 1536;
        W = wo; D = wop; srcld = H; Krow = H; plane = (size_t)H * H;
        n0 = (w2 & 15) * 64; k0 = (w2 >> 4) * 32;
    } else if (bid < 6144) {                // wg/wu: 2 x (FF/64=64 x H/32=32) = 4096
        int z = (bid - 2048) >> 11, w2 = (bid - 2048) & 2047;
        W = z ? wu : wg; D = z ? wup : wgp;
        srcld = FF; Krow = H; plane = (size_t)H * FF;
        n0 = (w2 & 63) * 64; k0 = (w2 >> 6) * 32;
    } else {                                // wd: H/64=16 x FF/32=128 = 2048
        int w2 = bid - 6144;
        W = wd; D = wdp; srcld = H; Krow = FF; plane = (size_t)H * FF;
        n0 = (w2 & 15) * 64; k0 = (w2 >> 4) * 32;
    }
    #pragma unroll
    for (int i = 0; i < 8; ++i) {
        int e = tid + i * 256;
        int rk = e >> 6, cn = e & 63;
        t[rk][cn] = W[(size_t)(k0 + rk) * srcld + n0 + cn];
    }
    __syncthreads();
    int rn = tid >> 2, kg = (tid & 3) * 8;
    int nn = n0 + rn;
    float vals[8];
    #pragma unroll
    for (int e = 0; e < 8; ++e) vals[e] = t[kg + e][rn];
    split_store8_swz(vals, D + doff, plane, (size_t)nn * Krow, k0 + kg, (nn >> 1) & 3, np);
}

// ============ Weight transpose + split: W[K,N](srcld) -> Wt [N][K] (head_w / cemb) ============
__global__ __launch_bounds__(256) void splitwt_k(const float* __restrict__ W,
    _Float16* __restrict__ Wt, int K, int N, int srcld, size_t plane, int np)
{
    __shared__ float t[32][65];
    const int tid = threadIdx.x;
    const int n0 = blockIdx.x * 64, k0 = blockIdx.y * 32;
    #pragma unroll
    for (int i = 0; i < 8; ++i) {
        int e = tid + i * 256;
        int rk = e >> 6, cn = e & 63;
        t[rk][cn] = W[(size_t)(k0 + rk) * srcld + n0 + cn];
    }
    __syncthreads();
    int rn = tid >> 2, kg = (tid & 3) * 8;
    int nn = n0 + rn;
    float vals[8];
    #pragma unroll
    for (int e = 0; e < 8; ++e) vals[e] = t[kg + e][rn];
    split_store8_swz(vals, Wt, plane, (size_t)nn * K, k0 + kg, (nn >> 1) & 3, np);
}

// ============ Plain fp32 -> fp16 split planes (rows of length H), vectorized ============
__global__ __launch_bounds__(256) void splita_swz_k(const float* __restrict__ x,
    _Float16* __restrict__ y, size_t plane, int np)
{
    int row = blockIdx.x;
    size_t rowbase = (size_t)row * H;
    int phi = (row >> 1) & 3;
    int tid = threadIdx.x;
    if (tid < H / 8) {
        int c0 = tid * 8;
        float vals[8];
        #pragma unroll
        for (int e = 0; e < 8; ++e) vals[e] = x[rowbase + c0 + e];
        split_store8_swz(vals, y, plane, rowbase, c0, phi, np);
    }
}

// ============ RMSNorm -> pre-swz fp16 split ============
__global__ __launch_bounds__(256) void rmsnorm_split_k(const float* __restrict__ x,
    const float* __restrict__ w, _Float16* __restrict__ y, size_t plane, int np)
{
    int row = blockIdx.x;
    const float* xr = x + (size_t)row * H;
    __shared__ float red[256];
    float s = 0.f;
    for (int i = threadIdx.x; i < H; i += 256) { float v = xr[i]; s += v * v; }
    red[threadIdx.x] = s; __syncthreads();
    for (int off = 128; off > 0; off >>= 1) {
        if (threadIdx.x < off) red[threadIdx.x] += red[threadIdx.x + off];
        __syncthreads();
    }
    float r = 1.0f / sqrtf(red[0] / (float)H + 1e-6f);
    size_t rowbase = (size_t)row * H;
    int phi = (row >> 1) & 3;
    if (threadIdx.x < H / 8) {
        int c0 = threadIdx.x * 8;
        float vals[8];
        #pragma unroll
        for (int e = 0; e < 8; ++e) vals[e] = xr[c0 + e] * r * w[c0 + e];
        split_store8_swz(vals, y, plane, rowbase, c0, phi, np);
    }
}

// ---------------- fp32 GEMM (fallback path) ----------------
__global__ __launch_bounds__(256) void gemm_k(
    const float* __restrict__ A, const float* __restrict__ Wm,
    const float* __restrict__ bias, float* __restrict__ C,
    int M, int N, int K, int lda, int ldb, int ldc, int flags)
{
    __shared__ float As[16][65];
    __shared__ float Bs[16][65];
    const int tid = threadIdx.x;
    const int tx = tid & 15, ty = tid >> 4;
    const int row0 = blockIdx.y * 64, col0 = blockIdx.x * 64;
    float acc[4][4] = {};
    for (int k0 = 0; k0 < K; k0 += 16) {
        #pragma unroll
        for (int l = 0; l < 4; ++l) {
            int e = tid + l * 256;
            int r = e >> 4, c = e & 15;
            int gr = row0 + r;
            float vv = 0.f;
            if (gr < M) vv = A[(size_t)gr * lda + (k0 + c)];
            As[c][r] = vv;
        }
        #pragma unroll
        for (int l = 0; l < 4; ++l) {
            int e = tid + l * 256;
            int r = e >> 6, c = e & 63;
            int gc = col0 + c;
            float vv = 0.f;
            if (gc < N) vv = Wm[(size_t)(k0 + r) * ldb + gc];
            Bs[r][c] = vv;
        }
        __syncthreads();
        #pragma unroll
        for (int kk = 0; kk < 16; ++kk) {
            float a[4], bb[4];
            #pragma unroll
            for (int i = 0; i < 4; ++i) a[i] = As[kk][ty * 4 + i];
            #pragma unroll
            for (int j = 0; j < 4; ++j) bb[j] = Bs[kk][tx * 4 + j];
            #pragma unroll
            for (int i = 0; i < 4; ++i)
                #pragma unroll
                for (int j = 0; j < 4; ++j)
                    acc[i][j] += a[i] * bb[j];
        }
        __syncthreads();
    }
    #pragma unroll
    for (int i = 0; i < 4; ++i) {
        int gr = row0 + ty * 4 + i;
        if (gr >= M) continue;
        #pragma unroll
        for (int j = 0; j < 4; ++j) {
            int gc = col0 + tx * 4 + j;
            if (gc >= N) continue;
            float vv = acc[i][j];
            if (flags & F_BIAS)  vv += bias[gc];
            if (flags & F_SILU)  vv = vv / (1.f + expf(-vv));
            size_t cidx = (size_t)gr * ldc + gc;
            if (flags & F_MULIN) vv *= C[cidx];
            if (flags & F_RESID) vv += C[cidx];
            C[cidx] = vv;
        }
    }
}

// ---------------- RMSNorm fp32 (fallback) ----------------
__global__ __launch_bounds__(256) void rmsnorm_k(const float* __restrict__ x,
    const float* __restrict__ w, float* __restrict__ y)
{
    int row = blockIdx.x;
    const float* xr = x + (size_t)row * H;
    float* yr = y + (size_t)row * H;
    __shared__ float red[256];
    float s = 0.f;
    for (int i = threadIdx.x; i < H; i += 256) { float v = xr[i]; s += v * v; }
    red[threadIdx.x] = s; __syncthreads();
    for (int off = 128; off > 0; off >>= 1) {
        if (threadIdx.x < off) red[threadIdx.x] += red[threadIdx.x + off];
        __syncthreads();
    }
    float r = 1.0f / sqrtf(red[0] / (float)H + 1e-6f);
    for (int i = threadIdx.x; i < H; i += 256) yr[i] = xr[i] * r * w[i];
}

// ---------------- Embed gather (float4) ----------------
__global__ __launch_bounds__(256) void embed_k(const int* __restrict__ ids,
    const float* __restrict__ emb, float* __restrict__ h)
{
    int bs = blockIdx.x;
    const float4* e = (const float4*)(emb + (size_t)ids[bs] * H);
    float4* hr = (float4*)(h + (size_t)bs * H);
    hr[threadIdx.x] = e[threadIdx.x];
}

// ---------------- RoPE fp32 in-place (fallback) ----------------
__global__ __launch_bounds__(256) void rope_k(float* __restrict__ x, const int* __restrict__ pos)
{
    int idx = blockIdx.x * 256 + threadIdx.x;
    int i = idx & 31;
    int head = (idx >> 5) & 15;
    int bs = idx >> 9;
    int p = pos[bs];
    double inv = exp(-((double)(2 * i) / 64.0) * log(10000.0));
    double ang = (double)p * inv;
    float c = (float)cos(ang), sn = (float)sin(ang);
    float* base = x + (size_t)bs * H + head * 64;
    float x1 = base[i], x2 = base[i + 32];
    base[i]      = x1 * c - x2 * sn;
    base[i + 32] = x2 * c + x1 * sn;
}

// ---------------- Flash attention fp32 (fallback) ----------------
__global__ __launch_bounds__(256) void fattn_k(const float* __restrict__ q,
    const float* __restrict__ k, const float* __restrict__ v,
    float* __restrict__ o, const int* __restrict__ valid)
{
    const int qt = blockIdx.x, hh = blockIdx.y, b = blockIdx.z;
    const int tid = threadIdx.x;
    const int tx = tid & 15, ty = tid >> 4;
    __shared__ float Qs[64][68];
    __shared__ float Ks[64][68];
    __shared__ float Vs[64][68];
    __shared__ int   kvs[64];
    const size_t hoff = (size_t)hh * HD;

    {
        int row = tid >> 2, d0 = (tid & 3) * 16;
        const float* qp = q + ((size_t)(b * S + qt * 64 + row)) * H + hoff + d0;
        float4* dst = (float4*)&Qs[row][d0];
        const float4* src = (const float4*)qp;
        #pragma unroll
        for (int e = 0; e < 4; ++e) dst[e] = src[e];
    }
    int qv[4]; int qrow_g[4];
    #pragma unroll
    for (int i = 0; i < 4; ++i) {
        qrow_g[i] = qt * 64 + ty * 4 + i;
        qv[i] = valid[b * S + qrow_g[i]];
    }
    float m[4], l[4], acc[4][4];
    #pragma unroll
    for (int i = 0; i < 4; ++i) {
        m[i] = -3.4e38f; l[i] = 0.f;
        #pragma unroll
        for (int j = 0; j < 4; ++j) acc[i][j] = 0.f;
    }

    for (int kt = 0; kt < S / 64; ++kt) {
        __syncthreads();
        {
            int row = tid >> 2, d0 = (tid & 3) * 16;
            const float* kp = k + ((size_t)(b * S + kt * 64 + row)) * H + hoff + d0;
            float4* dst = (float4*)&Ks[row][d0];
            const float4* src = (const float4*)kp;
            #pragma unroll
            for (int e = 0; e < 4; ++e) dst[e] = src[e];
        }
        {
            int kk = tid >> 2, d0 = (tid & 3) * 16;
            const float* vp = v + ((size_t)(b * S + kt * 64 + kk)) * H + hoff + d0;
            #pragma unroll
            for (int e = 0; e < 16; e += 4) {
                float4 vv = *(const float4*)(vp + e);
                Vs[d0 + e + 0][kk] = vv.x;
                Vs[d0 + e + 1][kk] = vv.y;
                Vs[d0 + e + 2][kk] = vv.z;
                Vs[d0 + e + 3][kk] = vv.w;
            }
        }
        if (tid < 64) kvs[tid] = valid[b * S + kt * 64 + tid];
        __syncthreads();

        float s4[4][4];
        #pragma unroll
        for (int i = 0; i < 4; ++i)
            #pragma unroll
            for (int j = 0; j < 4; ++j) s4[i][j] = 0.f;
        #pragma unroll
        for (int c = 0; c < 16; ++c) {
            float4 a[4], bb[4];
            #pragma unroll
            for (int i = 0; i < 4; ++i) a[i]  = ((const float4*)&Qs[ty * 4 + i][0])[c];
            #pragma unroll
            for (int j = 0; j < 4; ++j) bb[j] = ((const float4*)&Ks[tx * 4 + j][0])[c];
            #pragma unroll
            for (int i = 0; i < 4; ++i)
                #pragma unroll
                for (int j = 0; j < 4; ++j) {
                    s4[i][j] += a[i].x * bb[j].x + a[i].y * bb[j].y
                              + a[i].z * bb[j].z + a[i].w * bb[j].w;
                }
        }
        float p[4][4];
        float corr[4];
        #pragma unroll
        for (int i = 0; i < 4; ++i) {
            float rm = -3.4e38f;
            #pragma unroll
            for (int j = 0; j < 4; ++j) {
                int kc = kt * 64 + tx * 4 + j;
                float sv = s4[i][j] * 0.125f;
                int allowed = (kc <= qrow_g[i]) && qv[i] && kvs[tx * 4 + j];
                if (!allowed) sv = sv + -1e9f;
                s4[i][j] = sv;
                rm = fmaxf(rm, sv);
            }
            rm = fmaxf(rm, __shfl_xor(rm, 1));
            rm = fmaxf(rm, __shfl_xor(rm, 2));
            rm = fmaxf(rm, __shfl_xor(rm, 4));
            rm = fmaxf(rm, __shfl_xor(rm, 8));
            float mn = fmaxf(m[i], rm);
            corr[i] = expf(m[i] - mn);
            float rs = 0.f;
            #pragma unroll
            for (int j = 0; j < 4; ++j) { p[i][j] = expf(s4[i][j] - mn); rs += p[i][j]; }
            rs += __shfl_xor(rs, 1);
            rs += __shfl_xor(rs, 2);
            rs += __shfl_xor(rs, 4);
            rs += __shfl_xor(rs, 8);
            l[i] = l[i] * corr[i] + rs;
            m[i] = mn;
            #pragma unroll
            for (int j = 0; j < 4; ++j) acc[i][j] *= corr[i];
        }
        __syncthreads();
        #pragma unroll
        for (int i = 0; i < 4; ++i) {
            float4 pv4 = make_float4(p[i][0], p[i][1], p[i][2], p[i][3]);
            *(float4*)&Ks[ty * 4 + i][tx * 4] = pv4;
        }
        __syncthreads();
        #pragma unroll
        for (int c = 0; c < 16; ++c) {
            float4 a[4], bb[4];
            #pragma unroll
            for (int i = 0; i < 4; ++i) a[i]  = ((const float4*)&Ks[ty * 4 + i][0])[c];
            #pragma unroll
            for (int j = 0; j < 4; ++j) bb[j] = ((const float4*)&Vs[tx * 4 + j][0])[c];
            #pragma unroll
            for (int i = 0; i < 4; ++i)
                #pragma unroll
                for (int j = 0; j < 4; ++j) {
                    acc[i][j] += a[i].x * bb[j].x + a[i].y * bb[j].y
                               + a[i].z * bb[j].z + a[i].w * bb[j].w;
                }
        }
    }
    #pragma unroll
    for (int i = 0; i < 4; ++i) {
        float inv = 1.0f / l[i];
        float4 ov = make_float4(acc[i][0] * inv, acc[i][1] * inv,
                                acc[i][2] * inv, acc[i][3] * inv);
        *(float4*)(o + ((size_t)(b * S + qrow_g[i])) * H + hoff + tx * 4) = ov;
    }
}

// ---------------- Discretize + inline null-logit (fused headcol) ----------------
__global__ __launch_bounds__(256) void discretize_h_k(const float* __restrict__ logits,
    const float* __restrict__ h, const float* __restrict__ head_w, const float* __restrict__ head_b,
    const float* __restrict__ gumbel, _Float16* __restrict__ z, int* __restrict__ chosen)
{
    int bs = blockIdx.x;
    const float* lg = logits + (size_t)bs * CV1;
    const float* gm = gumbel + (size_t)bs * CV1;
    __shared__ float redv[256]; __shared__ int redi[256];
    int tid = threadIdx.x;
    // null logit (col CV): dot(h[bs], head_w[:,CV]) + head_b[CV]
    float ps = 0.f;
    for (int j = tid; j < H; j += 256)
        ps += h[(size_t)bs * H + j] * head_w[(size_t)j * CV1 + CV];
    redv[tid] = ps; __syncthreads();
    for (int off = 128; off > 0; off >>= 1) {
        if (tid < off) redv[tid] += redv[tid + off];
        __syncthreads();
    }
    float nullv = redv[0] + head_b[CV];
    __syncthreads();
    // argmax over all CV1 entries (thread 0 handles j==CV last, preserving order)
    float m = -3.4e38f; int mi = CV1;
    for (int j = tid; j < CV; j += 256) {
        float a = lg[j] + gm[j];
        if (a > m) { m = a; mi = j; }
    }
    if (tid == 0) {
        float a = nullv + gm[CV];
        if (a > m) { m = a; mi = CV; }
    }
    redv[tid] = m; redi[tid] = mi; __syncthreads();
    for (int off = 128; off > 0; off >>= 1) {
        if (tid < off) {
            float vo = redv[tid + off]; int io = redi[tid + off];
            if (vo > redv[tid] || (vo == redv[tid] && io < redi[tid])) { redv[tid] = vo; redi[tid] = io; }
        }
        __syncthreads();
    }
    m = redv[0]; int amax = redi[0];
    __syncthreads();
    float ssum = 0.f;
    for (int j = tid; j < CV; j += 256) ssum += expf(lg[j] + gm[j] - m);
    if (tid == 0) ssum += expf(nullv + gm[CV] - m);
    redv[tid] = ssum; __syncthreads();
    for (int off = 128; off > 0; off >>= 1) {
        if (tid < off) redv[tid] += redv[tid + off];
        __syncthreads();
    }
    float inv = 1.0f / redv[0];
    size_t rowbase = (size_t)bs * CV;
    int phi = (bs >> 1) & 3;
    {
        int j8 = tid * 8;   // CV/8 = 256 groups
        float vals[8];
        #pragma unroll
        for (int e = 0; e < 8; ++e) vals[e] = expf(lg[j8 + e] + gm[j8 + e] - m) * inv;
        split_store8_swz(vals, z, 0, rowbase, j8, phi, 1);
    }
    if (tid == 0) chosen[bs] = amax;
}

__global__ __launch_bounds__(256) void discretize_k(const float* __restrict__ logits,
    const float* __restrict__ gumbel, float* __restrict__ z, int* __restrict__ chosen)
{
    int bs = blockIdx.x;
    const float* lg = logits + (size_t)bs * CV1;
    const float* gm = gumbel + (size_t)bs * CV1;
    __shared__ float redv[256]; __shared__ int redi[256];
    int tid = threadIdx.x;
    float m = -3.4e38f; int mi = CV1;
    for (int j = tid; j < CV1; j += 256) {
        float a = lg[j] + gm[j];
        if (a > m) { m = a; mi = j; }
    }
    redv[tid] = m; redi[tid] = mi; __syncthreads();
    for (int off = 128; off > 0; off >>= 1) {
        if (tid < off) {
            float vo = redv[tid + off]; int io = redi[tid + off];
            if (vo > redv[tid] || (vo == redv[tid] && io < redi[tid])) { redv[tid] = vo; redi[tid] = io; }
        }
        __syncthreads();
    }
    m = redv[0]; int amax = redi[0];
    __syncthreads();
    float ssum = 0.f;
    for (int j = tid; j < CV1; j += 256) ssum += expf(lg[j] + gm[j] - m);
    redv[tid] = ssum; __syncthreads();
    for (int off = 128; off > 0; off >>= 1) {
        if (tid < off) redv[tid] += redv[tid + off];
        __syncthreads();
    }
    float inv = 1.0f / redv[0];
    for (int j = tid; j < CV; j += 256)
        z[(size_t)bs * CV + j] = expf(lg[j] + gm[j] - m) * inv;
    if (tid == 0) chosen[bs] = amax;
}

// ---------------- cea + loss (float4) ----------------
__global__ __launch_bounds__(256) void cea_k(const float* __restrict__ esoft,
    const float* __restrict__ cemb, const int* __restrict__ chosen,
    const int* __restrict__ amask, float* __restrict__ cea, float* __restrict__ partial)
{
    int bs = blockIdx.x;
    int ch = chosen[bs]; int vm = amask[bs];
    int comp = (ch != CV) && vm;
    const float4* ehr = (const float4*)(cemb + (size_t)(ch < CV - 1 ? ch : CV - 1) * H);
    const float4* esr = (const float4*)(esoft + (size_t)bs * H);
    float4* cer = (float4*)(cea + (size_t)bs * H);
    __shared__ float red[256];
    float vmf = vm ? 1.f : 0.f;
    float4 es = esr[threadIdx.x];
    float4 ehv = comp ? ehr[threadIdx.x] : make_float4(0.f, 0.f, 0.f, 0.f);
    float4 o;
    o.x = ((ehv.x + es.x) - es.x) * vmf;
    o.y = ((ehv.y + es.y) - es.y) * vmf;
    o.z = ((ehv.z + es.z) - es.z) * vmf;
    o.w = ((ehv.w + es.w) - es.w) * vmf;
    cer[threadIdx.x] = o;
    float dx = es.x - ehv.x, dy = es.y - ehv.y, dz = es.z - ehv.z, dw = es.w - ehv.w;
    float part = dx * dx + dy * dy + dz * dz + dw * dw;
    red[threadIdx.x] = part; __syncthreads();
    for (int off = 128; off > 0; off >>= 1) {
        if (threadIdx.x < off) red[threadIdx.x] += red[threadIdx.x + off];
        __syncthreads();
    }
    if (threadIdx.x == 0) partial[bs] = red[0];
}

__global__ __launch_bounds__(256) void loss_k(const float* __restrict__ partial, float* __restrict__ out)
{
    __shared__ float red[256];
    float s = 0.f;
    for (int i = threadIdx.x; i < BS; i += 256) s += partial[i];
    red[threadIdx.x] = s; __syncthreads();
    for (int off = 128; off > 0; off >>= 1) {
        if (threadIdx.x < off) red[threadIdx.x] += red[threadIdx.x + off];
        __syncthreads();
    }
    if (threadIdx.x == 0) out[0] = 1.25f * red[0] / (float)BSH;
}

// ---------------- Parallel stable pack ----------------
__global__ __launch_bounds__(1024) void pack_k(const int* __restrict__ chosen,
    const int* __restrict__ amask, int* __restrict__ order, int* __restrict__ cpos,
    int* __restrict__ cvalid, int* __restrict__ counts)
{
    int b = blockIdx.x, t = threadIdx.x;
    __shared__ int sc[1024];
    __shared__ int ord[1024];
    int f = (chosen[b * S + t] != CV && amask[b * S + t]) ? 1 : 0;
    sc[t] = f;
    __syncthreads();
    #pragma unroll
    for (int off = 1; off < 1024; off <<= 1) {
        int add = (t >= off) ? sc[t - off] : 0;
        __syncthreads();
        sc[t] += add;
        __syncthreads();
    }
    int cnt = sc[1023];
    int pos = f ? (sc[t] - 1) : (cnt + t - sc[t]);
    ord[pos] = t;
    __syncthreads();
    int o = ord[t];
    order[b * S + t] = o;
    cvalid[b * S + t] = (t < cnt) ? 1 : 0;
    cpos[b * S + t] = (t < cnt) ? o : 0;
    if (t == 0) counts[b] = cnt;
}

__global__ __launch_bounds__(256) void gather_k(const float* __restrict__ cea,
    const int* __restrict__ order, const int* __restrict__ cvalid, float* __restrict__ h)
{
    int bs = blockIdx.x;
    int b = bs >> 10;
    int src = order[bs];
    float f = cvalid[bs] ? 1.f : 0.f;
    const float4* sp = (const float4*)(cea + (size_t)(b * S + src) * H);
    float4* dst = (float4*)(h + (size_t)bs * H);
    float4 v = sp[threadIdx.x];
    dst[threadIdx.x] = make_float4(v.x * f, v.y * f, v.z * f, v.w * f);
}

__global__ __launch_bounds__(256) void outmask_k(const float* __restrict__ h,
    const int* __restrict__ cvalid, float* __restrict__ out)
{
    int bs = blockIdx.x;
    float f = cvalid[bs] ? 1.f : 0.f;
    const float4* sp = (const float4*)(h + (size_t)bs * H);
    float4* dst = (float4*)(out + (size_t)bs * H);
    float4 v = sp[threadIdx.x];
    dst[threadIdx.x] = make_float4(v.x * f, v.y * f, v.z * f, v.w * f);
}

__global__ __launch_bounds__(256) void iota_k(int* __restrict__ pos)
{
    int idx = blockIdx.x * 256 + threadIdx.x;
    if (idx < BS) pos[idx] = idx & (S - 1);
}

// ================= Host-side drivers =================
static void run_block_f32(int layer,
    const float* ln1, const float* wq, const float* wk, const float* wv,
    const float* wo, const float* ln2, const float* wg, const float* wu, const float* wd,
    float* h, float* hn, float* q, float* k, float* v, float* o, float* f1,
    const int* valid, const int* pos, hipStream_t stream)
{
    size_t LHH = (size_t)layer * H * H;
    size_t LHF = (size_t)layer * H * FF;
    rmsnorm_k<<<BS, 256, 0, stream>>>(h, ln1 + (size_t)layer * H, hn);
    gemm_k<<<dim3(16, 64), 256, 0, stream>>>(hn, wq + LHH, nullptr, q, BS, H, H, H, H, H, 0);
    gemm_k<<<dim3(16, 64), 256, 0, stream>>>(hn, wk + LHH, nullptr, k, BS, H, H, H, H, H, 0);
    gemm_k<<<dim3(16, 64), 256, 0, stream>>>(hn, wv + LHH, nullptr, v, BS, H, H, H, H, H, 0);
    rope_k<<<8192, 256, 0, stream>>>(q, pos);
    rope_k<<<8192, 256, 0, stream>>>(k, pos);
    fattn_k<<<dim3(S / 64, NH, B), 256, 0, stream>>>(q, k, v, o, valid);
    gemm_k<<<dim3(16, 64), 256, 0, stream>>>(o, wo + LHH, nullptr, h, BS, H, H, H, H, H, F_RESID);
    rmsnorm_k<<<BS, 256, 0, stream>>>(h, ln2 + (size_t)layer * H, hn);
    gemm_k<<<dim3(64, 64), 256, 0, stream>>>(hn, wg + LHF, nullptr, f1, BS, FF, H, H, FF, FF, F_SILU);
    gemm_k<<<dim3(64, 64), 256, 0, stream>>>(hn, wu + LHF, nullptr, f1, BS, FF, H, H, FF, FF, F_MULIN);
    gemm_k<<<dim3(16, 64), 256, 0, stream>>>(f1, wd + (size_t)layer * FF * H, nullptr, h, BS, H, FF, FF, H, H, F_RESID);
}

// MFMA block, templated on split planes / products / invalid-row skip
// (shallow <2,3,false> rvalid=nullptr; mid <1,1,true> rvalid=cvalid)
// Weight planes: wg/wu/wd in [128MB..176MB); qkv/wo in the zb region [64MB..80MB)
// (zb is dead during layer execution: written at discretize, consumed at esoft).
template<int NP, int NPROD, bool SKIPINV>
static void run_block_mf(int layer,
    const float* ln1, const float* wq, const float* wk, const float* wv,
    const float* wo, const float* ln2, const float* wg, const float* wu, const float* wd,
    float* h,
    _Float16* hnsp, _Float16* osp, _Float16* f1sp,
    _Float16* qsp, _Float16* ksp, _Float16* vtp,
    const float* ct, const float* st,
    const int* valid, const int* pos, const int* rvalid,
    char* base, hipStream_t stream)
{
    const size_t MB = 1ull << 20;
    const size_t PH = (size_t)H * H;        // wo plane
    const size_t P3H = 3 * PH;              // fused qkv plane
    const size_t PGU = (size_t)H * FF;      // wg/wu/wd plane
    const size_t PA = BSH;                  // activation plane
    const size_t PF = BSF;                  // f1 plane
    size_t LHH = (size_t)layer * H * H;
    size_t LHF = (size_t)layer * H * FF;

    // per-NP weight plane layout
    _Float16* wgp  = (_Float16*)(base + 128 * MB);
    _Float16* wup  = (_Float16*)(base + (128 + (NP == 2 ? 16 : 8)) * MB);
    _Float16* wdp  = (_Float16*)(base + (128 + (NP == 2 ? 32 : 16)) * MB);
    _Float16* qkvp = (_Float16*)(base + 64 * MB);
    _Float16* wop  = (_Float16*)(base + (64 + (NP == 2 ? 12 : 6)) * MB);

    splitlayer_k<<<8192, 256, 0, stream>>>(
        wq + LHH, wk + LHH, wv + LHH, wo + LHH, wg + LHF, wu + LHF, wd + LHF,
        qkvp, wop, wgp, wup, wdp, NP);
    rmsnorm_split_k<<<BS, 256, 0, stream>>>(h, ln1 + (size_t)layer * H, hnsp, PA, NP);
    gemmqkv_k<NP, NPROD><<<dim3(3 * H / 128, BS / 128), 256, 0, stream>>>(
        hnsp, qkvp, pos, ct, st, qsp, ksp, vtp, H, PA, P3H, 1, rvalid);
    mfattn_k<NP, NPROD, SKIPINV><<<dim3(S / 64, NH, B), 256, 0, stream>>>(qsp, ksp, vtp, osp, valid);
    gemm_mf_k<NP, NPROD><<<dim3(H / 128, BS / 128), 256, 0, stream>>>(
        osp, wop, nullptr, h, h, BS, H, H, H, PA, PH, 1, rvalid);
    rmsnorm_split_k<<<BS, 256, 0, stream>>>(h, ln2 + (size_t)layer * H, hnsp, PA, NP);
    gateup_k<NP, NPROD><<<dim3(FF / 128, BS / 128), 256, 0, stream>>>(
        hnsp, wgp, wup, f1sp, BS, FF, H, PA, PGU, PF, NP, 2, rvalid);
    gemm_mf_k<NP, NPROD><<<dim3(H / 128, BS / 128), 256, 0, stream>>>(
        f1sp, wdp, nullptr, h, h, BS, H, FF, H, PF, PGU, 1, rvalid);
}

extern "C" void kernel_launch(void* const* d_in, const int* in_sizes, int n_in,
                              void* d_out, int out_size, void* d_ws, size_t ws_size,
                              hipStream_t stream)
{
    const int*   ids    = (const int*)d_in[0];
    const int*   amask  = (const int*)d_in[1];
    const float* embed  = (const float*)d_in[2];
    const float* ln1    = (const float*)d_in[3];
    const float* wq     = (const float*)d_in[4];
    const float* wk     = (const float*)d_in[5];
    const float* wv     = (const float*)d_in[6];
    const float* wo     = (const float*)d_in[7];
    const float* ln2    = (const float*)d_in[8];
    const float* wg     = (const float*)d_in[9];
    const float* wu     = (const float*)d_in[10];
    const float* wd     = (const float*)d_in[11];
    const float* head_w = (const float*)d_in[12];
    const float* head_b = (const float*)d_in[13];
    const float* cemb   = (const float*)d_in[14];
    const float* gumbel = (const float*)d_in[15];
    float* out = (float*)d_out;

    const size_t MB = 1ull << 20;
    const size_t NEED = 274 * MB;

    if (ws_size >= NEED) {
        // ===== MFMA path =====
        char* base = (char*)d_ws;
        float* h   = (float*)base;                  // 16MB
        float* qkv = (float*)(base + 16 * MB);      // 48MB (logits/esoft/cea workspace)
        _Float16* zb   = (_Float16*)(base + 64 * MB);   // 16MB [BS][CV]; doubles as qkv/wo planes during layers
        _Float16* hnsp = (_Float16*)(base + 80 * MB);   // 2 planes x 8MB
        _Float16* osp  = (_Float16*)(base + 104 * MB);
        _Float16* wsp  = (_Float16*)(base + 128 * MB);  // head/cemb planes; wg/wu/wd during layers
        _Float16* f1sp = (_Float16*)(base + 176 * MB);  // 2 planes x 32MB
        _Float16* qsp  = (_Float16*)(base + 176 * MB);  // alias f1sp (disjoint lifetime)
        _Float16* ksp  = (_Float16*)(base + 200 * MB);
        _Float16* vtp  = (_Float16*)(base + 224 * MB);
        int* meta   = (int*)(base + 272 * MB);
        int* chosen = meta;
        int* order  = meta + BS;
        int* cpos   = meta + 2 * BS;
        int* cvalid = meta + 3 * BS;
        int* counts = meta + 4 * BS;
        int* pos_sh = meta + 5 * BS;
        float* partial = (float*)(meta + 6 * BS);
        float* ct = (float*)(base + 273 * MB);          // S*32 floats (128KB)
        float* st = ct + S * 32;                        // S*32 floats
        float* logits = qkv;
        float* esoft  = qkv;
        float* ceab   = qkv + BSH;

        embed_k<<<BS, 256, 0, stream>>>(ids, embed, h);
        init_k<<<S * 32 / 256, 256, 0, stream>>>(ct, st, pos_sh);

        for (int L = 0; L < 2; ++L)
            run_block_mf<2, 3, false>(L, ln1, wq, wk, wv, wo, ln2, wg, wu, wd,
                                      h, hnsp, osp, f1sp,
                                      qsp, ksp, vtp, ct, st, amask, pos_sh, nullptr,
                                      base, stream);

        // ---- head logits: fp16 2-plane, ALL 4 products (argmax-critical) ----
        splita_swz_k<<<BS, 256, 0, stream>>>(h, hnsp, BSH, 2);
        splitwt_k<<<dim3(CV / 64, H / 32), 256, 0, stream>>>(head_w, wsp, H, CV, CV1, (size_t)CV * H, 2);
        gemm_mf_k<2, 4><<<dim3(CV / 128, BS / 128), 256, 0, stream>>>(
            hnsp, wsp, head_b, logits, nullptr, BS, CV, H, CV1, BSH, (size_t)CV * H, 1, nullptr);
        discretize_h_k<<<BS, 256, 0, stream>>>(logits, h, head_w, head_b, gumbel, zb, chosen);

        // ---- e_soft = z @ cemb (fp16 1-plane) ----
        splitwt_k<<<dim3(H / 64, CV / 32), 256, 0, stream>>>(cemb, wsp, CV, H, H, (size_t)H * CV, 1);
        gemm_mf_k<1, 1><<<dim3(H / 128, BS / 128), 256, 0, stream>>>(
            zb, wsp, nullptr, esoft, nullptr, BS, H, CV, H, (size_t)BS * CV, (size_t)H * CV, 0, nullptr);

        cea_k<<<BS, 256, 0, stream>>>(esoft, cemb, chosen, amask, ceab, partial);
        loss_k<<<1, 256, 0, stream>>>(partial, out + BSH);
        pack_k<<<B, 1024, 0, stream>>>(chosen, amask, order, cpos, cvalid, counts);
        gather_k<<<BS, 256, 0, stream>>>(ceab, order, cvalid, h);

        for (int L = 2; L < 4; ++L)
            run_block_mf<1, 1, true>(L, ln1, wq, wk, wv, wo, ln2, wg, wu, wd,
                                     h, hnsp, osp, f1sp,
                                     qsp, ksp, vtp, ct, st, cvalid, cpos, cvalid,
                                     base, stream);

        outmask_k<<<BS, 256, 0, stream>>>(h, cvalid, out);
    } else {
        // ===== fallback: fp32 path =====
        float* wsf = (float*)d_ws;
        float* h   = wsf;
        float* hn  = wsf + BSH;
        float* q   = wsf + 2 * BSH;
        float* k   = wsf + 3 * BSH;
        float* v   = wsf + 4 * BSH;
        float* o   = wsf + 5 * BSH;
        float* f1  = wsf + 6 * BSH;
        float* zbuf  = q;
        float* esoft = v;
        float* ceab  = o;
        int* meta   = (int*)(wsf + 6 * BSH + BSF);
        int* chosen = meta;
        int* order  = meta + BS;
        int* cpos   = meta + 2 * BS;
        int* cvalid = meta + 3 * BS;
        int* counts = meta + 4 * BS;
        int* pos_sh = meta + 5 * BS;
        float* partial = (float*)(meta + 6 * BS);

        embed_k<<<BS, 256, 0, stream>>>(ids, embed, h);
        iota_k<<<16, 256, 0, stream>>>(pos_sh);
        for (int L = 0; L < 2; ++L)
            run_block_f32(L, ln1, wq, wk, wv, wo, ln2, wg, wu, wd,
                          h, hn, q, k, v, o, f1, amask, pos_sh, stream);
        gemm_k<<<dim3(33, 64), 256, 0, stream>>>(h, head_w, head_b, f1, BS, CV1, H, H, CV1, CV1, F_BIAS);
        discretize_k<<<BS, 256, 0, stream>>>(f1, gumbel, zbuf, chosen);
        gemm_k<<<dim3(16, 64), 256, 0, stream>>>(zbuf, cemb, nullptr, esoft, BS, H, CV, CV, H, H, 0);
        cea_k<<<BS, 256, 0, stream>>>(esoft, cemb, chosen, amask, ceab, partial);
        loss_k<<<1, 256, 0, stream>>>(partial, out + BSH);
        pack_k<<<B, 1024, 0, stream>>>(chosen, amask, order, cpos, cvalid, counts);
        gather_k<<<BS, 256, 0, stream>>>(ceab, order, cvalid, h);
        for (int L = 2; L < 4; ++L)
            run_block_f32(L, ln1, wq, wk, wv, wo, ln2, wg, wu, wd,
                          h, hn, q, k, v, o, f1, cvalid, cpos, stream);
        outmask_k<<<BS, 256, 0, stream>>>(h, cvalid, out);
    }
}